// Round 1
// baseline (4581.490 us; speedup 1.0000x reference)
//
#include <hip/hip_runtime.h>
#include <hip/hip_bf16.h>

#define DD 128
#define HH 4
#define CC 32
#define LL 3

// ---------- helpers ----------

__device__ __forceinline__ void redsum2_128(float& a, float& b) {
    // blockDim.x == 128 (2 waves). Returns full-block sums of a and b to all threads.
    #pragma unroll
    for (int off = 32; off > 0; off >>= 1) {
        a += __shfl_down(a, off);
        b += __shfl_down(b, off);
    }
    __shared__ float sa[2], sb[2];
    int w = threadIdx.x >> 6;
    if ((threadIdx.x & 63) == 0) { sa[w] = a; sb[w] = b; }
    __syncthreads();
    a = sa[0] + sa[1];
    b = sb[0] + sb[1];
    __syncthreads();
}

__device__ __forceinline__ unsigned encodeF(float f) {
    unsigned u = __float_as_uint(f);
    return (u >> 31) ? ~u : (u | 0x80000000u);
}
__device__ __forceinline__ float decodeF(unsigned k) {
    return (k >> 31) ? __uint_as_float(k & 0x7fffffffu) : __uint_as_float(~k);
}

// ---------- kernels ----------

// x = relu(LN(cat(xyz,attr) @ encW + encb))
__global__ void enc_kernel(const float* __restrict__ xyz, const float* __restrict__ attr,
                           const float* __restrict__ W, const float* __restrict__ b,
                           const float* __restrict__ g, const float* __restrict__ bb,
                           float* __restrict__ x) {
    int i = blockIdx.x, d = threadIdx.x;
    __shared__ float sin4[4];
    if (d < 3) sin4[d] = xyz[i * 3 + d];
    if (d == 3) sin4[3] = attr[i];
    __syncthreads();
    float y = b[d];
    #pragma unroll
    for (int kk = 0; kk < 4; ++kk) y += sin4[kk] * W[kk * DD + d];
    float s = y, s2 = y * y;
    redsum2_128(s, s2);
    float mean = s * (1.0f / DD);
    float var = s2 * (1.0f / DD) - mean * mean;
    float xn = (y - mean) * rsqrtf(var + 1e-5f) * g[d] + bb[d];
    x[i * DD + d] = fmaxf(xn, 0.f);
}

// e = relu(LN(rel @ W1 + b1)) @ W2 + b2, rel = xyz[dst]-xyz[src]
__global__ void pos_kernel(const float* __restrict__ xyz, const int* __restrict__ ei,
                           const float* __restrict__ W1, const float* __restrict__ b1,
                           const float* __restrict__ g, const float* __restrict__ bb,
                           const float* __restrict__ W2, const float* __restrict__ b2,
                           float* __restrict__ e, int nE) {
    int eid = blockIdx.x, d = threadIdx.x;
    __shared__ float srel[3];
    if (d < 3) {
        int s = ei[eid], t = ei[nE + eid];
        srel[d] = xyz[t * 3 + d] - xyz[s * 3 + d];
    }
    __syncthreads();
    float y = b1[d] + srel[0] * W1[d] + srel[1] * W1[DD + d] + srel[2] * W1[2 * DD + d];
    float s = y, s2 = y * y;
    redsum2_128(s, s2);
    float mean = s * (1.0f / DD);
    float var = s2 * (1.0f / DD) - mean * mean;
    float t = fmaxf((y - mean) * rsqrtf(var + 1e-5f) * g[d] + bb[d], 0.f);
    __shared__ float st[DD];
    st[d] = t;
    __syncthreads();
    float o = b2[d];
    #pragma unroll 8
    for (int kk = 0; kk < DD; ++kk) o += st[kk] * W2[kk * DD + d];
    e[(size_t)eid * DD + d] = o;
}

// q,k,v,r = x @ {Wq,Wk,Wv,Wskip} + bias
__global__ void qkvr_kernel(const float* __restrict__ x,
                            const float* __restrict__ Wq, const float* __restrict__ bq,
                            const float* __restrict__ Wk, const float* __restrict__ bk,
                            const float* __restrict__ Wv, const float* __restrict__ bv,
                            const float* __restrict__ Ws, const float* __restrict__ bs,
                            float* __restrict__ q, float* __restrict__ k,
                            float* __restrict__ v, float* __restrict__ r) {
    int i = blockIdx.x, d = threadIdx.x;
    __shared__ float sx[DD];
    sx[d] = x[i * DD + d];
    __syncthreads();
    float aq = bq[d], ak = bk[d], av = bv[d], ar = bs[d];
    #pragma unroll 4
    for (int kk = 0; kk < DD; ++kk) {
        float xv = sx[kk];
        aq += xv * Wq[kk * DD + d];
        ak += xv * Wk[kk * DD + d];
        av += xv * Wv[kk * DD + d];
        ar += xv * Ws[kk * DD + d];
    }
    q[i * DD + d] = aq; k[i * DD + d] = ak; v[i * DD + d] = av; r[i * DD + d] = ar;
}

__global__ void amax_init_kernel(unsigned* __restrict__ amax, int n) {
    int i = blockIdx.x * blockDim.x + threadIdx.x;
    if (i < n) amax[i] = 0x007FFFFFu;  // encodeF(-inf)
}

// ee = e @ We; alpha = dot(q[dst], k[src]+ee)/sqrt(C); atomicMax amax
template <bool STORE>
__global__ void alpha_kernel(const float* __restrict__ e, const float* __restrict__ We,
                             const float* __restrict__ q, const float* __restrict__ k,
                             const int* __restrict__ ei, float* __restrict__ ee_buf,
                             float* __restrict__ alpha, unsigned* __restrict__ amax,
                             int nE, float inv_sqrt_c) {
    int eid = blockIdx.x, d = threadIdx.x;
    __shared__ float se[DD];
    se[d] = e[(size_t)eid * DD + d];
    __syncthreads();
    float o = 0.f;
    #pragma unroll 8
    for (int kk = 0; kk < DD; ++kk) o += se[kk] * We[kk * DD + d];
    if (STORE) ee_buf[(size_t)eid * DD + d] = o;
    int src = ei[eid], dst = ei[nE + eid];
    float kj = k[src * DD + d] + o;
    float p = q[dst * DD + d] * kj;
    #pragma unroll
    for (int m = 16; m > 0; m >>= 1) p += __shfl_xor(p, m);
    if ((d & 31) == 0) {
        int h = d >> 5;
        float al = p * inv_sqrt_c;
        alpha[(size_t)eid * HH + h] = al;
        atomicMax(&amax[dst * HH + h], encodeF(al));
    }
}

// ex = exp(alpha - amax[dst]); den[dst] += ex   (in-place over alpha)
__global__ void ex_kernel(float* __restrict__ alpha, const unsigned* __restrict__ amax,
                          const int* __restrict__ ei, float* __restrict__ den, int nE) {
    int idx = blockIdx.x * blockDim.x + threadIdx.x;
    if (idx >= nE * HH) return;
    int eid = idx >> 2;
    int h = idx & 3;
    int dst = ei[nE + eid];
    float m = decodeF(amax[dst * HH + h]);
    float ex = expf(alpha[idx] - m);
    alpha[idx] = ex;
    atomicAdd(&den[dst * HH + h], ex);
}

// out[dst] += (v[src]+ee) * (ex/den[dst])
template <bool STORE>
__global__ void msg_kernel(const float* __restrict__ e, const float* __restrict__ We,
                           const float* __restrict__ ee_buf, const float* __restrict__ v,
                           const float* __restrict__ alpha, const float* __restrict__ den,
                           const int* __restrict__ ei, float* __restrict__ out, int nE) {
    int eid = blockIdx.x, d = threadIdx.x;
    float o;
    if constexpr (STORE) {
        o = ee_buf[(size_t)eid * DD + d];
    } else {
        __shared__ float se[DD];
        se[d] = e[(size_t)eid * DD + d];
        __syncthreads();
        o = 0.f;
        #pragma unroll 8
        for (int kk = 0; kk < DD; ++kk) o += se[kk] * We[kk * DD + d];
    }
    int src = ei[eid], dst = ei[nE + eid];
    int h = d >> 5;
    float a = alpha[(size_t)eid * HH + h] / den[dst * HH + h];
    float m = (v[src * DD + d] + o) * a;
    atomicAdd(&out[dst * DD + d], m);
}

// beta-gated skip + residual + LN1 (x updated in place)
__global__ void combine_kernel(const float* __restrict__ out, const float* __restrict__ r,
                               const float* __restrict__ Wb, const float* __restrict__ g1,
                               const float* __restrict__ b1, float* __restrict__ x) {
    int i = blockIdx.x, d = threadIdx.x;
    float od = out[i * DD + d], rd = r[i * DD + d];
    float part = od * Wb[d] + rd * Wb[DD + d] + (od - rd) * Wb[2 * DD + d];
    float dummy = 0.f;
    redsum2_128(part, dummy);
    float beta = 1.f / (1.f + expf(-part));
    float comb = beta * rd + (1.f - beta) * od;
    float t = comb + x[i * DD + d];
    float s = t, s2 = t * t;
    redsum2_128(s, s2);
    float mean = s * (1.0f / DD);
    float var = s2 * (1.0f / DD) - mean * mean;
    x[i * DD + d] = (t - mean) * rsqrtf(var + 1e-5f) * g1[d] + b1[d];
}

// h1 = gelu_exact(x @ fW1 + fb1)   (256 threads)
__global__ void ffn1_kernel(const float* __restrict__ x, const float* __restrict__ W1,
                            const float* __restrict__ b1, float* __restrict__ h1) {
    int i = blockIdx.x, d = threadIdx.x;
    __shared__ float sx[DD];
    if (d < DD) sx[d] = x[i * DD + d];
    __syncthreads();
    float a = b1[d];
    #pragma unroll 8
    for (int kk = 0; kk < DD; ++kk) a += sx[kk] * W1[kk * 256 + d];
    h1[(size_t)i * 256 + d] = 0.5f * a * (1.f + erff(a * 0.70710678118654752f));
}

// x = LN(h1 @ fW2 + fb2 + x)
__global__ void ffn2_kernel(const float* __restrict__ h1, const float* __restrict__ W2,
                            const float* __restrict__ b2, const float* __restrict__ g2,
                            const float* __restrict__ bb2, float* __restrict__ x) {
    int i = blockIdx.x, d = threadIdx.x;
    __shared__ float sh[256];
    sh[d] = h1[(size_t)i * 256 + d];
    sh[d + 128] = h1[(size_t)i * 256 + d + 128];
    __syncthreads();
    float a = b2[d];
    #pragma unroll 8
    for (int kk = 0; kk < 256; ++kk) a += sh[kk] * W2[kk * DD + d];
    float t = a + x[i * DD + d];
    float s = t, s2 = t * t;
    redsum2_128(s, s2);
    float mean = s * (1.0f / DD);
    float var = s2 * (1.0f / DD) - mean * mean;
    x[i * DD + d] = (t - mean) * rsqrtf(var + 1e-5f) * g2[d] + bb2[d];
}

// cls and box heads
__global__ void heads_kernel(const float* __restrict__ x,
                             const float* __restrict__ cW1, const float* __restrict__ cb1,
                             const float* __restrict__ cW2, const float* __restrict__ cb2,
                             const float* __restrict__ bW1, const float* __restrict__ bb1,
                             const float* __restrict__ bW2, const float* __restrict__ bb2,
                             float* __restrict__ outc, float* __restrict__ outb) {
    int i = blockIdx.x, d = threadIdx.x;  // 128 threads
    __shared__ float sx[DD], st[128];
    sx[d] = x[i * DD + d];
    __syncthreads();
    float a;
    if (d < 64) {
        a = cb1[d];
        #pragma unroll 8
        for (int kk = 0; kk < DD; ++kk) a += sx[kk] * cW1[kk * 64 + d];
    } else {
        int dd = d - 64;
        a = bb1[dd];
        #pragma unroll 8
        for (int kk = 0; kk < DD; ++kk) a += sx[kk] * bW1[kk * 64 + dd];
    }
    st[d] = fmaxf(a, 0.f);
    __syncthreads();
    if (d < 4) {
        float o = cb2[d];
        #pragma unroll
        for (int kk = 0; kk < 64; ++kk) o += st[kk] * cW2[kk * 4 + d];
        outc[i * 4 + d] = o;
    } else if (d >= 64 && d < 71) {
        int j = d - 64;
        float o = bb2[j];
        #pragma unroll
        for (int kk = 0; kk < 64; ++kk) o += st[64 + kk] * bW2[kk * 7 + j];
        outb[i * 7 + j] = o;
    }
}

extern "C" void kernel_launch(void* const* d_in, const int* in_sizes, int n_in,
                              void* d_out, int out_size, void* d_ws, size_t ws_size,
                              hipStream_t stream) {
    const float* xyz   = (const float*)d_in[0];
    const float* attr  = (const float*)d_in[1];
    const int*   ei    = (const int*)d_in[2];
    const float* encW  = (const float*)d_in[3];
    const float* encb  = (const float*)d_in[4];
    const float* encg  = (const float*)d_in[5];
    const float* encbb = (const float*)d_in[6];
    const float* posW1 = (const float*)d_in[7];
    const float* posb1 = (const float*)d_in[8];
    const float* posg  = (const float*)d_in[9];
    const float* posbb = (const float*)d_in[10];
    const float* posW2 = (const float*)d_in[11];
    const float* posb2 = (const float*)d_in[12];
    const float* Wq    = (const float*)d_in[13];
    const float* bq    = (const float*)d_in[14];
    const float* Wk    = (const float*)d_in[15];
    const float* bk    = (const float*)d_in[16];
    const float* Wv    = (const float*)d_in[17];
    const float* bv    = (const float*)d_in[18];
    const float* We    = (const float*)d_in[19];
    const float* Wskip = (const float*)d_in[20];
    const float* bskip = (const float*)d_in[21];
    const float* Wbeta = (const float*)d_in[22];
    const float* ln1g  = (const float*)d_in[23];
    const float* ln1b  = (const float*)d_in[24];
    const float* ln2g  = (const float*)d_in[25];
    const float* ln2b  = (const float*)d_in[26];
    const float* fW1   = (const float*)d_in[27];
    const float* fb1   = (const float*)d_in[28];
    const float* fW2   = (const float*)d_in[29];
    const float* fb2   = (const float*)d_in[30];
    const float* cW1   = (const float*)d_in[31];
    const float* cb1   = (const float*)d_in[32];
    const float* cW2   = (const float*)d_in[33];
    const float* cb2   = (const float*)d_in[34];
    const float* bW1   = (const float*)d_in[35];
    const float* bb1   = (const float*)d_in[36];
    const float* bW2   = (const float*)d_in[37];
    const float* bb2   = (const float*)d_in[38];

    const int N = in_sizes[0] / 3;
    const int E = in_sizes[2] / 2;
    const float inv_sqrt_c = 0.17677669529663687f;  // 1/sqrt(32)

    // workspace carve-up
    size_t off = 0;
    auto alloc = [&](size_t nelem) {
        char* p = (char*)d_ws + off;
        off += nelem * sizeof(float);
        return (float*)p;
    };
    float* x    = alloc((size_t)N * DD);
    float* e    = alloc((size_t)E * DD);
    float* q    = alloc((size_t)N * DD);
    float* k    = alloc((size_t)N * DD);
    float* v    = alloc((size_t)N * DD);
    float* r    = alloc((size_t)N * DD);
    float* outb = alloc((size_t)N * DD);
    float* h1   = alloc((size_t)N * 256);
    float* alpha = alloc((size_t)E * HH);
    float* den  = alloc((size_t)N * HH);
    unsigned* amax = (unsigned*)alloc((size_t)N * HH);
    bool store_ee = (off + (size_t)E * DD * sizeof(float) <= ws_size);
    float* eebuf = store_ee ? alloc((size_t)E * DD) : nullptr;

    enc_kernel<<<N, DD, 0, stream>>>(xyz, attr, encW, encb, encg, encbb, x);
    pos_kernel<<<E, DD, 0, stream>>>(xyz, ei, posW1, posb1, posg, posbb, posW2, posb2, e, E);

    for (int l = 0; l < LL; ++l) {
        const float* Wq_l = Wq + (size_t)l * DD * DD;
        const float* Wk_l = Wk + (size_t)l * DD * DD;
        const float* Wv_l = Wv + (size_t)l * DD * DD;
        const float* We_l = We + (size_t)l * DD * DD;
        const float* Ws_l = Wskip + (size_t)l * DD * DD;
        const float* Wb_l = Wbeta + (size_t)l * 3 * DD;
        const float* fW1_l = fW1 + (size_t)l * DD * 256;
        const float* fW2_l = fW2 + (size_t)l * 256 * DD;

        hipMemsetAsync(den, 0, (size_t)N * HH * sizeof(float), stream);
        hipMemsetAsync(outb, 0, (size_t)N * DD * sizeof(float), stream);
        amax_init_kernel<<<(N * HH + 255) / 256, 256, 0, stream>>>(amax, N * HH);

        qkvr_kernel<<<N, DD, 0, stream>>>(x, Wq_l, bq + l * DD, Wk_l, bk + l * DD,
                                          Wv_l, bv + l * DD, Ws_l, bskip + l * DD,
                                          q, k, v, r);
        if (store_ee)
            alpha_kernel<true><<<E, DD, 0, stream>>>(e, We_l, q, k, ei, eebuf, alpha, amax, E, inv_sqrt_c);
        else
            alpha_kernel<false><<<E, DD, 0, stream>>>(e, We_l, q, k, ei, eebuf, alpha, amax, E, inv_sqrt_c);
        ex_kernel<<<(E * HH + 255) / 256, 256, 0, stream>>>(alpha, amax, ei, den, E);
        if (store_ee)
            msg_kernel<true><<<E, DD, 0, stream>>>(e, We_l, eebuf, v, alpha, den, ei, outb, E);
        else
            msg_kernel<false><<<E, DD, 0, stream>>>(e, We_l, eebuf, v, alpha, den, ei, outb, E);
        combine_kernel<<<N, DD, 0, stream>>>(outb, r, Wb_l, ln1g + l * DD, ln1b + l * DD, x);
        ffn1_kernel<<<N, 256, 0, stream>>>(x, fW1_l, fb1 + l * 256, h1);
        ffn2_kernel<<<N, DD, 0, stream>>>(h1, fW2_l, fb2 + l * DD, ln2g + l * DD, ln2b + l * DD, x);
    }

    float* outc = (float*)d_out;
    float* outbx = (float*)d_out + (size_t)N * 4;
    heads_kernel<<<N, DD, 0, stream>>>(x, cW1, cb1, cW2, cb2, bW1, bb1, bW2, bb2, outc, outbx);
}

// Round 2
// 2519.058 us; speedup vs baseline: 1.8187x; 1.8187x over previous
//
#include <hip/hip_runtime.h>
#include <hip/hip_bf16.h>
#include <math.h>

#define DD 128
#define HH 4

// ---------- helpers ----------

__device__ __forceinline__ void redsum2_128(float& a, float& b) {
    // blockDim.x == 128 (2 waves). Full-block sums of a and b to all threads.
    #pragma unroll
    for (int off = 32; off > 0; off >>= 1) {
        a += __shfl_down(a, off);
        b += __shfl_down(b, off);
    }
    __shared__ float sa[2], sb[2];
    int w = threadIdx.x >> 6;
    if ((threadIdx.x & 63) == 0) { sa[w] = a; sb[w] = b; }
    __syncthreads();
    a = sa[0] + sa[1];
    b = sb[0] + sb[1];
    __syncthreads();
}

__device__ __forceinline__ void fma4(float4& d, float s, const float4& w) {
    d.x += s * w.x; d.y += s * w.y; d.z += s * w.z; d.w += s * w.w;
}

// ---------- tiled GEMM: out[rows,Dout] = act(A[rows,K] @ W[K,Dout] + bias) ----------
// ACT: 0=none, 1=gelu(exact), 2=relu.  K, Dout multiples of 128.
// Tile 128x128, block 256 threads, 8x8 per thread in split halves.
// In-place (out==A) is safe iff gridDim.y==1 and K==128 (block reads its whole
// A tile into LDS before any store; blocks touch disjoint row ranges).
template <int ACT>
__global__ __launch_bounds__(256, 1) void gemm_kernel(
        const float* __restrict__ A, const float* __restrict__ W,
        const float* __restrict__ bias, float* out,
        int rows, int K, int Dout) {
    __shared__ float sA[128 * 128];  // transposed [kk][row], rows XOR-swizzled by kk
    __shared__ float sW[128 * 128];  // [kk][col]
    const int t = threadIdx.x;
    const int rowBase = blockIdx.x << 7;
    const int colBase = blockIdx.y << 7;
    const int rg = t >> 4;      // 16 row-groups (4 rows each, split halves)
    const int cg = t & 15;      // 16 col-groups (4 cols each, split halves)

    float4 acc[2][2][4];
    #pragma unroll
    for (int a = 0; a < 2; ++a)
        #pragma unroll
        for (int b = 0; b < 2; ++b)
            #pragma unroll
            for (int c = 0; c < 4; ++c) acc[a][b][c] = make_float4(0.f, 0.f, 0.f, 0.f);

    for (int k0 = 0; k0 < K; k0 += 128) {
        if (k0) __syncthreads();
        #pragma unroll 8
        for (int i = 0; i < 64; ++i) {
            int lin = (i << 8) + t;
            int kk = lin & 127;         // A: k index (coalesced in global)
            int rr = lin >> 7;          // A: row in tile
            int grow = rowBase + rr;
            float va = (grow < rows) ? A[(size_t)grow * K + (k0 + kk)] : 0.f;
            sA[(kk << 7) + (rr ^ ((kk & 7) << 2))] = va;
            // W: kw = lin>>7, c = lin&127 (coalesced in c)
            sW[(rr << 7) + kk] = W[(size_t)(k0 + rr) * Dout + colBase + kk];
        }
        __syncthreads();
        #pragma unroll 8
        for (int kk = 0; kk < 128; ++kk) {
            const int rsw = ((rg ^ (kk & 7)) << 2);
            const float4 a0 = *(const float4*)&sA[(kk << 7) + rsw];
            const float4 a1 = *(const float4*)&sA[(kk << 7) + 64 + rsw];
            const float4 w0 = *(const float4*)&sW[(kk << 7) + (cg << 2)];
            const float4 w1 = *(const float4*)&sW[(kk << 7) + 64 + (cg << 2)];
            const float ar0[4] = {a0.x, a0.y, a0.z, a0.w};
            const float ar1[4] = {a1.x, a1.y, a1.z, a1.w};
            #pragma unroll
            for (int rr = 0; rr < 4; ++rr) {
                fma4(acc[0][0][rr], ar0[rr], w0);
                fma4(acc[0][1][rr], ar0[rr], w1);
                fma4(acc[1][0][rr], ar1[rr], w0);
                fma4(acc[1][1][rr], ar1[rr], w1);
            }
        }
    }

    #pragma unroll
    for (int ri = 0; ri < 2; ++ri) {
        #pragma unroll
        for (int rr = 0; rr < 4; ++rr) {
            int grow = rowBase + ri * 64 + (rg << 2) + rr;
            if (grow >= rows) continue;
            #pragma unroll
            for (int ci = 0; ci < 2; ++ci) {
                int gcol = colBase + ci * 64 + (cg << 2);
                float4 r = acc[ri][ci][rr];
                if (bias) {
                    const float4 bv = *(const float4*)&bias[gcol];
                    r.x += bv.x; r.y += bv.y; r.z += bv.z; r.w += bv.w;
                }
                if (ACT == 1) {
                    r.x = 0.5f * r.x * (1.f + erff(r.x * 0.70710678118654752f));
                    r.y = 0.5f * r.y * (1.f + erff(r.y * 0.70710678118654752f));
                    r.z = 0.5f * r.z * (1.f + erff(r.z * 0.70710678118654752f));
                    r.w = 0.5f * r.w * (1.f + erff(r.w * 0.70710678118654752f));
                } else if (ACT == 2) {
                    r.x = fmaxf(r.x, 0.f); r.y = fmaxf(r.y, 0.f);
                    r.z = fmaxf(r.z, 0.f); r.w = fmaxf(r.w, 0.f);
                }
                *(float4*)&out[(size_t)grow * Dout + gcol] = r;
            }
        }
    }
}

// ---------- small kernels ----------

// x = relu(LN(cat(xyz,attr) @ encW + encb))
__global__ void enc_kernel(const float* __restrict__ xyz, const float* __restrict__ attr,
                           const float* __restrict__ W, const float* __restrict__ b,
                           const float* __restrict__ g, const float* __restrict__ bb,
                           float* __restrict__ x) {
    int i = blockIdx.x, d = threadIdx.x;
    __shared__ float sin4[4];
    if (d < 3) sin4[d] = xyz[i * 3 + d];
    if (d == 3) sin4[3] = attr[i];
    __syncthreads();
    float y = b[d];
    #pragma unroll
    for (int kk = 0; kk < 4; ++kk) y += sin4[kk] * W[kk * DD + d];
    float s = y, s2 = y * y;
    redsum2_128(s, s2);
    float mean = s * (1.0f / DD);
    float var = s2 * (1.0f / DD) - mean * mean;
    float xn = (y - mean) * rsqrtf(var + 1e-5f) * g[d] + bb[d];
    x[i * DD + d] = fmaxf(xn, 0.f);
}

// t = relu(LN(rel @ W1 + b1)) per edge -> tbuf
__global__ void pos1_kernel(const float* __restrict__ xyz, const int* __restrict__ ei,
                            const float* __restrict__ W1, const float* __restrict__ b1,
                            const float* __restrict__ g, const float* __restrict__ bb,
                            float* __restrict__ tbuf, int nE) {
    int eid = blockIdx.x, d = threadIdx.x;
    __shared__ float srel[3];
    if (d < 3) {
        int s = ei[eid], t = ei[nE + eid];
        srel[d] = xyz[t * 3 + d] - xyz[s * 3 + d];
    }
    __syncthreads();
    float y = b1[d] + srel[0] * W1[d] + srel[1] * W1[DD + d] + srel[2] * W1[2 * DD + d];
    float s = y, s2 = y * y;
    redsum2_128(s, s2);
    float mean = s * (1.0f / DD);
    float var = s2 * (1.0f / DD) - mean * mean;
    tbuf[(size_t)eid * DD + d] = fmaxf((y - mean) * rsqrtf(var + 1e-5f) * g[d] + bb[d], 0.f);
}

// row r<128: W2We[r][d] = sum_k W2[r][k]*We[k][d]; row 128: b2We[d] = sum_k b2[k]*We[k][d]
__global__ void wcomb_kernel(const float* __restrict__ W2, const float* __restrict__ b2,
                             const float* __restrict__ We, float* __restrict__ W2We,
                             float* __restrict__ b2We) {
    int r = blockIdx.x, d = threadIdx.x;
    __shared__ float sa[DD];
    sa[d] = (r < DD) ? W2[r * DD + d] : b2[d];
    __syncthreads();
    float acc = 0.f;
    #pragma unroll 8
    for (int kk = 0; kk < DD; ++kk) acc += sa[kk] * We[kk * DD + d];
    if (r < DD) W2We[r * DD + d] = acc;
    else        b2We[d] = acc;
}

// ---------- CSR build ----------

__global__ void hist_kernel(const int* __restrict__ ei, int* __restrict__ deg, int E) {
    int e = blockIdx.x * blockDim.x + threadIdx.x;
    if (e < E) atomicAdd(&deg[ei[E + e]], 1);
}

__global__ void scan_kernel(const int* __restrict__ deg, int* __restrict__ ptr, int n) {
    __shared__ int buf[1024];
    __shared__ int carry_s;
    int t = threadIdx.x;
    if (t == 0) { carry_s = 0; ptr[0] = 0; }
    __syncthreads();
    for (int base = 0; base < n; base += 1024) {
        int i = base + t;
        buf[t] = (i < n) ? deg[i] : 0;
        __syncthreads();
        for (int off = 1; off < 1024; off <<= 1) {
            int add = (t >= off) ? buf[t - off] : 0;
            __syncthreads();
            buf[t] += add;
            __syncthreads();
        }
        int c = carry_s;
        if (i < n) ptr[i + 1] = c + buf[t];
        __syncthreads();
        if (t == 0) carry_s = c + buf[1023];
        __syncthreads();
    }
}

__global__ void scatter_kernel(const int* __restrict__ ei, const int* __restrict__ ptr,
                               int* __restrict__ cur, int* __restrict__ cs_src,
                               int* __restrict__ cs_eid, int E) {
    int e = blockIdx.x * blockDim.x + threadIdx.x;
    if (e >= E) return;
    int dstn = ei[E + e];
    int p = atomicAdd(&cur[dstn], 1);
    int slot = ptr[dstn] + p;
    cs_src[slot] = ei[e];
    cs_eid[slot] = e;
}

// ---------- fused attention aggregation (online softmax over in-edges) ----------
__global__ void agg_kernel(const float* __restrict__ q, const float* __restrict__ k,
                           const float* __restrict__ v, const float* __restrict__ ee,
                           const int* __restrict__ ptr, const int* __restrict__ cs_src,
                           const int* __restrict__ cs_eid, float* __restrict__ out) {
    int i = blockIdx.x, d = threadIdx.x;
    float qd = q[i * DD + d];
    float m = -INFINITY, s = 0.f, acc = 0.f;
    int beg = ptr[i], end = ptr[i + 1];
    for (int idx = beg; idx < end; ++idx) {
        int j = cs_src[idx];
        size_t eoff = (size_t)cs_eid[idx] * DD + d;
        float eed = ee[eoff];
        float kj = k[j * DD + d] + eed;
        float p = qd * kj;
        #pragma unroll
        for (int mm = 16; mm; mm >>= 1) p += __shfl_xor(p, mm);
        float al = p * 0.17677669529663687f;  // 1/sqrt(32)
        float nm = fmaxf(m, al);
        float cold = expf(m - nm);   // 0 on first edge (m=-inf)
        float w = expf(al - nm);
        s = s * cold + w;
        acc = acc * cold + (v[j * DD + d] + eed) * w;
        m = nm;
    }
    out[i * DD + d] = (s > 0.f) ? acc / s : 0.f;
}

// beta-gated skip + residual + LN1 (x updated in place)
__global__ void combine_kernel(const float* __restrict__ out, const float* __restrict__ r,
                               const float* __restrict__ Wb, const float* __restrict__ g1,
                               const float* __restrict__ b1, float* __restrict__ x) {
    int i = blockIdx.x, d = threadIdx.x;
    float od = out[i * DD + d], rd = r[i * DD + d];
    float part = od * Wb[d] + rd * Wb[DD + d] + (od - rd) * Wb[2 * DD + d];
    float dummy = 0.f;
    redsum2_128(part, dummy);
    float beta = 1.f / (1.f + expf(-part));
    float comb = beta * rd + (1.f - beta) * od;
    float t = comb + x[i * DD + d];
    float s = t, s2 = t * t;
    redsum2_128(s, s2);
    float mean = s * (1.0f / DD);
    float var = s2 * (1.0f / DD) - mean * mean;
    x[i * DD + d] = (t - mean) * rsqrtf(var + 1e-5f) * g1[d] + b1[d];
}

// x = LN(h2 + x)
__global__ void ln2_kernel(const float* __restrict__ h2, const float* __restrict__ g,
                           const float* __restrict__ b, float* __restrict__ x) {
    int i = blockIdx.x, d = threadIdx.x;
    float t = h2[i * DD + d] + x[i * DD + d];
    float s = t, s2 = t * t;
    redsum2_128(s, s2);
    float mean = s * (1.0f / DD);
    float var = s2 * (1.0f / DD) - mean * mean;
    x[i * DD + d] = (t - mean) * rsqrtf(var + 1e-5f) * g[d] + b[d];
}

// cls and box heads
__global__ void heads_kernel(const float* __restrict__ x,
                             const float* __restrict__ cW1, const float* __restrict__ cb1,
                             const float* __restrict__ cW2, const float* __restrict__ cb2,
                             const float* __restrict__ bW1, const float* __restrict__ bb1,
                             const float* __restrict__ bW2, const float* __restrict__ bb2,
                             float* __restrict__ outc, float* __restrict__ outb) {
    int i = blockIdx.x, d = threadIdx.x;  // 128 threads
    __shared__ float sx[DD], st[128];
    sx[d] = x[i * DD + d];
    __syncthreads();
    float a;
    if (d < 64) {
        a = cb1[d];
        #pragma unroll 8
        for (int kk = 0; kk < DD; ++kk) a += sx[kk] * cW1[kk * 64 + d];
    } else {
        int dd = d - 64;
        a = bb1[dd];
        #pragma unroll 8
        for (int kk = 0; kk < DD; ++kk) a += sx[kk] * bW1[kk * 64 + dd];
    }
    st[d] = fmaxf(a, 0.f);
    __syncthreads();
    if (d < 4) {
        float o = cb2[d];
        #pragma unroll
        for (int kk = 0; kk < 64; ++kk) o += st[kk] * cW2[kk * 4 + d];
        outc[i * 4 + d] = o;
    } else if (d >= 64 && d < 71) {
        int j = d - 64;
        float o = bb2[j];
        #pragma unroll
        for (int kk = 0; kk < 64; ++kk) o += st[64 + kk] * bW2[kk * 7 + j];
        outb[i * 7 + j] = o;
    }
}

extern "C" void kernel_launch(void* const* d_in, const int* in_sizes, int n_in,
                              void* d_out, int out_size, void* d_ws, size_t ws_size,
                              hipStream_t stream) {
    const float* xyz   = (const float*)d_in[0];
    const float* attr  = (const float*)d_in[1];
    const int*   ei    = (const int*)d_in[2];
    const float* encW  = (const float*)d_in[3];
    const float* encb  = (const float*)d_in[4];
    const float* encg  = (const float*)d_in[5];
    const float* encbb = (const float*)d_in[6];
    const float* posW1 = (const float*)d_in[7];
    const float* posb1 = (const float*)d_in[8];
    const float* posg  = (const float*)d_in[9];
    const float* posbb = (const float*)d_in[10];
    const float* posW2 = (const float*)d_in[11];
    const float* posb2 = (const float*)d_in[12];
    const float* Wq    = (const float*)d_in[13];
    const float* bq    = (const float*)d_in[14];
    const float* Wk    = (const float*)d_in[15];
    const float* bk    = (const float*)d_in[16];
    const float* Wv    = (const float*)d_in[17];
    const float* bv    = (const float*)d_in[18];
    const float* We    = (const float*)d_in[19];
    const float* Wskip = (const float*)d_in[20];
    const float* bskip = (const float*)d_in[21];
    const float* Wbeta = (const float*)d_in[22];
    const float* ln1g  = (const float*)d_in[23];
    const float* ln1b  = (const float*)d_in[24];
    const float* ln2g  = (const float*)d_in[25];
    const float* ln2b  = (const float*)d_in[26];
    const float* fW1   = (const float*)d_in[27];
    const float* fb1   = (const float*)d_in[28];
    const float* fW2   = (const float*)d_in[29];
    const float* fb2   = (const float*)d_in[30];
    const float* cW1   = (const float*)d_in[31];
    const float* cb1   = (const float*)d_in[32];
    const float* cW2   = (const float*)d_in[33];
    const float* cb2   = (const float*)d_in[34];
    const float* bW1   = (const float*)d_in[35];
    const float* bb1   = (const float*)d_in[36];
    const float* bW2   = (const float*)d_in[37];
    const float* bb2   = (const float*)d_in[38];

    const int N = in_sizes[0] / 3;
    const int E = in_sizes[2] / 2;

    // workspace carve-up (must stay under proven ws budget ~209 MB)
    size_t off = 0;
    auto alloc = [&](size_t nelem) {
        char* p = (char*)d_ws + off;
        off += nelem * sizeof(float);
        return (float*)p;
    };
    float* x     = alloc((size_t)N * DD);
    float* q     = alloc((size_t)N * DD);
    float* k     = alloc((size_t)N * DD);
    float* v     = alloc((size_t)N * DD);
    float* r     = alloc((size_t)N * DD);
    float* outb  = alloc((size_t)N * DD);          // also h2
    float* h1    = alloc((size_t)N * 256);
    float* big   = alloc((size_t)E * DD);          // tbuf, then in-place -> ee
    float* W2We  = alloc(DD * DD);
    float* b2We  = alloc(DD);
    int* deg     = (int*)alloc(N);
    int* ptr     = (int*)alloc(N + 1);
    int* cur     = (int*)alloc(N);
    int* cs_src  = (int*)alloc(E);
    int* cs_eid  = (int*)alloc(E);

    const int rtN = (N + 127) / 128;     // row tiles for N
    const int rtE = (E + 127) / 128;     // row tiles for E

    // ---- input encoder + CSR build ----
    enc_kernel<<<N, DD, 0, stream>>>(xyz, attr, encW, encb, encg, encbb, x);
    hipMemsetAsync(deg, 0, N * sizeof(int), stream);
    hipMemsetAsync(cur, 0, N * sizeof(int), stream);
    hist_kernel<<<(E + 255) / 256, 256, 0, stream>>>(ei, deg, E);
    scan_kernel<<<1, 1024, 0, stream>>>(deg, ptr, N);
    scatter_kernel<<<(E + 255) / 256, 256, 0, stream>>>(ei, ptr, cur, cs_src, cs_eid, E);

    for (int l = 0; l < 3; ++l) {
        const float* Wq_l = Wq + (size_t)l * DD * DD;
        const float* Wk_l = Wk + (size_t)l * DD * DD;
        const float* Wv_l = Wv + (size_t)l * DD * DD;
        const float* We_l = We + (size_t)l * DD * DD;
        const float* Ws_l = Wskip + (size_t)l * DD * DD;
        const float* Wb_l = Wbeta + (size_t)l * 3 * DD;
        const float* fW1_l = fW1 + (size_t)l * DD * 256;
        const float* fW2_l = fW2 + (size_t)l * 256 * DD;

        // edge features: t = relu(LN(rel@W1+b1)); ee = t @ (W2@We_l) + b2@We_l  (in place)
        pos1_kernel<<<E, DD, 0, stream>>>(xyz, ei, posW1, posb1, posg, posbb, big, E);
        wcomb_kernel<<<DD + 1, DD, 0, stream>>>(posW2, posb2, We_l, W2We, b2We);
        gemm_kernel<0><<<dim3(rtE, 1), 256, 0, stream>>>(big, W2We, b2We, big, E, DD, DD);

        // q,k,v,r
        gemm_kernel<0><<<dim3(rtN, 1), 256, 0, stream>>>(x, Wq_l, bq + l * DD, q, N, DD, DD);
        gemm_kernel<0><<<dim3(rtN, 1), 256, 0, stream>>>(x, Wk_l, bk + l * DD, k, N, DD, DD);
        gemm_kernel<0><<<dim3(rtN, 1), 256, 0, stream>>>(x, Wv_l, bv + l * DD, v, N, DD, DD);
        gemm_kernel<0><<<dim3(rtN, 1), 256, 0, stream>>>(x, Ws_l, bskip + l * DD, r, N, DD, DD);

        // fused scatter-softmax aggregation
        agg_kernel<<<N, DD, 0, stream>>>(q, k, v, big, ptr, cs_src, cs_eid, outb);

        // beta gate + residual + LN1
        combine_kernel<<<N, DD, 0, stream>>>(outb, r, Wb_l, ln1g + l * DD, ln1b + l * DD, x);

        // FFN
        gemm_kernel<1><<<dim3(rtN, 2), 256, 0, stream>>>(x, fW1_l, fb1 + l * 256, h1, N, DD, 256);
        gemm_kernel<0><<<dim3(rtN, 1), 256, 0, stream>>>(h1, fW2_l, fb2 + l * DD, outb, N, 256, DD);
        ln2_kernel<<<N, DD, 0, stream>>>(outb, ln2g + l * DD, ln2b + l * DD, x);
    }

    float* outc  = (float*)d_out;
    float* outbx = (float*)d_out + (size_t)N * 4;
    heads_kernel<<<N, DD, 0, stream>>>(x, cW1, cb1, cW2, cb2, bW1, bb1, bW2, bb2, outc, outbx);
}

// Round 3
// 928.967 us; speedup vs baseline: 4.9318x; 2.7117x over previous
//
#include <hip/hip_runtime.h>
#include <hip/hip_bf16.h>
#include <math.h>

#define DD 128
#define HH 4

typedef __attribute__((ext_vector_type(8))) short short8;
typedef __attribute__((ext_vector_type(4))) float f32x4;

// ---------- helpers ----------

__device__ __forceinline__ unsigned short f2b(float f) {
    unsigned u = __float_as_uint(f);
    return (unsigned short)((u + 0x7FFFu + ((u >> 16) & 1u)) >> 16);
}
__device__ __forceinline__ float b2f(unsigned short b) {
    return __uint_as_float(((unsigned)b) << 16);
}

__device__ __forceinline__ void redsum2_128(float& a, float& b) {
    #pragma unroll
    for (int off = 32; off > 0; off >>= 1) {
        a += __shfl_down(a, off);
        b += __shfl_down(b, off);
    }
    __shared__ float sa[2], sb[2];
    int w = threadIdx.x >> 6;
    if ((threadIdx.x & 63) == 0) { sa[w] = a; sb[w] = b; }
    __syncthreads();
    a = sa[0] + sa[1];
    b = sb[0] + sb[1];
    __syncthreads();
}

// ---------- MFMA GEMM ----------
// out[rows,Dout](+colBase tile) = act(A[rows,K] @ W[K,Dout] + bias)
// A row-major (f32 or bf16 per ABF), W row-major f32, out f32 or bf16 per OBF.
// Block: 256 thr = 4 waves; each wave 16 rows; tile 64 rows x 128 cols.
// B staged transposed+swizzled in LDS as bf16: Bt[n][k], u32idx=(n*64+k/2)^((n&7)<<2).
template <int ACT, bool ABF, bool OBF>
__global__ __launch_bounds__(256) void mgemm(
        const void* __restrict__ A_, const float* __restrict__ W,
        const float* __restrict__ bias, void* __restrict__ out_,
        int rows, int K, int Dout) {
    __shared__ unsigned Bt[128 * 64];  // 32 KB
    const int t = threadIdx.x;
    const int rowBase = blockIdx.x << 6;
    const int colBase = blockIdx.y << 7;
    const int lane = t & 63, wid = t >> 6;

    f32x4 acc[8];
    #pragma unroll
    for (int i = 0; i < 8; ++i) acc[i] = (f32x4){0.f, 0.f, 0.f, 0.f};

    int arow = rowBase + wid * 16 + (lane & 15);
    if (arow > rows - 1) arow = rows - 1;   // clamp (stores are guarded)
    const int kqo = (lane >> 4) * 8;

    for (int k0 = 0; k0 < K; k0 += 128) {
        if (k0) __syncthreads();
        // stage W[k0..k0+127][colBase..+127] -> Bt (transposed, bf16, swizzled)
        #pragma unroll 8
        for (int it = 0; it < 32; ++it) {
            int idx = it * 256 + t;          // 0..8191
            int n = idx & 127, kp = idx >> 7;  // kp: pair index 0..63
            int krow = k0 + kp * 2;
            float w0 = W[(size_t)krow * Dout + colBase + n];
            float w1 = W[(size_t)(krow + 1) * Dout + colBase + n];
            unsigned pk = (unsigned)f2b(w0) | ((unsigned)f2b(w1) << 16);
            Bt[((n << 6) + kp) ^ ((n & 7) << 2)] = pk;
        }
        __syncthreads();
        // A fragments: lane holds row (lane&15), k = kc*32 + (lane>>4)*8 + 0..7
        short8 a[4];
        #pragma unroll
        for (int kc = 0; kc < 4; ++kc) {
            int kk = k0 + kc * 32 + kqo;
            if (ABF) {
                a[kc] = *(const short8*)((const unsigned short*)A_ + (size_t)arow * K + kk);
            } else {
                const float* Af = (const float*)A_ + (size_t)arow * K + kk;
                float4 lo = *(const float4*)Af;
                float4 hi = *(const float4*)(Af + 4);
                union { short8 s; unsigned short u[8]; } cv;
                cv.u[0] = f2b(lo.x); cv.u[1] = f2b(lo.y); cv.u[2] = f2b(lo.z); cv.u[3] = f2b(lo.w);
                cv.u[4] = f2b(hi.x); cv.u[5] = f2b(hi.y); cv.u[6] = f2b(hi.z); cv.u[7] = f2b(hi.w);
                a[kc] = cv.s;
            }
        }
        // MFMA over 8 col-groups x 4 k-chunks
        #pragma unroll
        for (int ng = 0; ng < 8; ++ng) {
            int col = ng * 16 + (lane & 15);
            #pragma unroll
            for (int kc = 0; kc < 4; ++kc) {
                int kidx = kc * 16 + (lane >> 4) * 4;  // u32 index (=k/2), 4-aligned
                const short8 b = *(const short8*)((const char*)Bt +
                        ((((col << 6) + kidx) ^ ((col & 7) << 2)) << 2));
                acc[ng] = __builtin_amdgcn_mfma_f32_16x16x32_bf16(a[kc], b, acc[ng], 0, 0, 0);
            }
        }
    }
    // epilogue: D col = lane&15 (+16*ng), row = (lane>>4)*4 + r (+16*wid)
    #pragma unroll
    for (int ng = 0; ng < 8; ++ng) {
        int gcol = colBase + ng * 16 + (lane & 15);
        float bv = bias ? bias[gcol] : 0.f;
        #pragma unroll
        for (int r = 0; r < 4; ++r) {
            int grow = rowBase + wid * 16 + (lane >> 4) * 4 + r;
            if (grow >= rows) continue;
            float val = acc[ng][r] + bv;
            if (ACT == 1) val = 0.5f * val * (1.f + erff(val * 0.70710678118654752f));
            else if (ACT == 2) val = fmaxf(val, 0.f);
            if (OBF) ((unsigned short*)out_)[(size_t)grow * Dout + gcol] = f2b(val);
            else     ((float*)out_)[(size_t)grow * Dout + gcol] = val;
        }
    }
}

// ---------- small kernels ----------

__global__ void enc_kernel(const float* __restrict__ xyz, const float* __restrict__ attr,
                           const float* __restrict__ W, const float* __restrict__ b,
                           const float* __restrict__ g, const float* __restrict__ bb,
                           float* __restrict__ x) {
    int i = blockIdx.x, d = threadIdx.x;
    __shared__ float sin4[4];
    if (d < 3) sin4[d] = xyz[i * 3 + d];
    if (d == 3) sin4[3] = attr[i];
    __syncthreads();
    float y = b[d];
    #pragma unroll
    for (int kk = 0; kk < 4; ++kk) y += sin4[kk] * W[kk * DD + d];
    float s = y, s2 = y * y;
    redsum2_128(s, s2);
    float mean = s * (1.0f / DD);
    float var = s2 * (1.0f / DD) - mean * mean;
    float xn = (y - mean) * rsqrtf(var + 1e-5f) * g[d] + bb[d];
    x[i * DD + d] = fmaxf(xn, 0.f);
}

// t = relu(LN(rel @ W1 + b1)) per edge -> bf16 tbuf  (runs ONCE)
__global__ void pos1_kernel(const float* __restrict__ xyz, const int* __restrict__ ei,
                            const float* __restrict__ W1, const float* __restrict__ b1,
                            const float* __restrict__ g, const float* __restrict__ bb,
                            unsigned short* __restrict__ tbuf, int nE) {
    int eid = blockIdx.x, d = threadIdx.x;
    __shared__ float srel[3];
    if (d < 3) {
        int s = ei[eid], t = ei[nE + eid];
        srel[d] = xyz[t * 3 + d] - xyz[s * 3 + d];
    }
    __syncthreads();
    float y = b1[d] + srel[0] * W1[d] + srel[1] * W1[DD + d] + srel[2] * W1[2 * DD + d];
    float s = y, s2 = y * y;
    redsum2_128(s, s2);
    float mean = s * (1.0f / DD);
    float var = s2 * (1.0f / DD) - mean * mean;
    float v = fmaxf((y - mean) * rsqrtf(var + 1e-5f) * g[d] + bb[d], 0.f);
    tbuf[(size_t)eid * DD + d] = f2b(v);
}

// W2We[r][d] = sum_k W2[r][k]*We[k][d]; row 128: b2We[d]
__global__ void wcomb_kernel(const float* __restrict__ W2, const float* __restrict__ b2,
                             const float* __restrict__ We, float* __restrict__ W2We,
                             float* __restrict__ b2We) {
    int r = blockIdx.x, d = threadIdx.x;
    __shared__ float sa[DD];
    sa[d] = (r < DD) ? W2[r * DD + d] : b2[d];
    __syncthreads();
    float acc = 0.f;
    #pragma unroll 8
    for (int kk = 0; kk < DD; ++kk) acc += sa[kk] * We[kk * DD + d];
    if (r < DD) W2We[r * DD + d] = acc;
    else        b2We[d] = acc;
}

// ---------- CSR build ----------

__global__ void hist_kernel(const int* __restrict__ ei, int* __restrict__ deg, int E) {
    int e = blockIdx.x * blockDim.x + threadIdx.x;
    if (e < E) atomicAdd(&deg[ei[E + e]], 1);
}

__global__ void scan_kernel(const int* __restrict__ deg, int* __restrict__ ptr, int n) {
    __shared__ int buf[1024];
    __shared__ int carry_s;
    int t = threadIdx.x;
    if (t == 0) { carry_s = 0; ptr[0] = 0; }
    __syncthreads();
    for (int base = 0; base < n; base += 1024) {
        int i = base + t;
        buf[t] = (i < n) ? deg[i] : 0;
        __syncthreads();
        for (int off = 1; off < 1024; off <<= 1) {
            int add = (t >= off) ? buf[t - off] : 0;
            __syncthreads();
            buf[t] += add;
            __syncthreads();
        }
        int c = carry_s;
        if (i < n) ptr[i + 1] = c + buf[t];
        __syncthreads();
        if (t == 0) carry_s = c + buf[1023];
        __syncthreads();
    }
}

__global__ void scatter_kernel(const int* __restrict__ ei, const int* __restrict__ ptr,
                               int* __restrict__ cur, int* __restrict__ cs_src,
                               int* __restrict__ cs_eid, int E) {
    int e = blockIdx.x * blockDim.x + threadIdx.x;
    if (e >= E) return;
    int dstn = ei[E + e];
    int p = atomicAdd(&cur[dstn], 1);
    int slot = ptr[dstn] + p;
    cs_src[slot] = ei[e];
    cs_eid[slot] = e;
}

// ---------- fused attention aggregation (online softmax over in-edges) ----------
__global__ void agg_kernel(const float* __restrict__ q, const float* __restrict__ k,
                           const float* __restrict__ v, const unsigned short* __restrict__ ee,
                           const int* __restrict__ ptr, const int* __restrict__ cs_src,
                           const int* __restrict__ cs_eid, float* __restrict__ out) {
    int i = blockIdx.x, d = threadIdx.x;
    float qd = q[i * DD + d];
    float m = -INFINITY, s = 0.f, acc = 0.f;
    int beg = ptr[i], end = ptr[i + 1];
    for (int idx = beg; idx < end; ++idx) {
        int j = cs_src[idx];
        size_t eoff = (size_t)cs_eid[idx] * DD + d;
        float eed = b2f(ee[eoff]);
        float kj = k[j * DD + d] + eed;
        float p = qd * kj;
        #pragma unroll
        for (int mm = 16; mm; mm >>= 1) p += __shfl_xor(p, mm);
        float al = p * 0.17677669529663687f;  // 1/sqrt(32)
        float nm = fmaxf(m, al);
        float cold = expf(m - nm);
        float w = expf(al - nm);
        s = s * cold + w;
        acc = acc * cold + (v[j * DD + d] + eed) * w;
        m = nm;
    }
    out[i * DD + d] = (s > 0.f) ? acc / s : 0.f;
}

// beta-gated skip + residual + LN1 (x updated in place)
__global__ void combine_kernel(const float* __restrict__ out, const float* __restrict__ r,
                               const float* __restrict__ Wb, const float* __restrict__ g1,
                               const float* __restrict__ b1, float* __restrict__ x) {
    int i = blockIdx.x, d = threadIdx.x;
    float od = out[i * DD + d], rd = r[i * DD + d];
    float part = od * Wb[d] + rd * Wb[DD + d] + (od - rd) * Wb[2 * DD + d];
    float dummy = 0.f;
    redsum2_128(part, dummy);
    float beta = 1.f / (1.f + expf(-part));
    float comb = beta * rd + (1.f - beta) * od;
    float t = comb + x[i * DD + d];
    float s = t, s2 = t * t;
    redsum2_128(s, s2);
    float mean = s * (1.0f / DD);
    float var = s2 * (1.0f / DD) - mean * mean;
    x[i * DD + d] = (t - mean) * rsqrtf(var + 1e-5f) * g1[d] + b1[d];
}

// x = LN(h2 + x)
__global__ void ln2_kernel(const float* __restrict__ h2, const float* __restrict__ g,
                           const float* __restrict__ b, float* __restrict__ x) {
    int i = blockIdx.x, d = threadIdx.x;
    float t = h2[i * DD + d] + x[i * DD + d];
    float s = t, s2 = t * t;
    redsum2_128(s, s2);
    float mean = s * (1.0f / DD);
    float var = s2 * (1.0f / DD) - mean * mean;
    x[i * DD + d] = (t - mean) * rsqrtf(var + 1e-5f) * g[d] + b[d];
}

// cls and box heads
__global__ void heads_kernel(const float* __restrict__ x,
                             const float* __restrict__ cW1, const float* __restrict__ cb1,
                             const float* __restrict__ cW2, const float* __restrict__ cb2,
                             const float* __restrict__ bW1, const float* __restrict__ bb1,
                             const float* __restrict__ bW2, const float* __restrict__ bb2,
                             float* __restrict__ outc, float* __restrict__ outb) {
    int i = blockIdx.x, d = threadIdx.x;  // 128 threads
    __shared__ float sx[DD], st[128];
    sx[d] = x[i * DD + d];
    __syncthreads();
    float a;
    if (d < 64) {
        a = cb1[d];
        #pragma unroll 8
        for (int kk = 0; kk < DD; ++kk) a += sx[kk] * cW1[kk * 64 + d];
    } else {
        int dd = d - 64;
        a = bb1[dd];
        #pragma unroll 8
        for (int kk = 0; kk < DD; ++kk) a += sx[kk] * bW1[kk * 64 + dd];
    }
    st[d] = fmaxf(a, 0.f);
    __syncthreads();
    if (d < 4) {
        float o = cb2[d];
        #pragma unroll
        for (int kk = 0; kk < 64; ++kk) o += st[kk] * cW2[kk * 4 + d];
        outc[i * 4 + d] = o;
    } else if (d >= 64 && d < 71) {
        int j = d - 64;
        float o = bb2[j];
        #pragma unroll
        for (int kk = 0; kk < 64; ++kk) o += st[64 + kk] * bW2[kk * 7 + j];
        outb[i * 7 + j] = o;
    }
}

extern "C" void kernel_launch(void* const* d_in, const int* in_sizes, int n_in,
                              void* d_out, int out_size, void* d_ws, size_t ws_size,
                              hipStream_t stream) {
    const float* xyz   = (const float*)d_in[0];
    const float* attr  = (const float*)d_in[1];
    const int*   ei    = (const int*)d_in[2];
    const float* encW  = (const float*)d_in[3];
    const float* encb  = (const float*)d_in[4];
    const float* encg  = (const float*)d_in[5];
    const float* encbb = (const float*)d_in[6];
    const float* posW1 = (const float*)d_in[7];
    const float* posb1 = (const float*)d_in[8];
    const float* posg  = (const float*)d_in[9];
    const float* posbb = (const float*)d_in[10];
    const float* posW2 = (const float*)d_in[11];
    const float* posb2 = (const float*)d_in[12];
    const float* Wq    = (const float*)d_in[13];
    const float* bq    = (const float*)d_in[14];
    const float* Wk    = (const float*)d_in[15];
    const float* bk    = (const float*)d_in[16];
    const float* Wv    = (const float*)d_in[17];
    const float* bv    = (const float*)d_in[18];
    const float* We    = (const float*)d_in[19];
    const float* Wskip = (const float*)d_in[20];
    const float* bskip = (const float*)d_in[21];
    const float* Wbeta = (const float*)d_in[22];
    const float* ln1g  = (const float*)d_in[23];
    const float* ln1b  = (const float*)d_in[24];
    const float* ln2g  = (const float*)d_in[25];
    const float* ln2b  = (const float*)d_in[26];
    const float* fW1   = (const float*)d_in[27];
    const float* fb1   = (const float*)d_in[28];
    const float* fW2   = (const float*)d_in[29];
    const float* fb2   = (const float*)d_in[30];
    const float* cW1   = (const float*)d_in[31];
    const float* cb1   = (const float*)d_in[32];
    const float* cW2   = (const float*)d_in[33];
    const float* cb2   = (const float*)d_in[34];
    const float* bW1   = (const float*)d_in[35];
    const float* bb1   = (const float*)d_in[36];
    const float* bW2   = (const float*)d_in[37];
    const float* bb2   = (const float*)d_in[38];

    const int N = in_sizes[0] / 3;
    const int E = in_sizes[2] / 2;

    // workspace carve-up (float units; keep 16B alignment: float allocs first)
    size_t off = 0;
    auto alloc = [&](size_t nelem) {
        char* p = (char*)d_ws + off;
        off += nelem * sizeof(float);
        return (float*)p;
    };
    float* x     = alloc((size_t)N * DD);
    float* q     = alloc((size_t)N * DD);
    float* k     = alloc((size_t)N * DD);
    float* v     = alloc((size_t)N * DD);
    float* r     = alloc((size_t)N * DD);
    float* outb  = alloc((size_t)N * DD);          // agg out / h2
    unsigned short* h1 = (unsigned short*)alloc((size_t)N * 128);  // N*256 bf16
    unsigned short* tb = (unsigned short*)alloc((size_t)E * 64);   // E*128 bf16
    unsigned short* eeb = (unsigned short*)alloc((size_t)E * 64);  // E*128 bf16
    float* W2We  = alloc(DD * DD);
    float* b2We  = alloc(DD);
    int* deg     = (int*)alloc(N);
    int* ptr     = (int*)alloc(N + 1);
    int* cur     = (int*)alloc(N);
    int* cs_src  = (int*)alloc(E);
    int* cs_eid  = (int*)alloc(E);

    const int rtN = (N + 63) / 64;   // 64-row tiles
    const int rtE = (E + 63) / 64;

    // ---- input encoder + edge MLP stage 1 + CSR build (once) ----
    enc_kernel<<<N, DD, 0, stream>>>(xyz, attr, encW, encb, encg, encbb, x);
    pos1_kernel<<<E, DD, 0, stream>>>(xyz, ei, posW1, posb1, posg, posbb, tb, E);
    hipMemsetAsync(deg, 0, N * sizeof(int), stream);
    hipMemsetAsync(cur, 0, N * sizeof(int), stream);
    hist_kernel<<<(E + 255) / 256, 256, 0, stream>>>(ei, deg, E);
    scan_kernel<<<1, 1024, 0, stream>>>(deg, ptr, N);
    scatter_kernel<<<(E + 255) / 256, 256, 0, stream>>>(ei, ptr, cur, cs_src, cs_eid, E);

    for (int l = 0; l < 3; ++l) {
        const float* Wq_l = Wq + (size_t)l * DD * DD;
        const float* Wk_l = Wk + (size_t)l * DD * DD;
        const float* Wv_l = Wv + (size_t)l * DD * DD;
        const float* We_l = We + (size_t)l * DD * DD;
        const float* Ws_l = Wskip + (size_t)l * DD * DD;
        const float* Wb_l = Wbeta + (size_t)l * 3 * DD;
        const float* fW1_l = fW1 + (size_t)l * DD * 256;
        const float* fW2_l = fW2 + (size_t)l * 256 * DD;

        // folded edge weight, then ee = t @ W2We + b2We   (bf16 in, bf16 out)
        wcomb_kernel<<<DD + 1, DD, 0, stream>>>(posW2, posb2, We_l, W2We, b2We);
        mgemm<0, true, true><<<dim3(rtE, 1), 256, 0, stream>>>(tb, W2We, b2We, eeb, E, DD, DD);

        // q,k,v,r (f32 A, f32 out)
        mgemm<0, false, false><<<dim3(rtN, 1), 256, 0, stream>>>(x, Wq_l, bq + l * DD, q, N, DD, DD);
        mgemm<0, false, false><<<dim3(rtN, 1), 256, 0, stream>>>(x, Wk_l, bk + l * DD, k, N, DD, DD);
        mgemm<0, false, false><<<dim3(rtN, 1), 256, 0, stream>>>(x, Wv_l, bv + l * DD, v, N, DD, DD);
        mgemm<0, false, false><<<dim3(rtN, 1), 256, 0, stream>>>(x, Ws_l, bskip + l * DD, r, N, DD, DD);

        // fused scatter-softmax aggregation
        agg_kernel<<<N, DD, 0, stream>>>(q, k, v, eeb, ptr, cs_src, cs_eid, outb);

        // beta gate + residual + LN1
        combine_kernel<<<N, DD, 0, stream>>>(outb, r, Wb_l, ln1g + l * DD, ln1b + l * DD, x);

        // FFN: h1 = gelu(x@fW1+fb1) bf16 ; h2 = h1@fW2+fb2 ; x = LN(h2+x)
        mgemm<1, false, true><<<dim3(rtN, 2), 256, 0, stream>>>(x, fW1_l, fb1 + l * 256, h1, N, DD, 256);
        mgemm<0, true, false><<<dim3(rtN, 1), 256, 0, stream>>>(h1, fW2_l, fb2 + l * DD, outb, N, 256, DD);
        ln2_kernel<<<N, DD, 0, stream>>>(outb, ln2g + l * DD, ln2b + l * DD, x);
    }

    float* outc  = (float*)d_out;
    float* outbx = (float*)d_out + (size_t)N * 4;
    heads_kernel<<<N, DD, 0, stream>>>(x, cW1, cb1, cW2, cb2, bW1, bb1, bW2, bb2, outc, outbx);
}

// Round 4
// 785.809 us; speedup vs baseline: 5.8303x; 1.1822x over previous
//
#include <hip/hip_runtime.h>
#include <hip/hip_bf16.h>
#include <math.h>

#define DD 128
#define HH 4

typedef __attribute__((ext_vector_type(8))) short short8;
typedef __attribute__((ext_vector_type(4))) float f32x4;

// ---------- helpers ----------

__device__ __forceinline__ unsigned short f2b(float f) {
    unsigned u = __float_as_uint(f);
    return (unsigned short)((u + 0x7FFFu + ((u >> 16) & 1u)) >> 16);
}
__device__ __forceinline__ float b2f(unsigned short b) {
    return __uint_as_float(((unsigned)b) << 16);
}

__device__ __forceinline__ void redsum2_128(float& a, float& b) {
    #pragma unroll
    for (int off = 32; off > 0; off >>= 1) {
        a += __shfl_down(a, off);
        b += __shfl_down(b, off);
    }
    __shared__ float sa[2], sb[2];
    int w = threadIdx.x >> 6;
    if ((threadIdx.x & 63) == 0) { sa[w] = a; sb[w] = b; }
    __syncthreads();
    a = sa[0] + sa[1];
    b = sb[0] + sb[1];
    __syncthreads();
}

// ---------- MFMA GEMM (generic) ----------
// out[rows,Dout](col tile by blockIdx.y) = act(A[rows,K] @ W[K,Dout] + bias)
// Block: 256 thr = 4 waves; wave = 16 rows; tile 64x128.
template <int ACT, bool ABF, bool OBF>
__global__ __launch_bounds__(256) void mgemm(
        const void* __restrict__ A_, const float* __restrict__ W,
        const float* __restrict__ bias, void* __restrict__ out_,
        int rows, int K, int Dout) {
    __shared__ unsigned Bt[128 * 64];  // 32 KB
    const int t = threadIdx.x;
    const int rowBase = blockIdx.x << 6;
    const int colBase = blockIdx.y << 7;
    const int lane = t & 63, wid = t >> 6;

    f32x4 acc[8];
    #pragma unroll
    for (int i = 0; i < 8; ++i) acc[i] = (f32x4){0.f, 0.f, 0.f, 0.f};

    int arow = rowBase + wid * 16 + (lane & 15);
    if (arow > rows - 1) arow = rows - 1;
    const int kqo = (lane >> 4) * 8;

    for (int k0 = 0; k0 < K; k0 += 128) {
        if (k0) __syncthreads();
        #pragma unroll 8
        for (int it = 0; it < 32; ++it) {
            int idx = it * 256 + t;
            int n = idx & 127, kp = idx >> 7;
            int krow = k0 + kp * 2;
            float w0 = W[(size_t)krow * Dout + colBase + n];
            float w1 = W[(size_t)(krow + 1) * Dout + colBase + n];
            Bt[((n << 6) + kp) ^ ((n & 7) << 2)] = (unsigned)f2b(w0) | ((unsigned)f2b(w1) << 16);
        }
        __syncthreads();
        short8 a[4];
        #pragma unroll
        for (int kc = 0; kc < 4; ++kc) {
            int kk = k0 + kc * 32 + kqo;
            if (ABF) {
                a[kc] = *(const short8*)((const unsigned short*)A_ + (size_t)arow * K + kk);
            } else {
                const float* Af = (const float*)A_ + (size_t)arow * K + kk;
                float4 lo = *(const float4*)Af;
                float4 hi = *(const float4*)(Af + 4);
                union { short8 s; unsigned short u[8]; } cv;
                cv.u[0] = f2b(lo.x); cv.u[1] = f2b(lo.y); cv.u[2] = f2b(lo.z); cv.u[3] = f2b(lo.w);
                cv.u[4] = f2b(hi.x); cv.u[5] = f2b(hi.y); cv.u[6] = f2b(hi.z); cv.u[7] = f2b(hi.w);
                a[kc] = cv.s;
            }
        }
        #pragma unroll
        for (int ng = 0; ng < 8; ++ng) {
            int col = ng * 16 + (lane & 15);
            #pragma unroll
            for (int kc = 0; kc < 4; ++kc) {
                int kidx = kc * 16 + (lane >> 4) * 4;
                const short8 b = *(const short8*)((const char*)Bt +
                        ((((col << 6) + kidx) ^ ((col & 7) << 2)) << 2));
                acc[ng] = __builtin_amdgcn_mfma_f32_16x16x32_bf16(a[kc], b, acc[ng], 0, 0, 0);
            }
        }
    }
    #pragma unroll
    for (int ng = 0; ng < 8; ++ng) {
        int gcol = colBase + ng * 16 + (lane & 15);
        float bv = bias ? bias[gcol] : 0.f;
        #pragma unroll
        for (int r = 0; r < 4; ++r) {
            int grow = rowBase + wid * 16 + (lane >> 4) * 4 + r;
            if (grow >= rows) continue;
            float val = acc[ng][r] + bv;
            if (ACT == 1) val = 0.5f * val * (1.f + erff(val * 0.70710678118654752f));
            else if (ACT == 2) val = fmaxf(val, 0.f);
            if (OBF) ((unsigned short*)out_)[(size_t)grow * Dout + gcol] = f2b(val);
            else     ((float*)out_)[(size_t)grow * Dout + gcol] = val;
        }
    }
}

// ---------- fused q,k,v GEMM: blockIdx.y selects weight; out bf16 [rows][384] ----------
struct QKVW { const float* W[3]; const float* b[3]; };

__global__ __launch_bounds__(256) void mgemm_qkv(
        const float* __restrict__ x, QKVW wp, unsigned short* __restrict__ qkv, int rows) {
    __shared__ unsigned Bt[128 * 64];
    const float* W = wp.W[blockIdx.y];
    const float* bias = wp.b[blockIdx.y];
    const int t = threadIdx.x;
    const int rowBase = blockIdx.x << 6;
    const int lane = t & 63, wid = t >> 6;

    f32x4 acc[8];
    #pragma unroll
    for (int i = 0; i < 8; ++i) acc[i] = (f32x4){0.f, 0.f, 0.f, 0.f};

    int arow = rowBase + wid * 16 + (lane & 15);
    if (arow > rows - 1) arow = rows - 1;
    const int kqo = (lane >> 4) * 8;

    #pragma unroll 8
    for (int it = 0; it < 32; ++it) {
        int idx = it * 256 + t;
        int n = idx & 127, kp = idx >> 7;
        float w0 = W[(size_t)(kp * 2) * DD + n];
        float w1 = W[(size_t)(kp * 2 + 1) * DD + n];
        Bt[((n << 6) + kp) ^ ((n & 7) << 2)] = (unsigned)f2b(w0) | ((unsigned)f2b(w1) << 16);
    }
    __syncthreads();
    short8 a[4];
    #pragma unroll
    for (int kc = 0; kc < 4; ++kc) {
        const float* Af = x + (size_t)arow * DD + kc * 32 + kqo;
        float4 lo = *(const float4*)Af;
        float4 hi = *(const float4*)(Af + 4);
        union { short8 s; unsigned short u[8]; } cv;
        cv.u[0] = f2b(lo.x); cv.u[1] = f2b(lo.y); cv.u[2] = f2b(lo.z); cv.u[3] = f2b(lo.w);
        cv.u[4] = f2b(hi.x); cv.u[5] = f2b(hi.y); cv.u[6] = f2b(hi.z); cv.u[7] = f2b(hi.w);
        a[kc] = cv.s;
    }
    #pragma unroll
    for (int ng = 0; ng < 8; ++ng) {
        int col = ng * 16 + (lane & 15);
        #pragma unroll
        for (int kc = 0; kc < 4; ++kc) {
            int kidx = kc * 16 + (lane >> 4) * 4;
            const short8 b = *(const short8*)((const char*)Bt +
                    ((((col << 6) + kidx) ^ ((col & 7) << 2)) << 2));
            acc[ng] = __builtin_amdgcn_mfma_f32_16x16x32_bf16(a[kc], b, acc[ng], 0, 0, 0);
        }
    }
    const int co = (int)blockIdx.y << 7;
    #pragma unroll
    for (int ng = 0; ng < 8; ++ng) {
        int col = ng * 16 + (lane & 15);
        float bv = bias[col];
        #pragma unroll
        for (int r = 0; r < 4; ++r) {
            int grow = rowBase + wid * 16 + (lane >> 4) * 4 + r;
            if (grow >= rows) continue;
            qkv[(size_t)grow * 384 + co + col] = f2b(acc[ng][r] + bv);
        }
    }
}

// ---------- ffn2 GEMM + residual + LN (x in-place), A = h1 bf16 [rows][256] ----------
__global__ __launch_bounds__(256) void mgemm_ln(
        const unsigned short* __restrict__ h1, const float* __restrict__ W,
        const float* __restrict__ bias, const float* __restrict__ g,
        const float* __restrict__ bb, float* __restrict__ x, int rows) {
    __shared__ unsigned Bt[128 * 64];
    const int t = threadIdx.x;
    const int rowBase = blockIdx.x << 6;
    const int lane = t & 63, wid = t >> 6;

    f32x4 acc[8];
    #pragma unroll
    for (int i = 0; i < 8; ++i) acc[i] = (f32x4){0.f, 0.f, 0.f, 0.f};

    int arow = rowBase + wid * 16 + (lane & 15);
    if (arow > rows - 1) arow = rows - 1;
    const int kqo = (lane >> 4) * 8;

    for (int k0 = 0; k0 < 256; k0 += 128) {
        if (k0) __syncthreads();
        #pragma unroll 8
        for (int it = 0; it < 32; ++it) {
            int idx = it * 256 + t;
            int n = idx & 127, kp = idx >> 7;
            int krow = k0 + kp * 2;
            float w0 = W[(size_t)krow * DD + n];
            float w1 = W[(size_t)(krow + 1) * DD + n];
            Bt[((n << 6) + kp) ^ ((n & 7) << 2)] = (unsigned)f2b(w0) | ((unsigned)f2b(w1) << 16);
        }
        __syncthreads();
        short8 a[4];
        #pragma unroll
        for (int kc = 0; kc < 4; ++kc) {
            a[kc] = *(const short8*)(h1 + (size_t)arow * 256 + k0 + kc * 32 + kqo);
        }
        #pragma unroll
        for (int ng = 0; ng < 8; ++ng) {
            int col = ng * 16 + (lane & 15);
            #pragma unroll
            for (int kc = 0; kc < 4; ++kc) {
                int kidx = kc * 16 + (lane >> 4) * 4;
                const short8 b = *(const short8*)((const char*)Bt +
                        ((((col << 6) + kidx) ^ ((col & 7) << 2)) << 2));
                acc[ng] = __builtin_amdgcn_mfma_f32_16x16x32_bf16(a[kc], b, acc[ng], 0, 0, 0);
            }
        }
    }
    // epilogue: tt = gemm + bias + x_old; row-wise LN over 128 cols; store x.
    float tt[8][4];
    float rs[4] = {0.f, 0.f, 0.f, 0.f}, rs2[4] = {0.f, 0.f, 0.f, 0.f};
    #pragma unroll
    for (int ng = 0; ng < 8; ++ng) {
        int col = ng * 16 + (lane & 15);
        float bv = bias[col];
        #pragma unroll
        for (int r = 0; r < 4; ++r) {
            int grow = rowBase + wid * 16 + (lane >> 4) * 4 + r;
            float xo = (grow < rows) ? x[(size_t)grow * DD + col] : 0.f;
            float v = acc[ng][r] + bv + xo;
            tt[ng][r] = v;
            rs[r] += v;
            rs2[r] += v * v;
        }
    }
    #pragma unroll
    for (int r = 0; r < 4; ++r) {
        #pragma unroll
        for (int m = 1; m < 16; m <<= 1) {
            rs[r] += __shfl_xor(rs[r], m);
            rs2[r] += __shfl_xor(rs2[r], m);
        }
    }
    #pragma unroll
    for (int ng = 0; ng < 8; ++ng) {
        int col = ng * 16 + (lane & 15);
        float gg = g[col], bbb = bb[col];
        #pragma unroll
        for (int r = 0; r < 4; ++r) {
            int grow = rowBase + wid * 16 + (lane >> 4) * 4 + r;
            if (grow >= rows) continue;
            float mean = rs[r] * (1.f / DD);
            float var = rs2[r] * (1.f / DD) - mean * mean;
            x[(size_t)grow * DD + col] = (tt[ng][r] - mean) * rsqrtf(var + 1e-5f) * gg + bbb;
        }
    }
}

// ---------- small kernels ----------

__global__ void enc_kernel(const float* __restrict__ xyz, const float* __restrict__ attr,
                           const float* __restrict__ W, const float* __restrict__ b,
                           const float* __restrict__ g, const float* __restrict__ bb,
                           float* __restrict__ x) {
    int i = blockIdx.x, d = threadIdx.x;
    __shared__ float sin4[4];
    if (d < 3) sin4[d] = xyz[i * 3 + d];
    if (d == 3) sin4[3] = attr[i];
    __syncthreads();
    float y = b[d];
    #pragma unroll
    for (int kk = 0; kk < 4; ++kk) y += sin4[kk] * W[kk * DD + d];
    float s = y, s2 = y * y;
    redsum2_128(s, s2);
    float mean = s * (1.0f / DD);
    float var = s2 * (1.0f / DD) - mean * mean;
    float xn = (y - mean) * rsqrtf(var + 1e-5f) * g[d] + bb[d];
    x[i * DD + d] = fmaxf(xn, 0.f);
}

// one block, 128 threads: centered W1/b1 + quadratic-form coefficients for pos-LN
// pw layout: [0:128) W1c0, [128:256) W1c1, [256:384) W1c2, [384:512) b1c,
//            [512:522) {A00,A01,A02,A11,A12,A22,B0,B1,B2,C}
__global__ void posprep_kernel(const float* __restrict__ W1, const float* __restrict__ b1,
                               float* __restrict__ pw) {
    int d = threadIdx.x;
    float w0 = W1[d], w1 = W1[DD + d], w2 = W1[2 * DD + d], b = b1[d];
    float s0 = w0, s1 = w1;
    redsum2_128(s0, s1);
    float s2 = w2, s3 = b;
    redsum2_128(s2, s3);
    float c0 = w0 - s0 * (1.f / DD), c1 = w1 - s1 * (1.f / DD);
    float c2 = w2 - s2 * (1.f / DD), bc = b - s3 * (1.f / DD);
    pw[d] = c0; pw[DD + d] = c1; pw[2 * DD + d] = c2; pw[3 * DD + d] = bc;
    float p0 = c0 * c0, p1 = c0 * c1; redsum2_128(p0, p1);
    float p2 = c0 * c2, p3 = c1 * c1; redsum2_128(p2, p3);
    float p4 = c1 * c2, p5 = c2 * c2; redsum2_128(p4, p5);
    float p6 = c0 * bc, p7 = c1 * bc; redsum2_128(p6, p7);
    float p8 = c2 * bc, p9 = bc * bc; redsum2_128(p8, p9);
    if (d == 0) {
        pw[512] = p0 * (1.f / DD); pw[513] = p1 * (1.f / DD); pw[514] = p2 * (1.f / DD);
        pw[515] = p3 * (1.f / DD); pw[516] = p4 * (1.f / DD); pw[517] = p5 * (1.f / DD);
        pw[518] = p6 * (1.f / DD); pw[519] = p7 * (1.f / DD); pw[520] = p8 * (1.f / DD);
        pw[521] = p9 * (1.f / DD);
    }
}

// t = relu(LN(rel@W1+b1)) per edge, reduction-free: one wave per edge, 2 dims/lane.
__global__ void pos2_kernel(const float* __restrict__ xyz, const int* __restrict__ ei,
                            const float* __restrict__ pw, const float* __restrict__ g,
                            const float* __restrict__ bb, unsigned* __restrict__ tb32,
                            int nE) {
    const int lane = threadIdx.x & 63;
    const int waveg = (blockIdx.x * (blockDim.x >> 6)) + (threadIdx.x >> 6);
    const int nwaves = gridDim.x * (blockDim.x >> 6);
    float A00 = pw[512], A01 = pw[513], A02 = pw[514], A11 = pw[515], A12 = pw[516];
    float A22 = pw[517], B0 = pw[518], B1 = pw[519], B2 = pw[520], Cq = pw[521];
    int d0 = lane * 2, d1 = lane * 2 + 1;
    float w00 = pw[d0], w01 = pw[d1];
    float w10 = pw[DD + d0], w11 = pw[DD + d1];
    float w20 = pw[2 * DD + d0], w21 = pw[2 * DD + d1];
    float bc0 = pw[3 * DD + d0], bc1 = pw[3 * DD + d1];
    float g0 = g[d0], g1v = g[d1], bb0 = bb[d0], bb1 = bb[d1];
    for (int e = waveg; e < nE; e += nwaves) {
        int src = ei[e], dst = ei[nE + e];
        float rv = 0.f;
        if (lane < 3) rv = xyz[dst * 3 + lane] - xyz[src * 3 + lane];
        float r0 = __shfl(rv, 0), r1 = __shfl(rv, 1), r2 = __shfl(rv, 2);
        float var = A00 * r0 * r0 + A11 * r1 * r1 + A22 * r2 * r2
                  + 2.f * (A01 * r0 * r1 + A02 * r0 * r2 + A12 * r1 * r2)
                  + 2.f * (B0 * r0 + B1 * r1 + B2 * r2) + Cq;
        float inv = rsqrtf(var + 1e-5f);
        float y0 = r0 * w00 + r1 * w10 + r2 * w20 + bc0;
        float y1 = r0 * w01 + r1 * w11 + r2 * w21 + bc1;
        float t0 = fmaxf(y0 * inv * g0 + bb0, 0.f);
        float t1 = fmaxf(y1 * inv * g1v + bb1, 0.f);
        tb32[(size_t)e * 64 + lane] = (unsigned)f2b(t0) | ((unsigned)f2b(t1) << 16);
    }
}

// W2We[r][d] = sum_k W2[r][k]*We[k][d]; row 128: b2We[d]
__global__ void wcomb_kernel(const float* __restrict__ W2, const float* __restrict__ b2,
                             const float* __restrict__ We, float* __restrict__ W2We,
                             float* __restrict__ b2We) {
    int r = blockIdx.x, d = threadIdx.x;
    __shared__ float sa[DD];
    sa[d] = (r < DD) ? W2[r * DD + d] : b2[d];
    __syncthreads();
    float acc = 0.f;
    #pragma unroll 8
    for (int kk = 0; kk < DD; ++kk) acc += sa[kk] * We[kk * DD + d];
    if (r < DD) W2We[r * DD + d] = acc;
    else        b2We[d] = acc;
}

// ---------- CSR build ----------

__global__ void hist_kernel(const int* __restrict__ ei, int* __restrict__ deg, int E) {
    int e = blockIdx.x * blockDim.x + threadIdx.x;
    if (e < E) atomicAdd(&deg[ei[E + e]], 1);
}

__global__ void scan_kernel(const int* __restrict__ deg, int* __restrict__ ptr, int n) {
    __shared__ int buf[1024];
    __shared__ int carry_s;
    int t = threadIdx.x;
    if (t == 0) { carry_s = 0; ptr[0] = 0; }
    __syncthreads();
    for (int base = 0; base < n; base += 1024) {
        int i = base + t;
        buf[t] = (i < n) ? deg[i] : 0;
        __syncthreads();
        for (int off = 1; off < 1024; off <<= 1) {
            int add = (t >= off) ? buf[t - off] : 0;
            __syncthreads();
            buf[t] += add;
            __syncthreads();
        }
        int c = carry_s;
        if (i < n) ptr[i + 1] = c + buf[t];
        __syncthreads();
        if (t == 0) carry_s = c + buf[1023];
        __syncthreads();
    }
}

__global__ void scatter_kernel(const int* __restrict__ ei, const int* __restrict__ ptr,
                               int* __restrict__ cur, int* __restrict__ cs_src,
                               int* __restrict__ cs_eid, int E) {
    int e = blockIdx.x * blockDim.x + threadIdx.x;
    if (e >= E) return;
    int dstn = ei[E + e];
    int p = atomicAdd(&cur[dstn], 1);
    int slot = ptr[dstn] + p;
    cs_src[slot] = ei[e];
    cs_eid[slot] = e;
}

// ---------- fused attention agg + beta gate + residual + LN1 ----------
__global__ void aggc_kernel(const unsigned short* __restrict__ qkv,
                            const unsigned short* __restrict__ ee,
                            const int* __restrict__ ptr, const int* __restrict__ cs_src,
                            const int* __restrict__ cs_eid, const float* __restrict__ r,
                            const float* __restrict__ Wb, const float* __restrict__ g1,
                            const float* __restrict__ b1, float* __restrict__ x) {
    int i = blockIdx.x, d = threadIdx.x;
    float qd = b2f(qkv[(size_t)i * 384 + d]);
    float m = -INFINITY, s = 0.f, acc = 0.f;
    int beg = ptr[i], end = ptr[i + 1];
    for (int idx = beg; idx < end; ++idx) {
        int j = cs_src[idx];
        float eed = b2f(ee[(size_t)cs_eid[idx] * DD + d]);
        float kj = b2f(qkv[(size_t)j * 384 + 128 + d]) + eed;
        float p = qd * kj;
        #pragma unroll
        for (int mm = 16; mm; mm >>= 1) p += __shfl_xor(p, mm);
        float al = p * 0.17677669529663687f;  // 1/sqrt(32)
        float nm = fmaxf(m, al);
        float cold = expf(m - nm);
        float w = expf(al - nm);
        s = s * cold + w;
        acc = acc * cold + (b2f(qkv[(size_t)j * 384 + 256 + d]) + eed) * w;
        m = nm;
    }
    float od = (s > 0.f) ? acc / s : 0.f;
    float rd = r[i * DD + d];
    float part = od * Wb[d] + rd * Wb[DD + d] + (od - rd) * Wb[2 * DD + d];
    float dummy = 0.f;
    redsum2_128(part, dummy);
    float beta = 1.f / (1.f + expf(-part));
    float comb = beta * rd + (1.f - beta) * od;
    float t = comb + x[i * DD + d];
    float ss = t, ss2 = t * t;
    redsum2_128(ss, ss2);
    float mean = ss * (1.0f / DD);
    float var = ss2 * (1.0f / DD) - mean * mean;
    x[i * DD + d] = (t - mean) * rsqrtf(var + 1e-5f) * g1[d] + b1[d];
}

// cls and box heads
__global__ void heads_kernel(const float* __restrict__ x,
                             const float* __restrict__ cW1, const float* __restrict__ cb1,
                             const float* __restrict__ cW2, const float* __restrict__ cb2,
                             const float* __restrict__ bW1, const float* __restrict__ bb1,
                             const float* __restrict__ bW2, const float* __restrict__ bb2,
                             float* __restrict__ outc, float* __restrict__ outb) {
    int i = blockIdx.x, d = threadIdx.x;  // 128 threads
    __shared__ float sx[DD], st[128];
    sx[d] = x[i * DD + d];
    __syncthreads();
    float a;
    if (d < 64) {
        a = cb1[d];
        #pragma unroll 8
        for (int kk = 0; kk < DD; ++kk) a += sx[kk] * cW1[kk * 64 + d];
    } else {
        int dd = d - 64;
        a = bb1[dd];
        #pragma unroll 8
        for (int kk = 0; kk < DD; ++kk) a += sx[kk] * bW1[kk * 64 + dd];
    }
    st[d] = fmaxf(a, 0.f);
    __syncthreads();
    if (d < 4) {
        float o = cb2[d];
        #pragma unroll
        for (int kk = 0; kk < 64; ++kk) o += st[kk] * cW2[kk * 4 + d];
        outc[i * 4 + d] = o;
    } else if (d >= 64 && d < 71) {
        int j = d - 64;
        float o = bb2[j];
        #pragma unroll
        for (int kk = 0; kk < 64; ++kk) o += st[64 + kk] * bW2[kk * 7 + j];
        outb[i * 7 + j] = o;
    }
}

extern "C" void kernel_launch(void* const* d_in, const int* in_sizes, int n_in,
                              void* d_out, int out_size, void* d_ws, size_t ws_size,
                              hipStream_t stream) {
    const float* xyz   = (const float*)d_in[0];
    const float* attr  = (const float*)d_in[1];
    const int*   ei    = (const int*)d_in[2];
    const float* encW  = (const float*)d_in[3];
    const float* encb  = (const float*)d_in[4];
    const float* encg  = (const float*)d_in[5];
    const float* encbb = (const float*)d_in[6];
    const float* posW1 = (const float*)d_in[7];
    const float* posb1 = (const float*)d_in[8];
    const float* posg  = (const float*)d_in[9];
    const float* posbb = (const float*)d_in[10];
    const float* posW2 = (const float*)d_in[11];
    const float* posb2 = (const float*)d_in[12];
    const float* Wq    = (const float*)d_in[13];
    const float* bq    = (const float*)d_in[14];
    const float* Wk    = (const float*)d_in[15];
    const float* bk    = (const float*)d_in[16];
    const float* Wv    = (const float*)d_in[17];
    const float* bv    = (const float*)d_in[18];
    const float* We    = (const float*)d_in[19];
    const float* Wskip = (const float*)d_in[20];
    const float* bskip = (const float*)d_in[21];
    const float* Wbeta = (const float*)d_in[22];
    const float* ln1g  = (const float*)d_in[23];
    const float* ln1b  = (const float*)d_in[24];
    const float* ln2g  = (const float*)d_in[25];
    const float* ln2b  = (const float*)d_in[26];
    const float* fW1   = (const float*)d_in[27];
    const float* fb1   = (const float*)d_in[28];
    const float* fW2   = (const float*)d_in[29];
    const float* fb2   = (const float*)d_in[30];
    const float* cW1   = (const float*)d_in[31];
    const float* cb1   = (const float*)d_in[32];
    const float* cW2   = (const float*)d_in[33];
    const float* cb2   = (const float*)d_in[34];
    const float* bW1   = (const float*)d_in[35];
    const float* bb1   = (const float*)d_in[36];
    const float* bW2   = (const float*)d_in[37];
    const float* bb2   = (const float*)d_in[38];

    const int N = in_sizes[0] / 3;
    const int E = in_sizes[2] / 2;

    size_t off = 0;
    auto alloc = [&](size_t nelem) {
        char* p = (char*)d_ws + off;
        off += nelem * sizeof(float);
        return (float*)p;
    };
    float* x     = alloc((size_t)N * DD);
    unsigned short* qkv = (unsigned short*)alloc((size_t)N * 192);   // N*384 bf16
    float* r     = alloc((size_t)N * DD);
    unsigned short* h1 = (unsigned short*)alloc((size_t)N * 128);    // N*256 bf16
    unsigned* tb32 = (unsigned*)alloc((size_t)E * 64);               // E*128 bf16 (packed)
    unsigned short* eeb = (unsigned short*)alloc((size_t)E * 64);    // E*128 bf16
    float* W2We  = alloc(DD * DD);
    float* b2We  = alloc(DD);
    float* pw    = alloc(544);
    int* deg     = (int*)alloc(N);
    int* ptr     = (int*)alloc(N + 1);
    int* cur     = (int*)alloc(N);
    int* cs_src  = (int*)alloc(E);
    int* cs_eid  = (int*)alloc(E);

    const int rtN = (N + 63) / 64;
    const int rtE = (E + 63) / 64;

    // ---- once: encoder, pos-MLP stage 1 (LN-free), CSR build ----
    enc_kernel<<<N, DD, 0, stream>>>(xyz, attr, encW, encb, encg, encbb, x);
    posprep_kernel<<<1, DD, 0, stream>>>(posW1, posb1, pw);
    pos2_kernel<<<1280, 256, 0, stream>>>(xyz, ei, pw, posg, posbb, tb32, E);
    hipMemsetAsync(deg, 0, N * sizeof(int), stream);
    hipMemsetAsync(cur, 0, N * sizeof(int), stream);
    hist_kernel<<<(E + 255) / 256, 256, 0, stream>>>(ei, deg, E);
    scan_kernel<<<1, 1024, 0, stream>>>(deg, ptr, N);
    scatter_kernel<<<(E + 255) / 256, 256, 0, stream>>>(ei, ptr, cur, cs_src, cs_eid, E);

    for (int l = 0; l < 3; ++l) {
        const float* We_l = We + (size_t)l * DD * DD;
        const float* Wb_l = Wbeta + (size_t)l * 3 * DD;
        const float* fW1_l = fW1 + (size_t)l * DD * 256;
        const float* fW2_l = fW2 + (size_t)l * 256 * DD;
        QKVW wp;
        wp.W[0] = Wq + (size_t)l * DD * DD; wp.b[0] = bq + l * DD;
        wp.W[1] = Wk + (size_t)l * DD * DD; wp.b[1] = bk + l * DD;
        wp.W[2] = Wv + (size_t)l * DD * DD; wp.b[2] = bv + l * DD;

        // ee = t @ (W2@We_l) + b2@We_l
        wcomb_kernel<<<DD + 1, DD, 0, stream>>>(posW2, posb2, We_l, W2We, b2We);
        mgemm<0, true, true><<<dim3(rtE, 1), 256, 0, stream>>>(tb32, W2We, b2We, eeb, E, DD, DD);

        // q,k,v fused (bf16, strided 384) + r (f32)
        mgemm_qkv<<<dim3(rtN, 3), 256, 0, stream>>>(x, wp, qkv, N);
        mgemm<0, false, false><<<dim3(rtN, 1), 256, 0, stream>>>(
            x, Wskip + (size_t)l * DD * DD, bskip + l * DD, r, N, DD, DD);

        // fused: scatter-softmax agg + beta gate + residual + LN1
        aggc_kernel<<<N, DD, 0, stream>>>(qkv, eeb, ptr, cs_src, cs_eid, r,
                                          Wb_l, ln1g + l * DD, ln1b + l * DD, x);

        // FFN: h1 = gelu(x@fW1+fb1) bf16; x = LN(h1@fW2+fb2 + x)
        mgemm<1, false, true><<<dim3(rtN, 2), 256, 0, stream>>>(x, fW1_l, fb1 + l * 256, h1, N, DD, 256);
        mgemm_ln<<<dim3(rtN, 1), 256, 0, stream>>>(h1, fW2_l, fb2 + l * DD,
                                                   ln2g + l * DD, ln2b + l * DD, x, N);
    }

    float* outc  = (float*)d_out;
    float* outbx = (float*)d_out + (size_t)N * 4;
    heads_kernel<<<N, DD, 0, stream>>>(x, cW1, cb1, cW2, cb2, bW1, bb1, bW2, bb2, outc, outbx);
}

// Round 5
// 729.764 us; speedup vs baseline: 6.2780x; 1.0768x over previous
//
#include <hip/hip_runtime.h>
#include <hip/hip_bf16.h>
#include <math.h>

#define DD 128
#define HH 4

typedef __attribute__((ext_vector_type(8))) short short8;
typedef __attribute__((ext_vector_type(4))) float f32x4;

// ---------- helpers ----------

__device__ __forceinline__ unsigned short f2b(float f) {
    unsigned u = __float_as_uint(f);
    return (unsigned short)((u + 0x7FFFu + ((u >> 16) & 1u)) >> 16);
}
__device__ __forceinline__ float b2f(unsigned short b) {
    return __uint_as_float(((unsigned)b) << 16);
}

__device__ __forceinline__ void redsum2_128(float& a, float& b) {
    #pragma unroll
    for (int off = 32; off > 0; off >>= 1) {
        a += __shfl_down(a, off);
        b += __shfl_down(b, off);
    }
    __shared__ float sa[2], sb[2];
    int w = threadIdx.x >> 6;
    if ((threadIdx.x & 63) == 0) { sa[w] = a; sb[w] = b; }
    __syncthreads();
    a = sa[0] + sa[1];
    b = sb[0] + sb[1];
    __syncthreads();
}

// ---------- MFMA GEMM (generic) ----------
// out[rows,Dout](col tile by blockIdx.y) = act(A[rows,K] @ W[K,Dout] + bias)
// Block: 256 thr = 4 waves; wave = 16 rows; tile 64x128.
template <int ACT, bool ABF, bool OBF>
__global__ __launch_bounds__(256) void mgemm(
        const void* __restrict__ A_, const float* __restrict__ W,
        const float* __restrict__ bias, void* __restrict__ out_,
        int rows, int K, int Dout) {
    __shared__ unsigned Bt[128 * 64];  // 32 KB
    const int t = threadIdx.x;
    const int rowBase = blockIdx.x << 6;
    const int colBase = blockIdx.y << 7;
    const int lane = t & 63, wid = t >> 6;

    f32x4 acc[8];
    #pragma unroll
    for (int i = 0; i < 8; ++i) acc[i] = (f32x4){0.f, 0.f, 0.f, 0.f};

    int arow = rowBase + wid * 16 + (lane & 15);
    if (arow > rows - 1) arow = rows - 1;
    const int kqo = (lane >> 4) * 8;

    for (int k0 = 0; k0 < K; k0 += 128) {
        if (k0) __syncthreads();
        #pragma unroll 8
        for (int it = 0; it < 32; ++it) {
            int idx = it * 256 + t;
            int n = idx & 127, kp = idx >> 7;
            int krow = k0 + kp * 2;
            float w0 = W[(size_t)krow * Dout + colBase + n];
            float w1 = W[(size_t)(krow + 1) * Dout + colBase + n];
            Bt[((n << 6) + kp) ^ ((n & 7) << 2)] = (unsigned)f2b(w0) | ((unsigned)f2b(w1) << 16);
        }
        __syncthreads();
        short8 a[4];
        #pragma unroll
        for (int kc = 0; kc < 4; ++kc) {
            int kk = k0 + kc * 32 + kqo;
            if (ABF) {
                a[kc] = *(const short8*)((const unsigned short*)A_ + (size_t)arow * K + kk);
            } else {
                const float* Af = (const float*)A_ + (size_t)arow * K + kk;
                float4 lo = *(const float4*)Af;
                float4 hi = *(const float4*)(Af + 4);
                union { short8 s; unsigned short u[8]; } cv;
                cv.u[0] = f2b(lo.x); cv.u[1] = f2b(lo.y); cv.u[2] = f2b(lo.z); cv.u[3] = f2b(lo.w);
                cv.u[4] = f2b(hi.x); cv.u[5] = f2b(hi.y); cv.u[6] = f2b(hi.z); cv.u[7] = f2b(hi.w);
                a[kc] = cv.s;
            }
        }
        #pragma unroll
        for (int ng = 0; ng < 8; ++ng) {
            int col = ng * 16 + (lane & 15);
            #pragma unroll
            for (int kc = 0; kc < 4; ++kc) {
                int kidx = kc * 16 + (lane >> 4) * 4;
                const short8 b = *(const short8*)((const char*)Bt +
                        ((((col << 6) + kidx) ^ ((col & 7) << 2)) << 2));
                acc[ng] = __builtin_amdgcn_mfma_f32_16x16x32_bf16(a[kc], b, acc[ng], 0, 0, 0);
            }
        }
    }
    #pragma unroll
    for (int ng = 0; ng < 8; ++ng) {
        int gcol = colBase + ng * 16 + (lane & 15);
        float bv = bias ? bias[gcol] : 0.f;
        #pragma unroll
        for (int r = 0; r < 4; ++r) {
            int grow = rowBase + wid * 16 + (lane >> 4) * 4 + r;
            if (grow >= rows) continue;
            float val = acc[ng][r] + bv;
            if (ACT == 1) val = 0.5f * val * (1.f + erff(val * 0.70710678118654752f));
            else if (ACT == 2) val = fmaxf(val, 0.f);
            if (OBF) ((unsigned short*)out_)[(size_t)grow * Dout + gcol] = f2b(val);
            else     ((float*)out_)[(size_t)grow * Dout + gcol] = val;
        }
    }
}

// ---------- fused q,k,v,r GEMM: blockIdx.y selects weight ----------
// y=0..2 -> bf16 qkv[rows][384]; y=3 -> f32 r[rows][128]
struct QKVW { const float* W[4]; const float* b[4]; };

__global__ __launch_bounds__(256) void mgemm_qkvr(
        const float* __restrict__ x, QKVW wp, unsigned short* __restrict__ qkv,
        float* __restrict__ rbuf, int rows) {
    __shared__ unsigned Bt[128 * 64];
    const float* W = wp.W[blockIdx.y];
    const float* bias = wp.b[blockIdx.y];
    const int t = threadIdx.x;
    const int rowBase = blockIdx.x << 6;
    const int lane = t & 63, wid = t >> 6;

    f32x4 acc[8];
    #pragma unroll
    for (int i = 0; i < 8; ++i) acc[i] = (f32x4){0.f, 0.f, 0.f, 0.f};

    int arow = rowBase + wid * 16 + (lane & 15);
    if (arow > rows - 1) arow = rows - 1;
    const int kqo = (lane >> 4) * 8;

    #pragma unroll 8
    for (int it = 0; it < 32; ++it) {
        int idx = it * 256 + t;
        int n = idx & 127, kp = idx >> 7;
        float w0 = W[(size_t)(kp * 2) * DD + n];
        float w1 = W[(size_t)(kp * 2 + 1) * DD + n];
        Bt[((n << 6) + kp) ^ ((n & 7) << 2)] = (unsigned)f2b(w0) | ((unsigned)f2b(w1) << 16);
    }
    __syncthreads();
    short8 a[4];
    #pragma unroll
    for (int kc = 0; kc < 4; ++kc) {
        const float* Af = x + (size_t)arow * DD + kc * 32 + kqo;
        float4 lo = *(const float4*)Af;
        float4 hi = *(const float4*)(Af + 4);
        union { short8 s; unsigned short u[8]; } cv;
        cv.u[0] = f2b(lo.x); cv.u[1] = f2b(lo.y); cv.u[2] = f2b(lo.z); cv.u[3] = f2b(lo.w);
        cv.u[4] = f2b(hi.x); cv.u[5] = f2b(hi.y); cv.u[6] = f2b(hi.z); cv.u[7] = f2b(hi.w);
        a[kc] = cv.s;
    }
    #pragma unroll
    for (int ng = 0; ng < 8; ++ng) {
        int col = ng * 16 + (lane & 15);
        #pragma unroll
        for (int kc = 0; kc < 4; ++kc) {
            int kidx = kc * 16 + (lane >> 4) * 4;
            const short8 b = *(const short8*)((const char*)Bt +
                    ((((col << 6) + kidx) ^ ((col & 7) << 2)) << 2));
            acc[ng] = __builtin_amdgcn_mfma_f32_16x16x32_bf16(a[kc], b, acc[ng], 0, 0, 0);
        }
    }
    const int y = (int)blockIdx.y;
    #pragma unroll
    for (int ng = 0; ng < 8; ++ng) {
        int col = ng * 16 + (lane & 15);
        float bv = bias[col];
        #pragma unroll
        for (int r = 0; r < 4; ++r) {
            int grow = rowBase + wid * 16 + (lane >> 4) * 4 + r;
            if (grow >= rows) continue;
            float val = acc[ng][r] + bv;
            if (y == 3) rbuf[(size_t)grow * DD + col] = val;
            else        qkv[(size_t)grow * 384 + (y << 7) + col] = f2b(val);
        }
    }
}

// ---------- ffn2 GEMM + residual + LN (x in-place), A = h1 bf16 [rows][256] ----------
__global__ __launch_bounds__(256) void mgemm_ln(
        const unsigned short* __restrict__ h1, const float* __restrict__ W,
        const float* __restrict__ bias, const float* __restrict__ g,
        const float* __restrict__ bb, float* __restrict__ x, int rows) {
    __shared__ unsigned Bt[128 * 64];
    const int t = threadIdx.x;
    const int rowBase = blockIdx.x << 6;
    const int lane = t & 63, wid = t >> 6;

    f32x4 acc[8];
    #pragma unroll
    for (int i = 0; i < 8; ++i) acc[i] = (f32x4){0.f, 0.f, 0.f, 0.f};

    int arow = rowBase + wid * 16 + (lane & 15);
    if (arow > rows - 1) arow = rows - 1;
    const int kqo = (lane >> 4) * 8;

    for (int k0 = 0; k0 < 256; k0 += 128) {
        if (k0) __syncthreads();
        #pragma unroll 8
        for (int it = 0; it < 32; ++it) {
            int idx = it * 256 + t;
            int n = idx & 127, kp = idx >> 7;
            int krow = k0 + kp * 2;
            float w0 = W[(size_t)krow * DD + n];
            float w1 = W[(size_t)(krow + 1) * DD + n];
            Bt[((n << 6) + kp) ^ ((n & 7) << 2)] = (unsigned)f2b(w0) | ((unsigned)f2b(w1) << 16);
        }
        __syncthreads();
        short8 a[4];
        #pragma unroll
        for (int kc = 0; kc < 4; ++kc) {
            a[kc] = *(const short8*)(h1 + (size_t)arow * 256 + k0 + kc * 32 + kqo);
        }
        #pragma unroll
        for (int ng = 0; ng < 8; ++ng) {
            int col = ng * 16 + (lane & 15);
            #pragma unroll
            for (int kc = 0; kc < 4; ++kc) {
                int kidx = kc * 16 + (lane >> 4) * 4;
                const short8 b = *(const short8*)((const char*)Bt +
                        ((((col << 6) + kidx) ^ ((col & 7) << 2)) << 2));
                acc[ng] = __builtin_amdgcn_mfma_f32_16x16x32_bf16(a[kc], b, acc[ng], 0, 0, 0);
            }
        }
    }
    float tt[8][4];
    float rs[4] = {0.f, 0.f, 0.f, 0.f}, rs2[4] = {0.f, 0.f, 0.f, 0.f};
    #pragma unroll
    for (int ng = 0; ng < 8; ++ng) {
        int col = ng * 16 + (lane & 15);
        float bv = bias[col];
        #pragma unroll
        for (int r = 0; r < 4; ++r) {
            int grow = rowBase + wid * 16 + (lane >> 4) * 4 + r;
            float xo = (grow < rows) ? x[(size_t)grow * DD + col] : 0.f;
            float v = acc[ng][r] + bv + xo;
            tt[ng][r] = v;
            rs[r] += v;
            rs2[r] += v * v;
        }
    }
    #pragma unroll
    for (int r = 0; r < 4; ++r) {
        #pragma unroll
        for (int m = 1; m < 16; m <<= 1) {
            rs[r] += __shfl_xor(rs[r], m);
            rs2[r] += __shfl_xor(rs2[r], m);
        }
    }
    #pragma unroll
    for (int ng = 0; ng < 8; ++ng) {
        int col = ng * 16 + (lane & 15);
        float gg = g[col], bbb = bb[col];
        #pragma unroll
        for (int r = 0; r < 4; ++r) {
            int grow = rowBase + wid * 16 + (lane >> 4) * 4 + r;
            if (grow >= rows) continue;
            float mean = rs[r] * (1.f / DD);
            float var = rs2[r] * (1.f / DD) - mean * mean;
            x[(size_t)grow * DD + col] = (tt[ng][r] - mean) * rsqrtf(var + 1e-5f) * gg + bbb;
        }
    }
}

// ---------- small kernels ----------

__global__ void enc_kernel(const float* __restrict__ xyz, const float* __restrict__ attr,
                           const float* __restrict__ W, const float* __restrict__ b,
                           const float* __restrict__ g, const float* __restrict__ bb,
                           float* __restrict__ x) {
    int i = blockIdx.x, d = threadIdx.x;
    __shared__ float sin4[4];
    if (d < 3) sin4[d] = xyz[i * 3 + d];
    if (d == 3) sin4[3] = attr[i];
    __syncthreads();
    float y = b[d];
    #pragma unroll
    for (int kk = 0; kk < 4; ++kk) y += sin4[kk] * W[kk * DD + d];
    float s = y, s2 = y * y;
    redsum2_128(s, s2);
    float mean = s * (1.0f / DD);
    float var = s2 * (1.0f / DD) - mean * mean;
    float xn = (y - mean) * rsqrtf(var + 1e-5f) * g[d] + bb[d];
    x[i * DD + d] = fmaxf(xn, 0.f);
}

// centered W1/b1 + quadratic-form coefficients for pos-LN (one block, 128 thr)
__global__ void posprep_kernel(const float* __restrict__ W1, const float* __restrict__ b1,
                               float* __restrict__ pw) {
    int d = threadIdx.x;
    float w0 = W1[d], w1 = W1[DD + d], w2 = W1[2 * DD + d], b = b1[d];
    float s0 = w0, s1 = w1;
    redsum2_128(s0, s1);
    float s2 = w2, s3 = b;
    redsum2_128(s2, s3);
    float c0 = w0 - s0 * (1.f / DD), c1 = w1 - s1 * (1.f / DD);
    float c2 = w2 - s2 * (1.f / DD), bc = b - s3 * (1.f / DD);
    pw[d] = c0; pw[DD + d] = c1; pw[2 * DD + d] = c2; pw[3 * DD + d] = bc;
    float p0 = c0 * c0, p1 = c0 * c1; redsum2_128(p0, p1);
    float p2 = c0 * c2, p3 = c1 * c1; redsum2_128(p2, p3);
    float p4 = c1 * c2, p5 = c2 * c2; redsum2_128(p4, p5);
    float p6 = c0 * bc, p7 = c1 * bc; redsum2_128(p6, p7);
    float p8 = c2 * bc, p9 = bc * bc; redsum2_128(p8, p9);
    if (d == 0) {
        pw[512] = p0 * (1.f / DD); pw[513] = p1 * (1.f / DD); pw[514] = p2 * (1.f / DD);
        pw[515] = p3 * (1.f / DD); pw[516] = p4 * (1.f / DD); pw[517] = p5 * (1.f / DD);
        pw[518] = p6 * (1.f / DD); pw[519] = p7 * (1.f / DD); pw[520] = p8 * (1.f / DD);
        pw[521] = p9 * (1.f / DD);
    }
}

// t = relu(LN(rel@W1+b1)) per edge, written in CSR slot order (eid via cs_eid)
__global__ void pos2_kernel(const float* __restrict__ xyz, const int* __restrict__ ei,
                            const int* __restrict__ cs_eid, const float* __restrict__ pw,
                            const float* __restrict__ g, const float* __restrict__ bb,
                            unsigned* __restrict__ tb32, int nE) {
    const int lane = threadIdx.x & 63;
    const int waveg = (blockIdx.x * (blockDim.x >> 6)) + (threadIdx.x >> 6);
    const int nwaves = gridDim.x * (blockDim.x >> 6);
    float A00 = pw[512], A01 = pw[513], A02 = pw[514], A11 = pw[515], A12 = pw[516];
    float A22 = pw[517], B0 = pw[518], B1 = pw[519], B2 = pw[520], Cq = pw[521];
    int d0 = lane * 2, d1 = lane * 2 + 1;
    float w00 = pw[d0], w01 = pw[d1];
    float w10 = pw[DD + d0], w11 = pw[DD + d1];
    float w20 = pw[2 * DD + d0], w21 = pw[2 * DD + d1];
    float bc0 = pw[3 * DD + d0], bc1 = pw[3 * DD + d1];
    float g0 = g[d0], g1v = g[d1], bb0 = bb[d0], bb1 = bb[d1];
    for (int slot = waveg; slot < nE; slot += nwaves) {
        int e = cs_eid[slot];
        int src = ei[e], dst = ei[nE + e];
        float rv = 0.f;
        if (lane < 3) rv = xyz[dst * 3 + lane] - xyz[src * 3 + lane];
        float r0 = __shfl(rv, 0), r1 = __shfl(rv, 1), r2 = __shfl(rv, 2);
        float var = A00 * r0 * r0 + A11 * r1 * r1 + A22 * r2 * r2
                  + 2.f * (A01 * r0 * r1 + A02 * r0 * r2 + A12 * r1 * r2)
                  + 2.f * (B0 * r0 + B1 * r1 + B2 * r2) + Cq;
        float inv = rsqrtf(var + 1e-5f);
        float y0 = r0 * w00 + r1 * w10 + r2 * w20 + bc0;
        float y1 = r0 * w01 + r1 * w11 + r2 * w21 + bc1;
        float t0 = fmaxf(y0 * inv * g0 + bb0, 0.f);
        float t1 = fmaxf(y1 * inv * g1v + bb1, 0.f);
        tb32[(size_t)slot * 64 + lane] = (unsigned)f2b(t0) | ((unsigned)f2b(t1) << 16);
    }
}

// W2We[r][d] = sum_k W2[r][k]*We[k][d]; row 128: b2We[d]
__global__ void wcomb_kernel(const float* __restrict__ W2, const float* __restrict__ b2,
                             const float* __restrict__ We, float* __restrict__ W2We,
                             float* __restrict__ b2We) {
    int r = blockIdx.x, d = threadIdx.x;
    __shared__ float sa[DD];
    sa[d] = (r < DD) ? W2[r * DD + d] : b2[d];
    __syncthreads();
    float acc = 0.f;
    #pragma unroll 8
    for (int kk = 0; kk < DD; ++kk) acc += sa[kk] * We[kk * DD + d];
    if (r < DD) W2We[r * DD + d] = acc;
    else        b2We[d] = acc;
}

// ---------- CSR build ----------

__global__ void hist_kernel(const int* __restrict__ ei, int* __restrict__ deg, int E) {
    int e = blockIdx.x * blockDim.x + threadIdx.x;
    if (e < E) atomicAdd(&deg[ei[E + e]], 1);
}

__global__ void scan_kernel(const int* __restrict__ deg, int* __restrict__ ptr, int n) {
    __shared__ int buf[1024];
    __shared__ int carry_s;
    int t = threadIdx.x;
    if (t == 0) { carry_s = 0; ptr[0] = 0; }
    __syncthreads();
    for (int base = 0; base < n; base += 1024) {
        int i = base + t;
        buf[t] = (i < n) ? deg[i] : 0;
        __syncthreads();
        for (int off = 1; off < 1024; off <<= 1) {
            int add = (t >= off) ? buf[t - off] : 0;
            __syncthreads();
            buf[t] += add;
            __syncthreads();
        }
        int c = carry_s;
        if (i < n) ptr[i + 1] = c + buf[t];
        __syncthreads();
        if (t == 0) carry_s = c + buf[1023];
        __syncthreads();
    }
}

__global__ void scatter_kernel(const int* __restrict__ ei, const int* __restrict__ ptr,
                               int* __restrict__ cur, int* __restrict__ cs_src,
                               int* __restrict__ cs_eid, int E) {
    int e = blockIdx.x * blockDim.x + threadIdx.x;
    if (e >= E) return;
    int dstn = ei[E + e];
    int p = atomicAdd(&cur[dstn], 1);
    int slot = ptr[dstn] + p;
    cs_src[slot] = ei[e];
    cs_eid[slot] = e;
}

// ---------- fused agg (no-max softmax) + beta gate + residual + LN1 ----------
// 1 wave per node, 2 dims per lane, packed u32 bf16 loads. ee in CSR slot order.
__global__ __launch_bounds__(256) void aggc_kernel(
        const unsigned* __restrict__ qkv, const unsigned* __restrict__ ee,
        const int* __restrict__ ptr, const int* __restrict__ cs_src,
        const float* __restrict__ r, const float* __restrict__ Wb,
        const float* __restrict__ g1, const float* __restrict__ b1,
        float* __restrict__ x, int N) {
    int node = (blockIdx.x << 2) + (threadIdx.x >> 6);
    if (node >= N) return;
    const int lane = threadIdx.x & 63;
    unsigned qp = qkv[(size_t)node * 192 + lane];
    float q0 = b2f((unsigned short)qp), q1 = b2f((unsigned short)(qp >> 16));
    int beg = ptr[node], end = ptr[node + 1];
    float s = 0.f, a0 = 0.f, a1 = 0.f;
    for (int idx = beg; idx < end; ++idx) {
        int j = cs_src[idx];
        unsigned ep = ee[(size_t)idx * 64 + lane];
        unsigned kp = qkv[(size_t)j * 192 + 64 + lane];
        unsigned vp = qkv[(size_t)j * 192 + 128 + lane];
        float e0 = b2f((unsigned short)ep), e1 = b2f((unsigned short)(ep >> 16));
        float kj0 = b2f((unsigned short)kp) + e0;
        float kj1 = b2f((unsigned short)(kp >> 16)) + e1;
        float p = q0 * kj0 + q1 * kj1;
        p += __shfl_xor(p, 1); p += __shfl_xor(p, 2);
        p += __shfl_xor(p, 4); p += __shfl_xor(p, 8);
        float w = __expf(p * 0.17677669529663687f);  // |alpha| << 1: max-shift not needed
        s += w;
        a0 += (b2f((unsigned short)vp) + e0) * w;
        a1 += (b2f((unsigned short)(vp >> 16)) + e1) * w;
    }
    float inv_s = (s > 0.f) ? 1.f / s : 0.f;
    float od0 = a0 * inv_s, od1 = a1 * inv_s;
    float2 rd = *(const float2*)&r[(size_t)node * DD + lane * 2];
    float2 wb0 = *(const float2*)&Wb[lane * 2];
    float2 wb1 = *(const float2*)&Wb[DD + lane * 2];
    float2 wb2 = *(const float2*)&Wb[2 * DD + lane * 2];
    float part = od0 * wb0.x + rd.x * wb1.x + (od0 - rd.x) * wb2.x
               + od1 * wb0.y + rd.y * wb1.y + (od1 - rd.y) * wb2.y;
    #pragma unroll
    for (int m = 1; m < 64; m <<= 1) part += __shfl_xor(part, m);
    float beta = 1.f / (1.f + __expf(-part));
    float2 xo = *(const float2*)&x[(size_t)node * DD + lane * 2];
    float t0 = beta * rd.x + (1.f - beta) * od0 + xo.x;
    float t1 = beta * rd.y + (1.f - beta) * od1 + xo.y;
    float ss = t0 + t1, ss2 = t0 * t0 + t1 * t1;
    #pragma unroll
    for (int m = 1; m < 64; m <<= 1) { ss += __shfl_xor(ss, m); ss2 += __shfl_xor(ss2, m); }
    float mean = ss * (1.f / DD);
    float var = ss2 * (1.f / DD) - mean * mean;
    float inv = rsqrtf(var + 1e-5f);
    float2 gg = *(const float2*)&g1[lane * 2];
    float2 bbv = *(const float2*)&b1[lane * 2];
    float2 res;
    res.x = (t0 - mean) * inv * gg.x + bbv.x;
    res.y = (t1 - mean) * inv * gg.y + bbv.y;
    *(float2*)&x[(size_t)node * DD + lane * 2] = res;
}

// cls and box heads
__global__ void heads_kernel(const float* __restrict__ x,
                             const float* __restrict__ cW1, const float* __restrict__ cb1,
                             const float* __restrict__ cW2, const float* __restrict__ cb2,
                             const float* __restrict__ bW1, const float* __restrict__ bb1,
                             const float* __restrict__ bW2, const float* __restrict__ bb2,
                             float* __restrict__ outc, float* __restrict__ outb) {
    int i = blockIdx.x, d = threadIdx.x;  // 128 threads
    __shared__ float sx[DD], st[128];
    sx[d] = x[i * DD + d];
    __syncthreads();
    float a;
    if (d < 64) {
        a = cb1[d];
        #pragma unroll 8
        for (int kk = 0; kk < DD; ++kk) a += sx[kk] * cW1[kk * 64 + d];
    } else {
        int dd = d - 64;
        a = bb1[dd];
        #pragma unroll 8
        for (int kk = 0; kk < DD; ++kk) a += sx[kk] * bW1[kk * 64 + dd];
    }
    st[d] = fmaxf(a, 0.f);
    __syncthreads();
    if (d < 4) {
        float o = cb2[d];
        #pragma unroll
        for (int kk = 0; kk < 64; ++kk) o += st[kk] * cW2[kk * 4 + d];
        outc[i * 4 + d] = o;
    } else if (d >= 64 && d < 71) {
        int j = d - 64;
        float o = bb2[j];
        #pragma unroll
        for (int kk = 0; kk < 64; ++kk) o += st[64 + kk] * bW2[kk * 7 + j];
        outb[i * 7 + j] = o;
    }
}

extern "C" void kernel_launch(void* const* d_in, const int* in_sizes, int n_in,
                              void* d_out, int out_size, void* d_ws, size_t ws_size,
                              hipStream_t stream) {
    const float* xyz   = (const float*)d_in[0];
    const float* attr  = (const float*)d_in[1];
    const int*   ei    = (const int*)d_in[2];
    const float* encW  = (const float*)d_in[3];
    const float* encb  = (const float*)d_in[4];
    const float* encg  = (const float*)d_in[5];
    const float* encbb = (const float*)d_in[6];
    const float* posW1 = (const float*)d_in[7];
    const float* posb1 = (const float*)d_in[8];
    const float* posg  = (const float*)d_in[9];
    const float* posbb = (const float*)d_in[10];
    const float* posW2 = (const float*)d_in[11];
    const float* posb2 = (const float*)d_in[12];
    const float* Wq    = (const float*)d_in[13];
    const float* bq    = (const float*)d_in[14];
    const float* Wk    = (const float*)d_in[15];
    const float* bk    = (const float*)d_in[16];
    const float* Wv    = (const float*)d_in[17];
    const float* bv    = (const float*)d_in[18];
    const float* We    = (const float*)d_in[19];
    const float* Wskip = (const float*)d_in[20];
    const float* bskip = (const float*)d_in[21];
    const float* Wbeta = (const float*)d_in[22];
    const float* ln1g  = (const float*)d_in[23];
    const float* ln1b  = (const float*)d_in[24];
    const float* ln2g  = (const float*)d_in[25];
    const float* ln2b  = (const float*)d_in[26];
    const float* fW1   = (const float*)d_in[27];
    const float* fb1   = (const float*)d_in[28];
    const float* fW2   = (const float*)d_in[29];
    const float* fb2   = (const float*)d_in[30];
    const float* cW1   = (const float*)d_in[31];
    const float* cb1   = (const float*)d_in[32];
    const float* cW2   = (const float*)d_in[33];
    const float* cb2   = (const float*)d_in[34];
    const float* bW1   = (const float*)d_in[35];
    const float* bb1   = (const float*)d_in[36];
    const float* bW2   = (const float*)d_in[37];
    const float* bb2   = (const float*)d_in[38];

    const int N = in_sizes[0] / 3;
    const int E = in_sizes[2] / 2;

    size_t off = 0;
    auto alloc = [&](size_t nelem) {
        char* p = (char*)d_ws + off;
        off += nelem * sizeof(float);
        return (float*)p;
    };
    float* x     = alloc((size_t)N * DD);
    unsigned short* qkv = (unsigned short*)alloc((size_t)N * 192);   // N*384 bf16
    float* r     = alloc((size_t)N * DD);
    unsigned short* h1 = (unsigned short*)alloc((size_t)N * 128);    // N*256 bf16
    unsigned* tb32 = (unsigned*)alloc((size_t)E * 64);               // E*128 bf16 (CSR order)
    unsigned short* eeb = (unsigned short*)alloc((size_t)E * 64);    // E*128 bf16 (CSR order)
    float* W2We  = alloc(DD * DD);
    float* b2We  = alloc(DD);
    float* pw    = alloc(544);
    int* deg     = (int*)alloc(N);
    int* ptr     = (int*)alloc(N + 1);
    int* cur     = (int*)alloc(N);
    int* cs_src  = (int*)alloc(E);
    int* cs_eid  = (int*)alloc(E);

    const int rtN = (N + 63) / 64;
    const int rtE = (E + 63) / 64;

    // ---- once: encoder, CSR build, pos-MLP stage 1 (LN-free, CSR-ordered) ----
    enc_kernel<<<N, DD, 0, stream>>>(xyz, attr, encW, encb, encg, encbb, x);
    hipMemsetAsync(deg, 0, N * sizeof(int), stream);
    hipMemsetAsync(cur, 0, N * sizeof(int), stream);
    hist_kernel<<<(E + 255) / 256, 256, 0, stream>>>(ei, deg, E);
    scan_kernel<<<1, 1024, 0, stream>>>(deg, ptr, N);
    scatter_kernel<<<(E + 255) / 256, 256, 0, stream>>>(ei, ptr, cur, cs_src, cs_eid, E);
    posprep_kernel<<<1, DD, 0, stream>>>(posW1, posb1, pw);
    pos2_kernel<<<1280, 256, 0, stream>>>(xyz, ei, cs_eid, pw, posg, posbb, tb32, E);

    for (int l = 0; l < 3; ++l) {
        const float* We_l = We + (size_t)l * DD * DD;
        const float* Wb_l = Wbeta + (size_t)l * 3 * DD;
        const float* fW1_l = fW1 + (size_t)l * DD * 256;
        const float* fW2_l = fW2 + (size_t)l * 256 * DD;
        QKVW wp;
        wp.W[0] = Wq + (size_t)l * DD * DD;    wp.b[0] = bq + l * DD;
        wp.W[1] = Wk + (size_t)l * DD * DD;    wp.b[1] = bk + l * DD;
        wp.W[2] = Wv + (size_t)l * DD * DD;    wp.b[2] = bv + l * DD;
        wp.W[3] = Wskip + (size_t)l * DD * DD; wp.b[3] = bskip + l * DD;

        // ee = t @ (W2@We_l) + b2@We_l   (CSR-ordered rows)
        wcomb_kernel<<<DD + 1, DD, 0, stream>>>(posW2, posb2, We_l, W2We, b2We);
        mgemm<0, true, true><<<dim3(rtE, 1), 256, 0, stream>>>(tb32, W2We, b2We, eeb, E, DD, DD);

        // q,k,v (bf16, strided 384) + r (f32) in one fused dispatch
        mgemm_qkvr<<<dim3(rtN, 4), 256, 0, stream>>>(x, wp, qkv, r, N);

        // fused: softmax agg + beta gate + residual + LN1
        aggc_kernel<<<(N + 3) / 4, 256, 0, stream>>>((const unsigned*)qkv, (const unsigned*)eeb,
                                                     ptr, cs_src, r, Wb_l,
                                                     ln1g + l * DD, ln1b + l * DD, x, N);

        // FFN: h1 = gelu(x@fW1+fb1) bf16; x = LN(h1@fW2+fb2 + x)
        mgemm<1, false, true><<<dim3(rtN, 2), 256, 0, stream>>>(x, fW1_l, fb1 + l * 256, h1, N, DD, 256);
        mgemm_ln<<<dim3(rtN, 1), 256, 0, stream>>>(h1, fW2_l, fb2 + l * DD,
                                                   ln2g + l * DD, ln2b + l * DD, x, N);
    }

    float* outc  = (float*)d_out;
    float* outbx = (float*)d_out + (size_t)N * 4;
    heads_kernel<<<N, DD, 0, stream>>>(x, cW1, cb1, cW2, cb2, bW1, bb1, bW2, bb2, outc, outbx);
}

// Round 6
// 697.943 us; speedup vs baseline: 6.5643x; 1.0456x over previous
//
#include <hip/hip_runtime.h>
#include <hip/hip_bf16.h>
#include <math.h>

#define DD 128
#define HH 4

typedef __attribute__((ext_vector_type(8))) short short8;
typedef __attribute__((ext_vector_type(4))) float f32x4;

// ---------- helpers ----------

__device__ __forceinline__ unsigned short f2b(float f) {
    unsigned u = __float_as_uint(f);
    return (unsigned short)((u + 0x7FFFu + ((u >> 16) & 1u)) >> 16);
}
__device__ __forceinline__ float b2f(unsigned short b) {
    return __uint_as_float(((unsigned)b) << 16);
}

__device__ __forceinline__ void redsum2_128(float& a, float& b) {
    #pragma unroll
    for (int off = 32; off > 0; off >>= 1) {
        a += __shfl_down(a, off);
        b += __shfl_down(b, off);
    }
    __shared__ float sa[2], sb[2];
    int w = threadIdx.x >> 6;
    if ((threadIdx.x & 63) == 0) { sa[w] = a; sb[w] = b; }
    __syncthreads();
    a = sa[0] + sa[1];
    b = sb[0] + sb[1];
    __syncthreads();
}

// ---------- MFMA GEMM (generic) ----------
// out[rows,Dout](col tile by blockIdx.y) = act(A[rows,K] @ W[K,Dout] + bias)
// Block: 256 thr = 4 waves; wave = 16 rows; tile 64x128.
template <int ACT, bool ABF, bool OBF>
__global__ __launch_bounds__(256) void mgemm(
        const void* __restrict__ A_, const float* __restrict__ W,
        const float* __restrict__ bias, void* __restrict__ out_,
        int rows, int K, int Dout) {
    __shared__ unsigned Bt[128 * 64];  // 32 KB
    const int t = threadIdx.x;
    const int rowBase = blockIdx.x << 6;
    const int colBase = blockIdx.y << 7;
    const int lane = t & 63, wid = t >> 6;

    f32x4 acc[8];
    #pragma unroll
    for (int i = 0; i < 8; ++i) acc[i] = (f32x4){0.f, 0.f, 0.f, 0.f};

    int arow = rowBase + wid * 16 + (lane & 15);
    if (arow > rows - 1) arow = rows - 1;
    const int kqo = (lane >> 4) * 8;

    for (int k0 = 0; k0 < K; k0 += 128) {
        if (k0) __syncthreads();
        #pragma unroll 8
        for (int it = 0; it < 32; ++it) {
            int idx = it * 256 + t;
            int n = idx & 127, kp = idx >> 7;
            int krow = k0 + kp * 2;
            float w0 = W[(size_t)krow * Dout + colBase + n];
            float w1 = W[(size_t)(krow + 1) * Dout + colBase + n];
            Bt[((n << 6) + kp) ^ ((n & 7) << 2)] = (unsigned)f2b(w0) | ((unsigned)f2b(w1) << 16);
        }
        __syncthreads();
        short8 a[4];
        #pragma unroll
        for (int kc = 0; kc < 4; ++kc) {
            int kk = k0 + kc * 32 + kqo;
            if (ABF) {
                a[kc] = *(const short8*)((const unsigned short*)A_ + (size_t)arow * K + kk);
            } else {
                const float* Af = (const float*)A_ + (size_t)arow * K + kk;
                float4 lo = *(const float4*)Af;
                float4 hi = *(const float4*)(Af + 4);
                union { short8 s; unsigned short u[8]; } cv;
                cv.u[0] = f2b(lo.x); cv.u[1] = f2b(lo.y); cv.u[2] = f2b(lo.z); cv.u[3] = f2b(lo.w);
                cv.u[4] = f2b(hi.x); cv.u[5] = f2b(hi.y); cv.u[6] = f2b(hi.z); cv.u[7] = f2b(hi.w);
                a[kc] = cv.s;
            }
        }
        #pragma unroll
        for (int ng = 0; ng < 8; ++ng) {
            int col = ng * 16 + (lane & 15);
            #pragma unroll
            for (int kc = 0; kc < 4; ++kc) {
                int kidx = kc * 16 + (lane >> 4) * 4;
                const short8 b = *(const short8*)((const char*)Bt +
                        ((((col << 6) + kidx) ^ ((col & 7) << 2)) << 2));
                acc[ng] = __builtin_amdgcn_mfma_f32_16x16x32_bf16(a[kc], b, acc[ng], 0, 0, 0);
            }
        }
    }
    #pragma unroll
    for (int ng = 0; ng < 8; ++ng) {
        int gcol = colBase + ng * 16 + (lane & 15);
        float bv = bias ? bias[gcol] : 0.f;
        #pragma unroll
        for (int r = 0; r < 4; ++r) {
            int grow = rowBase + wid * 16 + (lane >> 4) * 4 + r;
            if (grow >= rows) continue;
            float val = acc[ng][r] + bv;
            if (ACT == 1) val = 0.5f * val * (1.f + erff(val * 0.70710678118654752f));
            else if (ACT == 2) val = fmaxf(val, 0.f);
            if (OBF) ((unsigned short*)out_)[(size_t)grow * Dout + gcol] = f2b(val);
            else     ((float*)out_)[(size_t)grow * Dout + gcol] = val;
        }
    }
}

// ---------- fused q,k,v,r GEMM: blockIdx.y selects weight ----------
// y=0..2 -> bf16 qkv[rows][384]; y=3 -> f32 r[rows][128]
struct QKVW { const float* W[4]; const float* b[4]; };

__global__ __launch_bounds__(256) void mgemm_qkvr(
        const float* __restrict__ x, QKVW wp, unsigned short* __restrict__ qkv,
        float* __restrict__ rbuf, int rows) {
    __shared__ unsigned Bt[128 * 64];
    const float* W = wp.W[blockIdx.y];
    const float* bias = wp.b[blockIdx.y];
    const int t = threadIdx.x;
    const int rowBase = blockIdx.x << 6;
    const int lane = t & 63, wid = t >> 6;

    f32x4 acc[8];
    #pragma unroll
    for (int i = 0; i < 8; ++i) acc[i] = (f32x4){0.f, 0.f, 0.f, 0.f};

    int arow = rowBase + wid * 16 + (lane & 15);
    if (arow > rows - 1) arow = rows - 1;
    const int kqo = (lane >> 4) * 8;

    #pragma unroll 8
    for (int it = 0; it < 32; ++it) {
        int idx = it * 256 + t;
        int n = idx & 127, kp = idx >> 7;
        float w0 = W[(size_t)(kp * 2) * DD + n];
        float w1 = W[(size_t)(kp * 2 + 1) * DD + n];
        Bt[((n << 6) + kp) ^ ((n & 7) << 2)] = (unsigned)f2b(w0) | ((unsigned)f2b(w1) << 16);
    }
    __syncthreads();
    short8 a[4];
    #pragma unroll
    for (int kc = 0; kc < 4; ++kc) {
        const float* Af = x + (size_t)arow * DD + kc * 32 + kqo;
        float4 lo = *(const float4*)Af;
        float4 hi = *(const float4*)(Af + 4);
        union { short8 s; unsigned short u[8]; } cv;
        cv.u[0] = f2b(lo.x); cv.u[1] = f2b(lo.y); cv.u[2] = f2b(lo.z); cv.u[3] = f2b(lo.w);
        cv.u[4] = f2b(hi.x); cv.u[5] = f2b(hi.y); cv.u[6] = f2b(hi.z); cv.u[7] = f2b(hi.w);
        a[kc] = cv.s;
    }
    #pragma unroll
    for (int ng = 0; ng < 8; ++ng) {
        int col = ng * 16 + (lane & 15);
        #pragma unroll
        for (int kc = 0; kc < 4; ++kc) {
            int kidx = kc * 16 + (lane >> 4) * 4;
            const short8 b = *(const short8*)((const char*)Bt +
                    ((((col << 6) + kidx) ^ ((col & 7) << 2)) << 2));
            acc[ng] = __builtin_amdgcn_mfma_f32_16x16x32_bf16(a[kc], b, acc[ng], 0, 0, 0);
        }
    }
    const int y = (int)blockIdx.y;
    #pragma unroll
    for (int ng = 0; ng < 8; ++ng) {
        int col = ng * 16 + (lane & 15);
        float bv = bias[col];
        #pragma unroll
        for (int r = 0; r < 4; ++r) {
            int grow = rowBase + wid * 16 + (lane >> 4) * 4 + r;
            if (grow >= rows) continue;
            float val = acc[ng][r] + bv;
            if (y == 3) rbuf[(size_t)grow * DD + col] = val;
            else        qkv[(size_t)grow * 384 + (y << 7) + col] = f2b(val);
        }
    }
}

// ---------- ffn2 GEMM + residual + LN (x in-place), A = h1 bf16 [rows][256] ----------
__global__ __launch_bounds__(256) void mgemm_ln(
        const unsigned short* __restrict__ h1, const float* __restrict__ W,
        const float* __restrict__ bias, const float* __restrict__ g,
        const float* __restrict__ bb, float* __restrict__ x, int rows) {
    __shared__ unsigned Bt[128 * 64];
    const int t = threadIdx.x;
    const int rowBase = blockIdx.x << 6;
    const int lane = t & 63, wid = t >> 6;

    f32x4 acc[8];
    #pragma unroll
    for (int i = 0; i < 8; ++i) acc[i] = (f32x4){0.f, 0.f, 0.f, 0.f};

    int arow = rowBase + wid * 16 + (lane & 15);
    if (arow > rows - 1) arow = rows - 1;
    const int kqo = (lane >> 4) * 8;

    for (int k0 = 0; k0 < 256; k0 += 128) {
        if (k0) __syncthreads();
        #pragma unroll 8
        for (int it = 0; it < 32; ++it) {
            int idx = it * 256 + t;
            int n = idx & 127, kp = idx >> 7;
            int krow = k0 + kp * 2;
            float w0 = W[(size_t)krow * DD + n];
            float w1 = W[(size_t)(krow + 1) * DD + n];
            Bt[((n << 6) + kp) ^ ((n & 7) << 2)] = (unsigned)f2b(w0) | ((unsigned)f2b(w1) << 16);
        }
        __syncthreads();
        short8 a[4];
        #pragma unroll
        for (int kc = 0; kc < 4; ++kc) {
            a[kc] = *(const short8*)(h1 + (size_t)arow * 256 + k0 + kc * 32 + kqo);
        }
        #pragma unroll
        for (int ng = 0; ng < 8; ++ng) {
            int col = ng * 16 + (lane & 15);
            #pragma unroll
            for (int kc = 0; kc < 4; ++kc) {
                int kidx = kc * 16 + (lane >> 4) * 4;
                const short8 b = *(const short8*)((const char*)Bt +
                        ((((col << 6) + kidx) ^ ((col & 7) << 2)) << 2));
                acc[ng] = __builtin_amdgcn_mfma_f32_16x16x32_bf16(a[kc], b, acc[ng], 0, 0, 0);
            }
        }
    }
    float tt[8][4];
    float rs[4] = {0.f, 0.f, 0.f, 0.f}, rs2[4] = {0.f, 0.f, 0.f, 0.f};
    #pragma unroll
    for (int ng = 0; ng < 8; ++ng) {
        int col = ng * 16 + (lane & 15);
        float bv = bias[col];
        #pragma unroll
        for (int r = 0; r < 4; ++r) {
            int grow = rowBase + wid * 16 + (lane >> 4) * 4 + r;
            float xo = (grow < rows) ? x[(size_t)grow * DD + col] : 0.f;
            float v = acc[ng][r] + bv + xo;
            tt[ng][r] = v;
            rs[r] += v;
            rs2[r] += v * v;
        }
    }
    #pragma unroll
    for (int r = 0; r < 4; ++r) {
        #pragma unroll
        for (int m = 1; m < 16; m <<= 1) {
            rs[r] += __shfl_xor(rs[r], m);
            rs2[r] += __shfl_xor(rs2[r], m);
        }
    }
    #pragma unroll
    for (int ng = 0; ng < 8; ++ng) {
        int col = ng * 16 + (lane & 15);
        float gg = g[col], bbb = bb[col];
        #pragma unroll
        for (int r = 0; r < 4; ++r) {
            int grow = rowBase + wid * 16 + (lane >> 4) * 4 + r;
            if (grow >= rows) continue;
            float mean = rs[r] * (1.f / DD);
            float var = rs2[r] * (1.f / DD) - mean * mean;
            x[(size_t)grow * DD + col] = (tt[ng][r] - mean) * rsqrtf(var + 1e-5f) * gg + bbb;
        }
    }
}

// ---------- small kernels ----------

__global__ void enc_kernel(const float* __restrict__ xyz, const float* __restrict__ attr,
                           const float* __restrict__ W, const float* __restrict__ b,
                           const float* __restrict__ g, const float* __restrict__ bb,
                           float* __restrict__ x) {
    int i = blockIdx.x, d = threadIdx.x;
    __shared__ float sin4[4];
    if (d < 3) sin4[d] = xyz[i * 3 + d];
    if (d == 3) sin4[3] = attr[i];
    __syncthreads();
    float y = b[d];
    #pragma unroll
    for (int kk = 0; kk < 4; ++kk) y += sin4[kk] * W[kk * DD + d];
    float s = y, s2 = y * y;
    redsum2_128(s, s2);
    float mean = s * (1.0f / DD);
    float var = s2 * (1.0f / DD) - mean * mean;
    float xn = (y - mean) * rsqrtf(var + 1e-5f) * g[d] + bb[d];
    x[i * DD + d] = fmaxf(xn, 0.f);
}

// centered W1/b1 + quadratic-form coefficients for pos-LN (one block, 128 thr)
__global__ void posprep_kernel(const float* __restrict__ W1, const float* __restrict__ b1,
                               float* __restrict__ pw) {
    int d = threadIdx.x;
    float w0 = W1[d], w1 = W1[DD + d], w2 = W1[2 * DD + d], b = b1[d];
    float s0 = w0, s1 = w1;
    redsum2_128(s0, s1);
    float s2 = w2, s3 = b;
    redsum2_128(s2, s3);
    float c0 = w0 - s0 * (1.f / DD), c1 = w1 - s1 * (1.f / DD);
    float c2 = w2 - s2 * (1.f / DD), bc = b - s3 * (1.f / DD);
    pw[d] = c0; pw[DD + d] = c1; pw[2 * DD + d] = c2; pw[3 * DD + d] = bc;
    float p0 = c0 * c0, p1 = c0 * c1; redsum2_128(p0, p1);
    float p2 = c0 * c2, p3 = c1 * c1; redsum2_128(p2, p3);
    float p4 = c1 * c2, p5 = c2 * c2; redsum2_128(p4, p5);
    float p6 = c0 * bc, p7 = c1 * bc; redsum2_128(p6, p7);
    float p8 = c2 * bc, p9 = bc * bc; redsum2_128(p8, p9);
    if (d == 0) {
        pw[512] = p0 * (1.f / DD); pw[513] = p1 * (1.f / DD); pw[514] = p2 * (1.f / DD);
        pw[515] = p3 * (1.f / DD); pw[516] = p4 * (1.f / DD); pw[517] = p5 * (1.f / DD);
        pw[518] = p6 * (1.f / DD); pw[519] = p7 * (1.f / DD); pw[520] = p8 * (1.f / DD);
        pw[521] = p9 * (1.f / DD);
    }
}

// t = relu(LN(rel@W1+b1)) per edge, written in CSR slot order (eid via cs_eid)
__global__ void pos2_kernel(const float* __restrict__ xyz, const int* __restrict__ ei,
                            const int* __restrict__ cs_eid, const float* __restrict__ pw,
                            const float* __restrict__ g, const float* __restrict__ bb,
                            unsigned* __restrict__ tb32, int nE) {
    const int lane = threadIdx.x & 63;
    const int waveg = (blockIdx.x * (blockDim.x >> 6)) + (threadIdx.x >> 6);
    const int nwaves = gridDim.x * (blockDim.x >> 6);
    float A00 = pw[512], A01 = pw[513], A02 = pw[514], A11 = pw[515], A12 = pw[516];
    float A22 = pw[517], B0 = pw[518], B1 = pw[519], B2 = pw[520], Cq = pw[521];
    int d0 = lane * 2, d1 = lane * 2 + 1;
    float w00 = pw[d0], w01 = pw[d1];
    float w10 = pw[DD + d0], w11 = pw[DD + d1];
    float w20 = pw[2 * DD + d0], w21 = pw[2 * DD + d1];
    float bc0 = pw[3 * DD + d0], bc1 = pw[3 * DD + d1];
    float g0 = g[d0], g1v = g[d1], bb0 = bb[d0], bb1 = bb[d1];
    for (int slot = waveg; slot < nE; slot += nwaves) {
        int e = cs_eid[slot];
        int src = ei[e], dst = ei[nE + e];
        float rv = 0.f;
        if (lane < 3) rv = xyz[dst * 3 + lane] - xyz[src * 3 + lane];
        float r0 = __shfl(rv, 0), r1 = __shfl(rv, 1), r2 = __shfl(rv, 2);
        float var = A00 * r0 * r0 + A11 * r1 * r1 + A22 * r2 * r2
                  + 2.f * (A01 * r0 * r1 + A02 * r0 * r2 + A12 * r1 * r2)
                  + 2.f * (B0 * r0 + B1 * r1 + B2 * r2) + Cq;
        float inv = rsqrtf(var + 1e-5f);
        float y0 = r0 * w00 + r1 * w10 + r2 * w20 + bc0;
        float y1 = r0 * w01 + r1 * w11 + r2 * w21 + bc1;
        float t0 = fmaxf(y0 * inv * g0 + bb0, 0.f);
        float t1 = fmaxf(y1 * inv * g1v + bb1, 0.f);
        tb32[(size_t)slot * 64 + lane] = (unsigned)f2b(t0) | ((unsigned)f2b(t1) << 16);
    }
}

// W2We[r][y*128+d] = sum_k W2[r][k]*We_y[k][d]; row DD holds bias fold.
// grid (DD+1, nL); DoutStride = nL*128.
__global__ void wcomb3_kernel(const float* __restrict__ W2, const float* __restrict__ b2,
                              const float* __restrict__ We, float* __restrict__ W2We,
                              float* __restrict__ b2We, int DoutStride) {
    int r = blockIdx.x, d = threadIdx.x, y = blockIdx.y;
    const float* We_l = We + (size_t)y * DD * DD;
    __shared__ float sa[DD];
    sa[d] = (r < DD) ? W2[r * DD + d] : b2[d];
    __syncthreads();
    float acc = 0.f;
    #pragma unroll 8
    for (int kk = 0; kk < DD; ++kk) acc += sa[kk] * We_l[kk * DD + d];
    if (r < DD) W2We[(size_t)r * DoutStride + y * DD + d] = acc;
    else        b2We[y * DD + d] = acc;
}

// ---------- CSR build ----------

__global__ void hist_kernel(const int* __restrict__ ei, int* __restrict__ deg, int E) {
    int e = blockIdx.x * blockDim.x + threadIdx.x;
    if (e < E) atomicAdd(&deg[ei[E + e]], 1);
}

// chunked exclusive scan: 1 block, 1024 threads, each owns ceil(n/1024) elements
__global__ void scan_kernel(const int* __restrict__ deg, int* __restrict__ ptr, int n) {
    __shared__ int partial[1024];
    int t = threadIdx.x;
    int CH = (n + 1023) >> 10;
    int beg = t * CH;
    int end = beg + CH; if (end > n) end = n;
    int s = 0;
    for (int i = beg; i < end; ++i) s += deg[i];
    partial[t] = s;
    __syncthreads();
    for (int off = 1; off < 1024; off <<= 1) {
        int add = (t >= off) ? partial[t - off] : 0;
        __syncthreads();
        partial[t] += add;
        __syncthreads();
    }
    int base = (t == 0) ? 0 : partial[t - 1];
    for (int i = beg; i < end; ++i) {
        ptr[i] = base;
        base += deg[i];
    }
    if (end == n && beg < n) ptr[n] = base;
}

__global__ void scatter_kernel(const int* __restrict__ ei, const int* __restrict__ ptr,
                               int* __restrict__ cur, int* __restrict__ cs_src,
                               int* __restrict__ cs_eid, int E) {
    int e = blockIdx.x * blockDim.x + threadIdx.x;
    if (e >= E) return;
    int dstn = ei[E + e];
    int p = atomicAdd(&cur[dstn], 1);
    int slot = ptr[dstn] + p;
    cs_src[slot] = ei[e];
    cs_eid[slot] = e;
}

// ---------- fused agg (no-max softmax) + beta gate + residual + LN1 ----------
// 1 wave per node, 2 dims per lane; ee rows in CSR slot order, stride eeStrideU32.
__global__ __launch_bounds__(256) void aggc_kernel(
        const unsigned* __restrict__ qkv, const unsigned* __restrict__ ee, int eeStrideU32,
        const int* __restrict__ ptr, const int* __restrict__ cs_src,
        const float* __restrict__ r, const float* __restrict__ Wb,
        const float* __restrict__ g1, const float* __restrict__ b1,
        float* __restrict__ x, int N) {
    int node = (blockIdx.x << 2) + (threadIdx.x >> 6);
    if (node >= N) return;
    const int lane = threadIdx.x & 63;
    unsigned qp = qkv[(size_t)node * 192 + lane];
    float q0 = b2f((unsigned short)qp), q1 = b2f((unsigned short)(qp >> 16));
    int beg = ptr[node], end = ptr[node + 1];
    float s = 0.f, a0 = 0.f, a1 = 0.f;
    for (int idx = beg; idx < end; ++idx) {
        int j = cs_src[idx];
        unsigned ep = ee[(size_t)idx * eeStrideU32 + lane];
        unsigned kp = qkv[(size_t)j * 192 + 64 + lane];
        unsigned vp = qkv[(size_t)j * 192 + 128 + lane];
        float e0 = b2f((unsigned short)ep), e1 = b2f((unsigned short)(ep >> 16));
        float kj0 = b2f((unsigned short)kp) + e0;
        float kj1 = b2f((unsigned short)(kp >> 16)) + e1;
        float p = q0 * kj0 + q1 * kj1;
        p += __shfl_xor(p, 1); p += __shfl_xor(p, 2);
        p += __shfl_xor(p, 4); p += __shfl_xor(p, 8);
        float w = __expf(p * 0.17677669529663687f);  // |alpha| << 1: max-shift not needed
        s += w;
        a0 += (b2f((unsigned short)vp) + e0) * w;
        a1 += (b2f((unsigned short)(vp >> 16)) + e1) * w;
    }
    float inv_s = (s > 0.f) ? 1.f / s : 0.f;
    float od0 = a0 * inv_s, od1 = a1 * inv_s;
    float2 rd = *(const float2*)&r[(size_t)node * DD + lane * 2];
    float2 wb0 = *(const float2*)&Wb[lane * 2];
    float2 wb1 = *(const float2*)&Wb[DD + lane * 2];
    float2 wb2 = *(const float2*)&Wb[2 * DD + lane * 2];
    float part = od0 * wb0.x + rd.x * wb1.x + (od0 - rd.x) * wb2.x
               + od1 * wb0.y + rd.y * wb1.y + (od1 - rd.y) * wb2.y;
    #pragma unroll
    for (int m = 1; m < 64; m <<= 1) part += __shfl_xor(part, m);
    float beta = 1.f / (1.f + __expf(-part));
    float2 xo = *(const float2*)&x[(size_t)node * DD + lane * 2];
    float t0 = beta * rd.x + (1.f - beta) * od0 + xo.x;
    float t1 = beta * rd.y + (1.f - beta) * od1 + xo.y;
    float ss = t0 + t1, ss2 = t0 * t0 + t1 * t1;
    #pragma unroll
    for (int m = 1; m < 64; m <<= 1) { ss += __shfl_xor(ss, m); ss2 += __shfl_xor(ss2, m); }
    float mean = ss * (1.f / DD);
    float var = ss2 * (1.f / DD) - mean * mean;
    float inv = rsqrtf(var + 1e-5f);
    float2 gg = *(const float2*)&g1[lane * 2];
    float2 bbv = *(const float2*)&b1[lane * 2];
    float2 res;
    res.x = (t0 - mean) * inv * gg.x + bbv.x;
    res.y = (t1 - mean) * inv * gg.y + bbv.y;
    *(float2*)&x[(size_t)node * DD + lane * 2] = res;
}

// ---------- heads ----------

// W1cat[k][0:64)=cW1[k], [64:128)=bW1[k]; b1cat likewise
__global__ void headprep_kernel(const float* __restrict__ cW1, const float* __restrict__ cb1,
                                const float* __restrict__ bW1, const float* __restrict__ bb1,
                                float* __restrict__ W1cat, float* __restrict__ b1cat) {
    int kk = blockIdx.x, d = threadIdx.x;
    W1cat[kk * DD + d] = (d < 64) ? cW1[kk * 64 + d] : bW1[kk * 64 + (d - 64)];
    if (kk == 0) b1cat[d] = (d < 64) ? cb1[d] : bb1[d - 64];
}

// finish heads from relu'd hidden (bf16 packed): wave per node
__global__ __launch_bounds__(256) void heads2_kernel(
        const unsigned* __restrict__ hh, const float* __restrict__ cW2,
        const float* __restrict__ cb2, const float* __restrict__ bW2,
        const float* __restrict__ bb2, float* __restrict__ outc,
        float* __restrict__ outb, int N) {
    int node = (blockIdx.x << 2) + (threadIdx.x >> 6);
    if (node >= N) return;
    const int lane = threadIdx.x & 63;
    unsigned hp = hh[(size_t)node * 64 + lane];
    float h0 = b2f((unsigned short)hp), h1 = b2f((unsigned short)(hp >> 16));
    bool isCls = lane < 32;
    int dd = isCls ? 2 * lane : 2 * lane - 128 + 64;  // local dim within its 64-block
    float c[4], bx[7];
    #pragma unroll
    for (int j = 0; j < 4; ++j)
        c[j] = isCls ? h0 * cW2[dd * 4 + j] + h1 * cW2[(dd + 1) * 4 + j] : 0.f;
    #pragma unroll
    for (int j = 0; j < 7; ++j)
        bx[j] = isCls ? 0.f : h0 * bW2[dd * 7 + j] + h1 * bW2[(dd + 1) * 7 + j];
    // half-wave reductions (cls lives in lanes 0..31, box in 32..63)
    #pragma unroll
    for (int m = 1; m < 32; m <<= 1) {
        #pragma unroll
        for (int j = 0; j < 4; ++j) c[j] += __shfl_xor(c[j], m);
        #pragma unroll
        for (int j = 0; j < 7; ++j) bx[j] += __shfl_xor(bx[j], m);
    }
    if (lane == 0) {
        #pragma unroll
        for (int j = 0; j < 4; ++j) outc[(size_t)node * 4 + j] = c[j] + cb2[j];
    } else if (lane == 32) {
        #pragma unroll
        for (int j = 0; j < 7; ++j) outb[(size_t)node * 7 + j] = bx[j] + bb2[j];
    }
}

extern "C" void kernel_launch(void* const* d_in, const int* in_sizes, int n_in,
                              void* d_out, int out_size, void* d_ws, size_t ws_size,
                              hipStream_t stream) {
    const float* xyz   = (const float*)d_in[0];
    const float* attr  = (const float*)d_in[1];
    const int*   ei    = (const int*)d_in[2];
    const float* encW  = (const float*)d_in[3];
    const float* encb  = (const float*)d_in[4];
    const float* encg  = (const float*)d_in[5];
    const float* encbb = (const float*)d_in[6];
    const float* posW1 = (const float*)d_in[7];
    const float* posb1 = (const float*)d_in[8];
    const float* posg  = (const float*)d_in[9];
    const float* posbb = (const float*)d_in[10];
    const float* posW2 = (const float*)d_in[11];
    const float* posb2 = (const float*)d_in[12];
    const float* Wq    = (const float*)d_in[13];
    const float* bq    = (const float*)d_in[14];
    const float* Wk    = (const float*)d_in[15];
    const float* bk    = (const float*)d_in[16];
    const float* Wv    = (const float*)d_in[17];
    const float* bv    = (const float*)d_in[18];
    const float* We    = (const float*)d_in[19];
    const float* Wskip = (const float*)d_in[20];
    const float* bskip = (const float*)d_in[21];
    const float* Wbeta = (const float*)d_in[22];
    const float* ln1g  = (const float*)d_in[23];
    const float* ln1b  = (const float*)d_in[24];
    const float* ln2g  = (const float*)d_in[25];
    const float* ln2b  = (const float*)d_in[26];
    const float* fW1   = (const float*)d_in[27];
    const float* fb1   = (const float*)d_in[28];
    const float* fW2   = (const float*)d_in[29];
    const float* fb2   = (const float*)d_in[30];
    const float* cW1   = (const float*)d_in[31];
    const float* cb1   = (const float*)d_in[32];
    const float* cW2   = (const float*)d_in[33];
    const float* cb2   = (const float*)d_in[34];
    const float* bW1   = (const float*)d_in[35];
    const float* bb1   = (const float*)d_in[36];
    const float* bW2   = (const float*)d_in[37];
    const float* bb2   = (const float*)d_in[38];

    const int N = in_sizes[0] / 3;
    const int E = in_sizes[2] / 2;

    size_t off = 0;
    auto alloc = [&](size_t nelem) {
        char* p = (char*)d_ws + off;
        off += nelem * sizeof(float);
        return (float*)p;
    };
    float* x     = alloc((size_t)N * DD);
    unsigned short* qkv = (unsigned short*)alloc((size_t)N * 192);   // N*384 bf16
    float* r     = alloc((size_t)N * DD);
    unsigned short* h1 = (unsigned short*)alloc((size_t)N * 128);    // N*256 bf16
    unsigned* tb32 = (unsigned*)alloc((size_t)E * 64);               // E*128 bf16 (CSR order)
    float* W2We  = alloc(DD * 384);   // up to 3 layers folded
    float* b2We  = alloc(384);
    float* pw    = alloc(544);
    float* W1cat = alloc(DD * DD);
    float* b1cat = alloc(DD);
    int* deg     = (int*)alloc(N);
    int* ptr     = (int*)alloc(N + 1);
    int* cur     = (int*)alloc(N);
    int* cs_src  = (int*)alloc(E);
    int* cs_eid  = (int*)alloc(E);
    // ee buffer: batched [E][384] bf16 if it fits, else per-layer [E][128]
    size_t need_big = off + (size_t)E * 192 * sizeof(unsigned);
    bool bigee = (need_big <= ws_size);
    unsigned* eeb = (unsigned*)alloc(bigee ? (size_t)E * 192 : (size_t)E * 64);
    const int eeStride = bigee ? 192 : 64;

    const int rtN = (N + 63) / 64;
    const int rtE = (E + 63) / 64;

    // ---- once: encoder, CSR build, pos-MLP stage 1 (LN-free, CSR-ordered) ----
    enc_kernel<<<N, DD, 0, stream>>>(xyz, attr, encW, encb, encg, encbb, x);
    hipMemsetAsync(deg, 0, N * sizeof(int), stream);
    hipMemsetAsync(cur, 0, N * sizeof(int), stream);
    hist_kernel<<<(E + 255) / 256, 256, 0, stream>>>(ei, deg, E);
    scan_kernel<<<1, 1024, 0, stream>>>(deg, ptr, N);
    scatter_kernel<<<(E + 255) / 256, 256, 0, stream>>>(ei, ptr, cur, cs_src, cs_eid, E);
    posprep_kernel<<<1, DD, 0, stream>>>(posW1, posb1, pw);
    pos2_kernel<<<1280, 256, 0, stream>>>(xyz, ei, cs_eid, pw, posg, posbb, tb32, E);

    if (bigee) {
        // all 3 layers' folded edge weights + one batched ee GEMM [E,128]@[128,384]
        wcomb3_kernel<<<dim3(DD + 1, 3), DD, 0, stream>>>(posW2, posb2, We, W2We, b2We, 384);
        mgemm<0, true, true><<<dim3(rtE, 3), 256, 0, stream>>>(tb32, W2We, b2We, eeb, E, DD, 384);
    }

    for (int l = 0; l < 3; ++l) {
        const float* Wb_l = Wbeta + (size_t)l * 3 * DD;
        const float* fW1_l = fW1 + (size_t)l * DD * 256;
        const float* fW2_l = fW2 + (size_t)l * 256 * DD;
        QKVW wp;
        wp.W[0] = Wq + (size_t)l * DD * DD;    wp.b[0] = bq + l * DD;
        wp.W[1] = Wk + (size_t)l * DD * DD;    wp.b[1] = bk + l * DD;
        wp.W[2] = Wv + (size_t)l * DD * DD;    wp.b[2] = bv + l * DD;
        wp.W[3] = Wskip + (size_t)l * DD * DD; wp.b[3] = bskip + l * DD;

        const unsigned* ee_l;
        if (bigee) {
            ee_l = eeb + (size_t)l * 64;
        } else {
            wcomb3_kernel<<<dim3(DD + 1, 1), DD, 0, stream>>>(
                posW2, posb2, We + (size_t)l * DD * DD, W2We, b2We, 128);
            mgemm<0, true, true><<<dim3(rtE, 1), 256, 0, stream>>>(tb32, W2We, b2We, eeb, E, DD, DD);
            ee_l = eeb;
        }

        // q,k,v (bf16, strided 384) + r (f32) in one fused dispatch
        mgemm_qkvr<<<dim3(rtN, 4), 256, 0, stream>>>(x, wp, qkv, r, N);

        // fused: softmax agg + beta gate + residual + LN1
        aggc_kernel<<<(N + 3) / 4, 256, 0, stream>>>((const unsigned*)qkv, ee_l, eeStride,
                                                     ptr, cs_src, r, Wb_l,
                                                     ln1g + l * DD, ln1b + l * DD, x, N);

        // FFN: h1 = gelu(x@fW1+fb1) bf16; x = LN(h1@fW2+fb2 + x)
        mgemm<1, false, true><<<dim3(rtN, 2), 256, 0, stream>>>(x, fW1_l, fb1 + l * 256, h1, N, DD, 256);
        mgemm_ln<<<dim3(rtN, 1), 256, 0, stream>>>(h1, fW2_l, fb2 + l * DD,
                                                   ln2g + l * DD, ln2b + l * DD, x, N);
    }

    // ---- heads: hidden = relu(x@[cW1|bW1]+[cb1|bb1]) via MFMA, then finish ----
    float* outc  = (float*)d_out;
    float* outbx = (float*)d_out + (size_t)N * 4;
    headprep_kernel<<<DD, DD, 0, stream>>>(cW1, cb1, bW1, bb1, W1cat, b1cat);
    mgemm<2, false, true><<<dim3(rtN, 1), 256, 0, stream>>>(x, W1cat, b1cat, h1, N, DD, DD);
    heads2_kernel<<<(N + 3) / 4, 256, 0, stream>>>((const unsigned*)h1, cW2, cb2, bW2, bb2,
                                                   outc, outbx, N);
}

// Round 7
// 522.576 us; speedup vs baseline: 8.7671x; 1.3356x over previous
//
#include <hip/hip_runtime.h>
#include <hip/hip_bf16.h>
#include <math.h>

#define DD 128

typedef __attribute__((ext_vector_type(8))) short short8;
typedef __attribute__((ext_vector_type(4))) float f32x4;

// ---------- helpers ----------

__device__ __forceinline__ unsigned short f2b(float f) {
    unsigned u = __float_as_uint(f);
    return (unsigned short)((u + 0x7FFFu + ((u >> 16) & 1u)) >> 16);
}
__device__ __forceinline__ float b2f(unsigned short b) {
    return __uint_as_float(((unsigned)b) << 16);
}
__device__ __forceinline__ unsigned packbf(float a, float b) {
    return (unsigned)f2b(a) | ((unsigned)f2b(b) << 16);
}

__device__ __forceinline__ void redsum2_128(float& a, float& b) {
    #pragma unroll
    for (int off = 32; off > 0; off >>= 1) {
        a += __shfl_down(a, off);
        b += __shfl_down(b, off);
    }
    __shared__ float sa[2], sb[2];
    int w = threadIdx.x >> 6;
    if ((threadIdx.x & 63) == 0) { sa[w] = a; sb[w] = b; }
    __syncthreads();
    a = sa[0] + sa[1];
    b = sb[0] + sb[1];
    __syncthreads();
}

// ---------- weight packing ----------
// Packed blob layout (8192 u32): Bt[((n<<6)+kp)^((n&7)<<2)] = bf16pair(W[2kp][n], W[2kp+1][n])

struct WP4 { const float* W[4]; };

__global__ void packw4_kernel(WP4 wp, unsigned* __restrict__ Wp4) {
    int bid = blockIdx.x, y = blockIdx.y, d = threadIdx.x;  // 64 x 4 blocks, 128 thr
    const float* W = wp.W[y];
    float w0 = W[(size_t)(2 * bid) * DD + d];
    float w1 = W[(size_t)(2 * bid + 1) * DD + d];
    Wp4[y * 8192 + (((d << 6) + bid) ^ ((d & 7) << 2))] = packbf(w0, w1);
}

// folded edge weight W2@We_y packed; block 64 = bias fold (f32)
__global__ void wcombp_kernel(const float* __restrict__ W2, const float* __restrict__ b2,
                              const float* __restrict__ We, unsigned* __restrict__ Wp,
                              float* __restrict__ b2We) {
    int bid = blockIdx.x, y = blockIdx.y, d = threadIdx.x;  // 65 x 3 blocks, 128 thr
    const float* We_l = We + (size_t)y * DD * DD;
    __shared__ float sa0[DD], sa1[DD];
    if (bid < 64) { sa0[d] = W2[(2 * bid) * DD + d]; sa1[d] = W2[(2 * bid + 1) * DD + d]; }
    else          { sa0[d] = b2[d]; sa1[d] = 0.f; }
    __syncthreads();
    float acc0 = 0.f, acc1 = 0.f;
    #pragma unroll 8
    for (int kk = 0; kk < DD; ++kk) {
        float w = We_l[kk * DD + d];
        acc0 += sa0[kk] * w;
        acc1 += sa1[kk] * w;
    }
    if (bid < 64) Wp[y * 8192 + (((d << 6) + bid) ^ ((d & 7) << 2))] = packbf(acc0, acc1);
    else          b2We[y * DD + d] = acc0;
}

// ---------- MFMA core pieces (shared patterns) ----------
// Bt stage of packed blob: 8 x uint4 per thread, coalesced.
// Epilogue: bf16 tile via LDS transpose -> coalesced uint4 global stores.

// ee GEMM: out[rows][128] bf16 = A[rows][128] bf16 @ Wp + bias
__global__ __launch_bounds__(256) void eegemm(
        const unsigned short* __restrict__ A, const unsigned* __restrict__ Wp,
        const float* __restrict__ bias, unsigned short* __restrict__ out, int rows) {
    __shared__ unsigned Bt[8192];
    const int t = threadIdx.x;
    const int rowBase = blockIdx.x << 6;
    const int lane = t & 63, wid = t >> 6;
    #pragma unroll
    for (int i = 0; i < 8; ++i)
        *(uint4*)&Bt[(i * 256 + t) * 4] = *(const uint4*)&Wp[(i * 256 + t) * 4];
    int arow = rowBase + wid * 16 + (lane & 15);
    if (arow > rows - 1) arow = rows - 1;
    const int kqo = (lane >> 4) * 8;
    short8 a[4];
    #pragma unroll
    for (int kc = 0; kc < 4; ++kc)
        a[kc] = *(const short8*)(A + (size_t)arow * DD + kc * 32 + kqo);
    __syncthreads();
    f32x4 acc[8];
    #pragma unroll
    for (int i = 0; i < 8; ++i) acc[i] = (f32x4){0.f, 0.f, 0.f, 0.f};
    #pragma unroll
    for (int ng = 0; ng < 8; ++ng) {
        int col = ng * 16 + (lane & 15);
        #pragma unroll
        for (int kc = 0; kc < 4; ++kc) {
            int kidx = kc * 16 + (lane >> 4) * 4;
            const short8 b = *(const short8*)((const char*)Bt +
                    ((((col << 6) + kidx) ^ ((col & 7) << 2)) << 2));
            acc[ng] = __builtin_amdgcn_mfma_f32_16x16x32_bf16(a[kc], b, acc[ng], 0, 0, 0);
        }
    }
    __syncthreads();
    unsigned short* sb16 = (unsigned short*)Bt;
    #pragma unroll
    for (int ng = 0; ng < 8; ++ng) {
        int col = ng * 16 + (lane & 15);
        float bv = bias[col];
        int cp = col >> 1, cb = col & 1;
        #pragma unroll
        for (int r = 0; r < 4; ++r) {
            int row = wid * 16 + (lane >> 4) * 4 + r;
            sb16[((row << 6) + (cp ^ ((row & 7) << 2))) * 2 + cb] = f2b(acc[ng][r] + bv);
        }
    }
    __syncthreads();
    unsigned* outw = (unsigned*)out;
    #pragma unroll
    for (int i = 0; i < 4; ++i) {
        int j = i * 1024 + t * 4;
        int row = j >> 6, cp = j & 63;
        uint4 v = *(const uint4*)&Bt[(row << 6) + (cp ^ ((row & 7) << 2))];
        int grow = rowBase + row;
        if (grow < rows) *(uint4*)&outw[(size_t)grow * 64 + cp] = v;
    }
}

// q,k,v,r GEMM from packed weights; A = xb bf16. y<3 -> bf16 qkv[rows][384]; y=3 -> f32 r.
struct B4 { const float* b[4]; };

__global__ __launch_bounds__(256) void qkvr_p4(
        const unsigned short* __restrict__ xb, const unsigned* __restrict__ Wp4, B4 bias,
        unsigned short* __restrict__ qkv, float* __restrict__ rbuf, int rows) {
    __shared__ unsigned Bt[8192];
    const int y = blockIdx.y;
    const unsigned* Wp = Wp4 + y * 8192;
    const int t = threadIdx.x;
    const int rowBase = blockIdx.x << 6;
    const int lane = t & 63, wid = t >> 6;
    #pragma unroll
    for (int i = 0; i < 8; ++i)
        *(uint4*)&Bt[(i * 256 + t) * 4] = *(const uint4*)&Wp[(i * 256 + t) * 4];
    int arow = rowBase + wid * 16 + (lane & 15);
    if (arow > rows - 1) arow = rows - 1;
    const int kqo = (lane >> 4) * 8;
    short8 a[4];
    #pragma unroll
    for (int kc = 0; kc < 4; ++kc)
        a[kc] = *(const short8*)(xb + (size_t)arow * DD + kc * 32 + kqo);
    __syncthreads();
    f32x4 acc[8];
    #pragma unroll
    for (int i = 0; i < 8; ++i) acc[i] = (f32x4){0.f, 0.f, 0.f, 0.f};
    #pragma unroll
    for (int ng = 0; ng < 8; ++ng) {
        int col = ng * 16 + (lane & 15);
        #pragma unroll
        for (int kc = 0; kc < 4; ++kc) {
            int kidx = kc * 16 + (lane >> 4) * 4;
            const short8 b = *(const short8*)((const char*)Bt +
                    ((((col << 6) + kidx) ^ ((col & 7) << 2)) << 2));
            acc[ng] = __builtin_amdgcn_mfma_f32_16x16x32_bf16(a[kc], b, acc[ng], 0, 0, 0);
        }
    }
    const float* bs = bias.b[y];
    if (y == 3) {
        #pragma unroll
        for (int ng = 0; ng < 8; ++ng) {
            int col = ng * 16 + (lane & 15);
            float bv = bs[col];
            #pragma unroll
            for (int r = 0; r < 4; ++r) {
                int grow = rowBase + wid * 16 + (lane >> 4) * 4 + r;
                if (grow < rows) rbuf[(size_t)grow * DD + col] = acc[ng][r] + bv;
            }
        }
        return;
    }
    __syncthreads();
    unsigned short* sb16 = (unsigned short*)Bt;
    #pragma unroll
    for (int ng = 0; ng < 8; ++ng) {
        int col = ng * 16 + (lane & 15);
        float bv = bs[col];
        int cp = col >> 1, cb = col & 1;
        #pragma unroll
        for (int r = 0; r < 4; ++r) {
            int row = wid * 16 + (lane >> 4) * 4 + r;
            sb16[((row << 6) + (cp ^ ((row & 7) << 2))) * 2 + cb] = f2b(acc[ng][r] + bv);
        }
    }
    __syncthreads();
    unsigned* outw = (unsigned*)qkv;
    #pragma unroll
    for (int i = 0; i < 4; ++i) {
        int j = i * 1024 + t * 4;
        int row = j >> 6, cp = j & 63;
        uint4 v = *(const uint4*)&Bt[(row << 6) + (cp ^ ((row & 7) << 2))];
        int grow = rowBase + row;
        if (grow < rows) *(uint4*)&outw[(size_t)grow * 192 + (y << 6) + cp] = v;
    }
}

// ---------- generic MFMA GEMM (f32 weights, bf16 A), bf16 out via LDS transpose ----------
// ACT: 0 none, 1 gelu, 2 relu
template <int ACT>
__global__ __launch_bounds__(256) void mgemm(
        const unsigned short* __restrict__ A, const float* __restrict__ W,
        const float* __restrict__ bias, unsigned short* __restrict__ out,
        int rows, int K, int Dout) {
    __shared__ unsigned Bt[8192];
    const int t = threadIdx.x;
    const int rowBase = blockIdx.x << 6;
    const int colBase = blockIdx.y << 7;
    const int lane = t & 63, wid = t >> 6;
    f32x4 acc[8];
    #pragma unroll
    for (int i = 0; i < 8; ++i) acc[i] = (f32x4){0.f, 0.f, 0.f, 0.f};
    int arow = rowBase + wid * 16 + (lane & 15);
    if (arow > rows - 1) arow = rows - 1;
    const int kqo = (lane >> 4) * 8;
    for (int k0 = 0; k0 < K; k0 += 128) {
        if (k0) __syncthreads();
        #pragma unroll 8
        for (int it = 0; it < 32; ++it) {
            int idx = it * 256 + t;
            int n = idx & 127, kp = idx >> 7;
            int krow = k0 + kp * 2;
            float w0 = W[(size_t)krow * Dout + colBase + n];
            float w1 = W[(size_t)(krow + 1) * Dout + colBase + n];
            Bt[((n << 6) + kp) ^ ((n & 7) << 2)] = packbf(w0, w1);
        }
        __syncthreads();
        short8 a[4];
        #pragma unroll
        for (int kc = 0; kc < 4; ++kc)
            a[kc] = *(const short8*)(A + (size_t)arow * K + k0 + kc * 32 + kqo);
        #pragma unroll
        for (int ng = 0; ng < 8; ++ng) {
            int col = ng * 16 + (lane & 15);
            #pragma unroll
            for (int kc = 0; kc < 4; ++kc) {
                int kidx = kc * 16 + (lane >> 4) * 4;
                const short8 b = *(const short8*)((const char*)Bt +
                        ((((col << 6) + kidx) ^ ((col & 7) << 2)) << 2));
                acc[ng] = __builtin_amdgcn_mfma_f32_16x16x32_bf16(a[kc], b, acc[ng], 0, 0, 0);
            }
        }
    }
    __syncthreads();
    unsigned short* sb16 = (unsigned short*)Bt;
    #pragma unroll
    for (int ng = 0; ng < 8; ++ng) {
        int col = ng * 16 + (lane & 15);
        float bv = bias[colBase + col];
        int cp = col >> 1, cb = col & 1;
        #pragma unroll
        for (int r = 0; r < 4; ++r) {
            int row = wid * 16 + (lane >> 4) * 4 + r;
            float val = acc[ng][r] + bv;
            if (ACT == 1) val = 0.5f * val * (1.f + erff(val * 0.70710678118654752f));
            else if (ACT == 2) val = fmaxf(val, 0.f);
            sb16[((row << 6) + (cp ^ ((row & 7) << 2))) * 2 + cb] = f2b(val);
        }
    }
    __syncthreads();
    unsigned* outw = (unsigned*)out;
    const int strideU = Dout >> 1, cbU = colBase >> 1;
    #pragma unroll
    for (int i = 0; i < 4; ++i) {
        int j = i * 1024 + t * 4;
        int row = j >> 6, cp = j & 63;
        uint4 v = *(const uint4*)&Bt[(row << 6) + (cp ^ ((row & 7) << 2))];
        int grow = rowBase + row;
        if (grow < rows) *(uint4*)&outw[(size_t)grow * strideU + cbU + cp] = v;
    }
}

// ---------- ffn2 GEMM + residual + LN: writes x (f32) and xb (bf16) ----------
__global__ __launch_bounds__(256) void mgemm_ln(
        const unsigned short* __restrict__ h1, const float* __restrict__ W,
        const float* __restrict__ bias, const float* __restrict__ g,
        const float* __restrict__ bb, float* __restrict__ x,
        unsigned short* __restrict__ xb, int rows) {
    __shared__ unsigned Bt[8192];
    const int t = threadIdx.x;
    const int rowBase = blockIdx.x << 6;
    const int lane = t & 63, wid = t >> 6;
    f32x4 acc[8];
    #pragma unroll
    for (int i = 0; i < 8; ++i) acc[i] = (f32x4){0.f, 0.f, 0.f, 0.f};
    int arow = rowBase + wid * 16 + (lane & 15);
    if (arow > rows - 1) arow = rows - 1;
    const int kqo = (lane >> 4) * 8;
    for (int k0 = 0; k0 < 256; k0 += 128) {
        if (k0) __syncthreads();
        #pragma unroll 8
        for (int it = 0; it < 32; ++it) {
            int idx = it * 256 + t;
            int n = idx & 127, kp = idx >> 7;
            int krow = k0 + kp * 2;
            float w0 = W[(size_t)krow * DD + n];
            float w1 = W[(size_t)(krow + 1) * DD + n];
            Bt[((n << 6) + kp) ^ ((n & 7) << 2)] = packbf(w0, w1);
        }
        __syncthreads();
        short8 a[4];
        #pragma unroll
        for (int kc = 0; kc < 4; ++kc)
            a[kc] = *(const short8*)(h1 + (size_t)arow * 256 + k0 + kc * 32 + kqo);
        #pragma unroll
        for (int ng = 0; ng < 8; ++ng) {
            int col = ng * 16 + (lane & 15);
            #pragma unroll
            for (int kc = 0; kc < 4; ++kc) {
                int kidx = kc * 16 + (lane >> 4) * 4;
                const short8 b = *(const short8*)((const char*)Bt +
                        ((((col << 6) + kidx) ^ ((col & 7) << 2)) << 2));
                acc[ng] = __builtin_amdgcn_mfma_f32_16x16x32_bf16(a[kc], b, acc[ng], 0, 0, 0);
            }
        }
    }
    float tt[8][4];
    float rs[4] = {0.f, 0.f, 0.f, 0.f}, rs2[4] = {0.f, 0.f, 0.f, 0.f};
    #pragma unroll
    for (int ng = 0; ng < 8; ++ng) {
        int col = ng * 16 + (lane & 15);
        float bv = bias[col];
        #pragma unroll
        for (int r = 0; r < 4; ++r) {
            int grow = rowBase + wid * 16 + (lane >> 4) * 4 + r;
            float xo = (grow < rows) ? x[(size_t)grow * DD + col] : 0.f;
            float v = acc[ng][r] + bv + xo;
            tt[ng][r] = v;
            rs[r] += v;
            rs2[r] += v * v;
        }
    }
    #pragma unroll
    for (int r = 0; r < 4; ++r) {
        #pragma unroll
        for (int m = 1; m < 16; m <<= 1) {
            rs[r] += __shfl_xor(rs[r], m);
            rs2[r] += __shfl_xor(rs2[r], m);
        }
    }
    __syncthreads();
    unsigned short* sb16 = (unsigned short*)Bt;
    #pragma unroll
    for (int ng = 0; ng < 8; ++ng) {
        int col = ng * 16 + (lane & 15);
        float gg = g[col], bbb = bb[col];
        int cp = col >> 1, cb = col & 1;
        #pragma unroll
        for (int r = 0; r < 4; ++r) {
            int grow = rowBase + wid * 16 + (lane >> 4) * 4 + r;
            float mean = rs[r] * (1.f / DD);
            float var = rs2[r] * (1.f / DD) - mean * mean;
            float val = (tt[ng][r] - mean) * rsqrtf(var + 1e-5f) * gg + bbb;
            if (grow < rows) x[(size_t)grow * DD + col] = val;
            int row = wid * 16 + (lane >> 4) * 4 + r;
            sb16[((row << 6) + (cp ^ ((row & 7) << 2))) * 2 + cb] = f2b(val);
        }
    }
    __syncthreads();
    unsigned* outw = (unsigned*)xb;
    #pragma unroll
    for (int i = 0; i < 4; ++i) {
        int j = i * 1024 + t * 4;
        int row = j >> 6, cp = j & 63;
        uint4 v = *(const uint4*)&Bt[(row << 6) + (cp ^ ((row & 7) << 2))];
        int grow = rowBase + row;
        if (grow < rows) *(uint4*)&outw[(size_t)grow * 64 + cp] = v;
    }
}

// ---------- small kernels ----------

__global__ void enc_kernel(const float* __restrict__ xyz, const float* __restrict__ attr,
                           const float* __restrict__ W, const float* __restrict__ b,
                           const float* __restrict__ g, const float* __restrict__ bb,
                           float* __restrict__ x, unsigned short* __restrict__ xb) {
    int i = blockIdx.x, d = threadIdx.x;
    __shared__ float sin4[4];
    if (d < 3) sin4[d] = xyz[i * 3 + d];
    if (d == 3) sin4[3] = attr[i];
    __syncthreads();
    float y = b[d];
    #pragma unroll
    for (int kk = 0; kk < 4; ++kk) y += sin4[kk] * W[kk * DD + d];
    float s = y, s2 = y * y;
    redsum2_128(s, s2);
    float mean = s * (1.0f / DD);
    float var = s2 * (1.0f / DD) - mean * mean;
    float xn = fmaxf((y - mean) * rsqrtf(var + 1e-5f) * g[d] + bb[d], 0.f);
    x[i * DD + d] = xn;
    xb[(size_t)i * DD + d] = f2b(xn);
}

// centered W1/b1 + quadratic-form coefficients for pos-LN
__global__ void posprep_kernel(const float* __restrict__ W1, const float* __restrict__ b1,
                               float* __restrict__ pw) {
    int d = threadIdx.x;
    float w0 = W1[d], w1 = W1[DD + d], w2 = W1[2 * DD + d], b = b1[d];
    float s0 = w0, s1 = w1;
    redsum2_128(s0, s1);
    float s2 = w2, s3 = b;
    redsum2_128(s2, s3);
    float c0 = w0 - s0 * (1.f / DD), c1 = w1 - s1 * (1.f / DD);
    float c2 = w2 - s2 * (1.f / DD), bc = b - s3 * (1.f / DD);
    pw[d] = c0; pw[DD + d] = c1; pw[2 * DD + d] = c2; pw[3 * DD + d] = bc;
    float p0 = c0 * c0, p1 = c0 * c1; redsum2_128(p0, p1);
    float p2 = c0 * c2, p3 = c1 * c1; redsum2_128(p2, p3);
    float p4 = c1 * c2, p5 = c2 * c2; redsum2_128(p4, p5);
    float p6 = c0 * bc, p7 = c1 * bc; redsum2_128(p6, p7);
    float p8 = c2 * bc, p9 = bc * bc; redsum2_128(p8, p9);
    if (d == 0) {
        pw[512] = p0 * (1.f / DD); pw[513] = p1 * (1.f / DD); pw[514] = p2 * (1.f / DD);
        pw[515] = p3 * (1.f / DD); pw[516] = p4 * (1.f / DD); pw[517] = p5 * (1.f / DD);
        pw[518] = p6 * (1.f / DD); pw[519] = p7 * (1.f / DD); pw[520] = p8 * (1.f / DD);
        pw[521] = p9 * (1.f / DD);
    }
}

// t = relu(LN(rel@W1+b1)) per edge, CSR slot order
__global__ void pos2_kernel(const float* __restrict__ xyz, const int* __restrict__ ei,
                            const int* __restrict__ cs_eid, const float* __restrict__ pw,
                            const float* __restrict__ g, const float* __restrict__ bb,
                            unsigned* __restrict__ tb32, int nE) {
    const int lane = threadIdx.x & 63;
    const int waveg = (blockIdx.x * (blockDim.x >> 6)) + (threadIdx.x >> 6);
    const int nwaves = gridDim.x * (blockDim.x >> 6);
    float A00 = pw[512], A01 = pw[513], A02 = pw[514], A11 = pw[515], A12 = pw[516];
    float A22 = pw[517], B0 = pw[518], B1 = pw[519], B2 = pw[520], Cq = pw[521];
    int d0 = lane * 2, d1 = lane * 2 + 1;
    float w00 = pw[d0], w01 = pw[d1];
    float w10 = pw[DD + d0], w11 = pw[DD + d1];
    float w20 = pw[2 * DD + d0], w21 = pw[2 * DD + d1];
    float bc0 = pw[3 * DD + d0], bc1 = pw[3 * DD + d1];
    float g0 = g[d0], g1v = g[d1], bb0 = bb[d0], bb1 = bb[d1];
    for (int slot = waveg; slot < nE; slot += nwaves) {
        int e = cs_eid[slot];
        int src = ei[e], dst = ei[nE + e];
        float rv = 0.f;
        if (lane < 3) rv = xyz[dst * 3 + lane] - xyz[src * 3 + lane];
        float r0 = __shfl(rv, 0), r1 = __shfl(rv, 1), r2 = __shfl(rv, 2);
        float var = A00 * r0 * r0 + A11 * r1 * r1 + A22 * r2 * r2
                  + 2.f * (A01 * r0 * r1 + A02 * r0 * r2 + A12 * r1 * r2)
                  + 2.f * (B0 * r0 + B1 * r1 + B2 * r2) + Cq;
        float inv = rsqrtf(var + 1e-5f);
        float y0 = r0 * w00 + r1 * w10 + r2 * w20 + bc0;
        float y1 = r0 * w01 + r1 * w11 + r2 * w21 + bc1;
        float t0 = fmaxf(y0 * inv * g0 + bb0, 0.f);
        float t1 = fmaxf(y1 * inv * g1v + bb1, 0.f);
        tb32[(size_t)slot * 64 + lane] = packbf(t0, t1);
    }
}

// ---------- CSR build ----------

__global__ void hist_kernel(const int* __restrict__ ei, int* __restrict__ deg, int E) {
    int e = blockIdx.x * blockDim.x + threadIdx.x;
    if (e < E) atomicAdd(&deg[ei[E + e]], 1);
}

__global__ void scan_kernel(const int* __restrict__ deg, int* __restrict__ ptr, int n) {
    __shared__ int partial[1024];
    int t = threadIdx.x;
    int CH = (n + 1023) >> 10;
    int beg = t * CH;
    int end = beg + CH; if (end > n) end = n;
    int s = 0;
    for (int i = beg; i < end; ++i) s += deg[i];
    partial[t] = s;
    __syncthreads();
    for (int off = 1; off < 1024; off <<= 1) {
        int add = (t >= off) ? partial[t - off] : 0;
        __syncthreads();
        partial[t] += add;
        __syncthreads();
    }
    int base = (t == 0) ? 0 : partial[t - 1];
    for (int i = beg; i < end; ++i) {
        ptr[i] = base;
        base += deg[i];
    }
    if (end == n && beg < n) ptr[n] = base;
}

__global__ void scatter_kernel(const int* __restrict__ ei, const int* __restrict__ ptr,
                               int* __restrict__ cur, int* __restrict__ cs_src,
                               int* __restrict__ cs_eid, int E) {
    int e = blockIdx.x * blockDim.x + threadIdx.x;
    if (e >= E) return;
    int dstn = ei[E + e];
    int p = atomicAdd(&cur[dstn], 1);
    int slot = ptr[dstn] + p;
    cs_src[slot] = ei[e];
    cs_eid[slot] = e;
}

// ---------- fused agg (no-max softmax) + beta gate + residual + LN1 ----------
__global__ __launch_bounds__(256) void aggc_kernel(
        const unsigned* __restrict__ qkv, const unsigned* __restrict__ ee,
        const int* __restrict__ ptr, const int* __restrict__ cs_src,
        const float* __restrict__ r, const float* __restrict__ Wb,
        const float* __restrict__ g1, const float* __restrict__ b1,
        float* __restrict__ x, unsigned* __restrict__ xbw, int N) {
    int node = (blockIdx.x << 2) + (threadIdx.x >> 6);
    if (node >= N) return;
    const int lane = threadIdx.x & 63;
    unsigned qp = qkv[(size_t)node * 192 + lane];
    float q0 = b2f((unsigned short)qp), q1 = b2f((unsigned short)(qp >> 16));
    int beg = ptr[node], end = ptr[node + 1];
    float s = 0.f, a0 = 0.f, a1 = 0.f;
    for (int idx = beg; idx < end; ++idx) {
        int j = cs_src[idx];
        unsigned ep = ee[(size_t)idx * 64 + lane];
        unsigned kp = qkv[(size_t)j * 192 + 64 + lane];
        unsigned vp = qkv[(size_t)j * 192 + 128 + lane];
        float e0 = b2f((unsigned short)ep), e1 = b2f((unsigned short)(ep >> 16));
        float kj0 = b2f((unsigned short)kp) + e0;
        float kj1 = b2f((unsigned short)(kp >> 16)) + e1;
        float p = q0 * kj0 + q1 * kj1;
        p += __shfl_xor(p, 1); p += __shfl_xor(p, 2);
        p += __shfl_xor(p, 4); p += __shfl_xor(p, 8);
        float w = __expf(p * 0.17677669529663687f);  // |alpha| << 1: max-shift not needed
        s += w;
        a0 += (b2f((unsigned short)vp) + e0) * w;
        a1 += (b2f((unsigned short)(vp >> 16)) + e1) * w;
    }
    float inv_s = (s > 0.f) ? 1.f / s : 0.f;
    float od0 = a0 * inv_s, od1 = a1 * inv_s;
    float2 rd = *(const float2*)&r[(size_t)node * DD + lane * 2];
    float2 wb0 = *(const float2*)&Wb[lane * 2];
    float2 wb1 = *(const float2*)&Wb[DD + lane * 2];
    float2 wb2 = *(const float2*)&Wb[2 * DD + lane * 2];
    float part = od0 * wb0.x + rd.x * wb1.x + (od0 - rd.x) * wb2.x
               + od1 * wb0.y + rd.y * wb1.y + (od1 - rd.y) * wb2.y;
    #pragma unroll
    for (int m = 1; m < 64; m <<= 1) part += __shfl_xor(part, m);
    float beta = 1.f / (1.f + __expf(-part));
    float2 xo = *(const float2*)&x[(size_t)node * DD + lane * 2];
    float t0 = beta * rd.x + (1.f - beta) * od0 + xo.x;
    float t1 = beta * rd.y + (1.f - beta) * od1 + xo.y;
    float ss = t0 + t1, ss2 = t0 * t0 + t1 * t1;
    #pragma unroll
    for (int m = 1; m < 64; m <<= 1) { ss += __shfl_xor(ss, m); ss2 += __shfl_xor(ss2, m); }
    float mean = ss * (1.f / DD);
    float var = ss2 * (1.f / DD) - mean * mean;
    float inv = rsqrtf(var + 1e-5f);
    float2 gg = *(const float2*)&g1[lane * 2];
    float2 bbv = *(const float2*)&b1[lane * 2];
    float2 res;
    res.x = (t0 - mean) * inv * gg.x + bbv.x;
    res.y = (t1 - mean) * inv * gg.y + bbv.y;
    *(float2*)&x[(size_t)node * DD + lane * 2] = res;
    xbw[(size_t)node * 64 + lane] = packbf(res.x, res.y);
}

// ---------- heads ----------

__global__ void headprep_kernel(const float* __restrict__ cW1, const float* __restrict__ cb1,
                                const float* __restrict__ bW1, const float* __restrict__ bb1,
                                float* __restrict__ W1cat, float* __restrict__ b1cat) {
    int kk = blockIdx.x, d = threadIdx.x;
    W1cat[kk * DD + d] = (d < 64) ? cW1[kk * 64 + d] : bW1[kk * 64 + (d - 64)];
    if (kk == 0) b1cat[d] = (d < 64) ? cb1[d] : bb1[d - 64];
}

__global__ __launch_bounds__(256) void heads2_kernel(
        const unsigned* __restrict__ hh, const float* __restrict__ cW2,
        const float* __restrict__ cb2, const float* __restrict__ bW2,
        const float* __restrict__ bb2, float* __restrict__ outc,
        float* __restrict__ outb, int N) {
    int node = (blockIdx.x << 2) + (threadIdx.x >> 6);
    if (node >= N) return;
    const int lane = threadIdx.x & 63;
    unsigned hp = hh[(size_t)node * 64 + lane];
    float h0 = b2f((unsigned short)hp), h1 = b2f((unsigned short)(hp >> 16));
    bool isCls = lane < 32;
    int dd = isCls ? 2 * lane : 2 * lane - 128 + 64;
    float c[4], bx[7];
    #pragma unroll
    for (int j = 0; j < 4; ++j)
        c[j] = isCls ? h0 * cW2[dd * 4 + j] + h1 * cW2[(dd + 1) * 4 + j] : 0.f;
    #pragma unroll
    for (int j = 0; j < 7; ++j)
        bx[j] = isCls ? 0.f : h0 * bW2[dd * 7 + j] + h1 * bW2[(dd + 1) * 7 + j];
    #pragma unroll
    for (int m = 1; m < 32; m <<= 1) {
        #pragma unroll
        for (int j = 0; j < 4; ++j) c[j] += __shfl_xor(c[j], m);
        #pragma unroll
        for (int j = 0; j < 7; ++j) bx[j] += __shfl_xor(bx[j], m);
    }
    if (lane == 0) {
        #pragma unroll
        for (int j = 0; j < 4; ++j) outc[(size_t)node * 4 + j] = c[j] + cb2[j];
    } else if (lane == 32) {
        #pragma unroll
        for (int j = 0; j < 7; ++j) outb[(size_t)node * 7 + j] = bx[j] + bb2[j];
    }
}

extern "C" void kernel_launch(void* const* d_in, const int* in_sizes, int n_in,
                              void* d_out, int out_size, void* d_ws, size_t ws_size,
                              hipStream_t stream) {
    const float* xyz   = (const float*)d_in[0];
    const float* attr  = (const float*)d_in[1];
    const int*   ei    = (const int*)d_in[2];
    const float* encW  = (const float*)d_in[3];
    const float* encb  = (const float*)d_in[4];
    const float* encg  = (const float*)d_in[5];
    const float* encbb = (const float*)d_in[6];
    const float* posW1 = (const float*)d_in[7];
    const float* posb1 = (const float*)d_in[8];
    const float* posg  = (const float*)d_in[9];
    const float* posbb = (const float*)d_in[10];
    const float* posW2 = (const float*)d_in[11];
    const float* posb2 = (const float*)d_in[12];
    const float* Wq    = (const float*)d_in[13];
    const float* bq    = (const float*)d_in[14];
    const float* Wk    = (const float*)d_in[15];
    const float* bk    = (const float*)d_in[16];
    const float* Wv    = (const float*)d_in[17];
    const float* bv    = (const float*)d_in[18];
    const float* We    = (const float*)d_in[19];
    const float* Wskip = (const float*)d_in[20];
    const float* bskip = (const float*)d_in[21];
    const float* Wbeta = (const float*)d_in[22];
    const float* ln1g  = (const float*)d_in[23];
    const float* ln1b  = (const float*)d_in[24];
    const float* ln2g  = (const float*)d_in[25];
    const float* ln2b  = (const float*)d_in[26];
    const float* fW1   = (const float*)d_in[27];
    const float* fb1   = (const float*)d_in[28];
    const float* fW2   = (const float*)d_in[29];
    const float* fb2   = (const float*)d_in[30];
    const float* cW1   = (const float*)d_in[31];
    const float* cb1   = (const float*)d_in[32];
    const float* cW2   = (const float*)d_in[33];
    const float* cb2   = (const float*)d_in[34];
    const float* bW1   = (const float*)d_in[35];
    const float* bb1   = (const float*)d_in[36];
    const float* bW2   = (const float*)d_in[37];
    const float* bb2   = (const float*)d_in[38];

    const int N = in_sizes[0] / 3;
    const int E = in_sizes[2] / 2;

    size_t off = 0;
    auto alloc = [&](size_t nelem) {
        char* p = (char*)d_ws + off;
        off += nelem * sizeof(float);
        return (float*)p;
    };
    float* x     = alloc((size_t)N * DD);
    unsigned short* qkv = (unsigned short*)alloc((size_t)N * 192);   // N*384 bf16
    float* r     = alloc((size_t)N * DD);
    unsigned short* h1 = (unsigned short*)alloc((size_t)N * 128);    // N*256 bf16
    unsigned short* xb = (unsigned short*)alloc((size_t)N * 64);     // N*128 bf16
    unsigned* tb32 = (unsigned*)alloc((size_t)E * 64);               // E*128 bf16 (CSR order)
    unsigned short* eeb = (unsigned short*)alloc((size_t)E * 64);    // E*128 bf16 (CSR order)
    unsigned* W2Wep = (unsigned*)alloc(3 * 8192);                    // folded packed weights
    float* b2We  = alloc(3 * DD);
    unsigned* Wp4 = (unsigned*)alloc(4 * 8192);                      // per-layer qkvr packed
    float* pw    = alloc(544);
    float* W1cat = alloc(DD * DD);
    float* b1cat = alloc(DD);
    int* deg     = (int*)alloc(N);
    int* ptr     = (int*)alloc(N + 1);
    int* cur     = (int*)alloc(N);
    int* cs_src  = (int*)alloc(E);
    int* cs_eid  = (int*)alloc(E);

    const int rtN = (N + 63) / 64;
    const int rtE = (E + 63) / 64;

    // ---- once: encoder, CSR build, pos stage-1, folded edge weights ----
    enc_kernel<<<N, DD, 0, stream>>>(xyz, attr, encW, encb, encg, encbb, x, xb);
    hipMemsetAsync(deg, 0, N * sizeof(int), stream);
    hipMemsetAsync(cur, 0, N * sizeof(int), stream);
    hist_kernel<<<(E + 255) / 256, 256, 0, stream>>>(ei, deg, E);
    scan_kernel<<<1, 1024, 0, stream>>>(deg, ptr, N);
    scatter_kernel<<<(E + 255) / 256, 256, 0, stream>>>(ei, ptr, cur, cs_src, cs_eid, E);
    posprep_kernel<<<1, DD, 0, stream>>>(posW1, posb1, pw);
    pos2_kernel<<<1280, 256, 0, stream>>>(xyz, ei, cs_eid, pw, posg, posbb, tb32, E);
    wcombp_kernel<<<dim3(65, 3), DD, 0, stream>>>(posW2, posb2, We, W2Wep, b2We);

    for (int l = 0; l < 3; ++l) {
        const float* Wb_l = Wbeta + (size_t)l * 3 * DD;
        const float* fW1_l = fW1 + (size_t)l * DD * 256;
        const float* fW2_l = fW2 + (size_t)l * 256 * DD;
        WP4 wp;
        wp.W[0] = Wq + (size_t)l * DD * DD;
        wp.W[1] = Wk + (size_t)l * DD * DD;
        wp.W[2] = Wv + (size_t)l * DD * DD;
        wp.W[3] = Wskip + (size_t)l * DD * DD;
        B4 bs;
        bs.b[0] = bq + l * DD; bs.b[1] = bk + l * DD;
        bs.b[2] = bv + l * DD; bs.b[3] = bskip + l * DD;

        // ee = t @ (W2@We_l) + b2@We_l  (packed folded weight)
        eegemm<<<rtE, 256, 0, stream>>>((const unsigned short*)tb32, W2Wep + l * 8192,
                                        b2We + l * DD, eeb, E);
        // pack q/k/v/skip weights, then fused qkvr GEMM from xb
        packw4_kernel<<<dim3(64, 4), DD, 0, stream>>>(wp, Wp4);
        qkvr_p4<<<dim3(rtN, 4), 256, 0, stream>>>(xb, Wp4, bs, qkv, r, N);

        // fused: softmax agg + beta gate + residual + LN1 -> x, xb
        aggc_kernel<<<(N + 3) / 4, 256, 0, stream>>>((const unsigned*)qkv, (const unsigned*)eeb,
                                                     ptr, cs_src, r, Wb_l,
                                                     ln1g + l * DD, ln1b + l * DD,
                                                     x, (unsigned*)xb, N);

        // FFN: h1 = gelu(xb@fW1+fb1) bf16; x,xb = LN(h1@fW2+fb2 + x)
        mgemm<1><<<dim3(rtN, 2), 256, 0, stream>>>(xb, fW1_l, fb1 + l * 256, h1, N, DD, 256);
        mgemm_ln<<<rtN, 256, 0, stream>>>(h1, fW2_l, fb2 + l * DD,
                                          ln2g + l * DD, ln2b + l * DD, x, xb, N);
    }

    // ---- heads ----
    float* outc  = (float*)d_out;
    float* outbx = (float*)d_out + (size_t)N * 4;
    headprep_kernel<<<DD, DD, 0, stream>>>(cW1, cb1, bW1, bb1, W1cat, b1cat);
    mgemm<2><<<dim3(rtN, 1), 256, 0, stream>>>(xb, W1cat, b1cat, h1, N, DD, DD);
    heads2_kernel<<<(N + 3) / 4, 256, 0, stream>>>((const unsigned*)h1, cW2, cb2, bW2, bb2,
                                                   outc, outbx, N);
}

// Round 8
// 484.356 us; speedup vs baseline: 9.4589x; 1.0789x over previous
//
#include <hip/hip_runtime.h>
#include <hip/hip_bf16.h>
#include <math.h>

#define DD 128

typedef __attribute__((ext_vector_type(8))) short short8;
typedef __attribute__((ext_vector_type(4))) float f32x4;

// ---------- helpers ----------

__device__ __forceinline__ unsigned short f2b(float f) {
    unsigned u = __float_as_uint(f);
    return (unsigned short)((u + 0x7FFFu + ((u >> 16) & 1u)) >> 16);
}
__device__ __forceinline__ float b2f(unsigned short b) {
    return __uint_as_float(((unsigned)b) << 16);
}
__device__ __forceinline__ unsigned packbf(float a, float b) {
    return (unsigned)f2b(a) | ((unsigned)f2b(b) << 16);
}

__device__ __forceinline__ void redsum2_128(float& a, float& b) {
    #pragma unroll
    for (int off = 32; off > 0; off >>= 1) {
        a += __shfl_down(a, off);
        b += __shfl_down(b, off);
    }
    __shared__ float sa[2], sb[2];
    int w = threadIdx.x >> 6;
    if ((threadIdx.x & 63) == 0) { sa[w] = a; sb[w] = b; }
    __syncthreads();
    a = sa[0] + sa[1];
    b = sb[0] + sb[1];
    __syncthreads();
}

// ---------- weight packing ----------
// Packed blob (8192 u32): Bt[((n<<6)+kp)^((n&7)<<2)] = bf16pair(W[2kp][n], W[2kp+1][n])

// pack all 12 layer weights: y = l*4 + wt, wt in {q,k,v,skip}
__global__ void packw12_kernel(const float* __restrict__ Wq, const float* __restrict__ Wk,
                               const float* __restrict__ Wv, const float* __restrict__ Ws,
                               unsigned* __restrict__ Wp) {
    int bid = blockIdx.x, y = blockIdx.y, d = threadIdx.x;  // 64 x 12, 128 thr
    int l = y >> 2, wt = y & 3;
    const float* W = (wt == 0 ? Wq : wt == 1 ? Wk : wt == 2 ? Wv : Ws) + (size_t)l * DD * DD;
    float w0 = W[(size_t)(2 * bid) * DD + d];
    float w1 = W[(size_t)(2 * bid + 1) * DD + d];
    Wp[y * 8192 + (((d << 6) + bid) ^ ((d & 7) << 2))] = packbf(w0, w1);
}

// folded edge weight W2@We_y packed; block 64 = bias fold (f32)
__global__ void wcombp_kernel(const float* __restrict__ W2, const float* __restrict__ b2,
                              const float* __restrict__ We, unsigned* __restrict__ Wp,
                              float* __restrict__ b2We) {
    int bid = blockIdx.x, y = blockIdx.y, d = threadIdx.x;  // 65 x 3 blocks, 128 thr
    const float* We_l = We + (size_t)y * DD * DD;
    __shared__ float sa0[DD], sa1[DD];
    if (bid < 64) { sa0[d] = W2[(2 * bid) * DD + d]; sa1[d] = W2[(2 * bid + 1) * DD + d]; }
    else          { sa0[d] = b2[d]; sa1[d] = 0.f; }
    __syncthreads();
    float acc0 = 0.f, acc1 = 0.f;
    #pragma unroll 8
    for (int kk = 0; kk < DD; ++kk) {
        float w = We_l[kk * DD + d];
        acc0 += sa0[kk] * w;
        acc1 += sa1[kk] * w;
    }
    if (bid < 64) Wp[y * 8192 + (((d << 6) + bid) ^ ((d & 7) << 2))] = packbf(acc0, acc1);
    else          b2We[y * DD + d] = acc0;
}

// ---------- ee GEMM with on-the-fly A ----------
// A row (t) generated from rel4[slot] + per-d constants; out[rows][128] bf16.
__global__ __launch_bounds__(256) void eegemm(
        const float4* __restrict__ rel4, const float* __restrict__ pw,
        const float* __restrict__ bb, const unsigned* __restrict__ Wp,
        const float* __restrict__ bias, unsigned short* __restrict__ out, int rows) {
    __shared__ unsigned Bt[8192];
    __shared__ float sc[640];  // gc0,gc1,gc2,gbc (from pw[0:512)), bb
    const int t = threadIdx.x;
    const int rowBase = blockIdx.x << 6;
    const int lane = t & 63, wid = t >> 6;
    #pragma unroll
    for (int i = 0; i < 8; ++i)
        *(uint4*)&Bt[(i * 256 + t) * 4] = *(const uint4*)&Wp[(i * 256 + t) * 4];
    for (int i = t; i < 640; i += 256)
        sc[i] = (i < 512) ? pw[i] : bb[i - 512];
    int arow = rowBase + wid * 16 + (lane & 15);
    if (arow > rows - 1) arow = rows - 1;
    const int kqo = (lane >> 4) * 8;
    float4 rv = rel4[arow];
    __syncthreads();
    short8 a[4];
    #pragma unroll
    for (int kc = 0; kc < 4; ++kc) {
        union { short8 s; unsigned short u[8]; } cv;
        #pragma unroll
        for (int j = 0; j < 8; ++j) {
            int d = kc * 32 + kqo + j;
            float y = fmaf(rv.x, sc[d], fmaf(rv.y, sc[128 + d], fmaf(rv.z, sc[256 + d], sc[384 + d])));
            cv.u[j] = f2b(fmaxf(fmaf(y, rv.w, sc[512 + d]), 0.f));
        }
        a[kc] = cv.s;
    }
    f32x4 acc[8];
    #pragma unroll
    for (int i = 0; i < 8; ++i) acc[i] = (f32x4){0.f, 0.f, 0.f, 0.f};
    #pragma unroll
    for (int ng = 0; ng < 8; ++ng) {
        int col = ng * 16 + (lane & 15);
        #pragma unroll
        for (int kc = 0; kc < 4; ++kc) {
            int kidx = kc * 16 + (lane >> 4) * 4;
            const short8 b = *(const short8*)((const char*)Bt +
                    ((((col << 6) + kidx) ^ ((col & 7) << 2)) << 2));
            acc[ng] = __builtin_amdgcn_mfma_f32_16x16x32_bf16(a[kc], b, acc[ng], 0, 0, 0);
        }
    }
    __syncthreads();
    unsigned short* sb16 = (unsigned short*)Bt;
    #pragma unroll
    for (int ng = 0; ng < 8; ++ng) {
        int col = ng * 16 + (lane & 15);
        float bv = bias[col];
        int cp = col >> 1, cb = col & 1;
        #pragma unroll
        for (int r = 0; r < 4; ++r) {
            int row = wid * 16 + (lane >> 4) * 4 + r;
            sb16[((row << 6) + (cp ^ ((row & 7) << 2))) * 2 + cb] = f2b(acc[ng][r] + bv);
        }
    }
    __syncthreads();
    unsigned* outw = (unsigned*)out;
    #pragma unroll
    for (int i = 0; i < 4; ++i) {
        int j = i * 1024 + t * 4;
        int row = j >> 6, cp = j & 63;
        uint4 v = *(const uint4*)&Bt[(row << 6) + (cp ^ ((row & 7) << 2))];
        int grow = rowBase + row;
        if (grow < rows) *(uint4*)&outw[(size_t)grow * 64 + cp] = v;
    }
}

// ---------- q,k,v,r GEMM from packed weights ----------
struct B4 { const float* b[4]; };

__global__ __launch_bounds__(256) void qkvr_p4(
        const unsigned short* __restrict__ xb, const unsigned* __restrict__ Wp4, B4 bias,
        unsigned short* __restrict__ qkv, float* __restrict__ rbuf, int rows) {
    __shared__ unsigned Bt[8192];
    const int y = blockIdx.y;
    const unsigned* Wp = Wp4 + y * 8192;
    const int t = threadIdx.x;
    const int rowBase = blockIdx.x << 6;
    const int lane = t & 63, wid = t >> 6;
    #pragma unroll
    for (int i = 0; i < 8; ++i)
        *(uint4*)&Bt[(i * 256 + t) * 4] = *(const uint4*)&Wp[(i * 256 + t) * 4];
    int arow = rowBase + wid * 16 + (lane & 15);
    if (arow > rows - 1) arow = rows - 1;
    const int kqo = (lane >> 4) * 8;
    short8 a[4];
    #pragma unroll
    for (int kc = 0; kc < 4; ++kc)
        a[kc] = *(const short8*)(xb + (size_t)arow * DD + kc * 32 + kqo);
    __syncthreads();
    f32x4 acc[8];
    #pragma unroll
    for (int i = 0; i < 8; ++i) acc[i] = (f32x4){0.f, 0.f, 0.f, 0.f};
    #pragma unroll
    for (int ng = 0; ng < 8; ++ng) {
        int col = ng * 16 + (lane & 15);
        #pragma unroll
        for (int kc = 0; kc < 4; ++kc) {
            int kidx = kc * 16 + (lane >> 4) * 4;
            const short8 b = *(const short8*)((const char*)Bt +
                    ((((col << 6) + kidx) ^ ((col & 7) << 2)) << 2));
            acc[ng] = __builtin_amdgcn_mfma_f32_16x16x32_bf16(a[kc], b, acc[ng], 0, 0, 0);
        }
    }
    const float* bs = bias.b[y];
    if (y == 3) {
        #pragma unroll
        for (int ng = 0; ng < 8; ++ng) {
            int col = ng * 16 + (lane & 15);
            float bv = bs[col];
            #pragma unroll
            for (int r = 0; r < 4; ++r) {
                int grow = rowBase + wid * 16 + (lane >> 4) * 4 + r;
                if (grow < rows) rbuf[(size_t)grow * DD + col] = acc[ng][r] + bv;
            }
        }
        return;
    }
    __syncthreads();
    unsigned short* sb16 = (unsigned short*)Bt;
    #pragma unroll
    for (int ng = 0; ng < 8; ++ng) {
        int col = ng * 16 + (lane & 15);
        float bv = bs[col];
        int cp = col >> 1, cb = col & 1;
        #pragma unroll
        for (int r = 0; r < 4; ++r) {
            int row = wid * 16 + (lane >> 4) * 4 + r;
            sb16[((row << 6) + (cp ^ ((row & 7) << 2))) * 2 + cb] = f2b(acc[ng][r] + bv);
        }
    }
    __syncthreads();
    unsigned* outw = (unsigned*)qkv;
    #pragma unroll
    for (int i = 0; i < 4; ++i) {
        int j = i * 1024 + t * 4;
        int row = j >> 6, cp = j & 63;
        uint4 v = *(const uint4*)&Bt[(row << 6) + (cp ^ ((row & 7) << 2))];
        int grow = rowBase + row;
        if (grow < rows) *(uint4*)&outw[(size_t)grow * 192 + (y << 6) + cp] = v;
    }
}

// ---------- generic MFMA GEMM (f32 weights, bf16 A), bf16 out ----------
template <int ACT>
__global__ __launch_bounds__(256) void mgemm(
        const unsigned short* __restrict__ A, const float* __restrict__ W,
        const float* __restrict__ bias, unsigned short* __restrict__ out,
        int rows, int K, int Dout) {
    __shared__ unsigned Bt[8192];
    const int t = threadIdx.x;
    const int rowBase = blockIdx.x << 6;
    const int colBase = blockIdx.y << 7;
    const int lane = t & 63, wid = t >> 6;
    f32x4 acc[8];
    #pragma unroll
    for (int i = 0; i < 8; ++i) acc[i] = (f32x4){0.f, 0.f, 0.f, 0.f};
    int arow = rowBase + wid * 16 + (lane & 15);
    if (arow > rows - 1) arow = rows - 1;
    const int kqo = (lane >> 4) * 8;
    for (int k0 = 0; k0 < K; k0 += 128) {
        if (k0) __syncthreads();
        #pragma unroll 8
        for (int it = 0; it < 32; ++it) {
            int idx = it * 256 + t;
            int n = idx & 127, kp = idx >> 7;
            int krow = k0 + kp * 2;
            float w0 = W[(size_t)krow * Dout + colBase + n];
            float w1 = W[(size_t)(krow + 1) * Dout + colBase + n];
            Bt[((n << 6) + kp) ^ ((n & 7) << 2)] = packbf(w0, w1);
        }
        __syncthreads();
        short8 a[4];
        #pragma unroll
        for (int kc = 0; kc < 4; ++kc)
            a[kc] = *(const short8*)(A + (size_t)arow * K + k0 + kc * 32 + kqo);
        #pragma unroll
        for (int ng = 0; ng < 8; ++ng) {
            int col = ng * 16 + (lane & 15);
            #pragma unroll
            for (int kc = 0; kc < 4; ++kc) {
                int kidx = kc * 16 + (lane >> 4) * 4;
                const short8 b = *(const short8*)((const char*)Bt +
                        ((((col << 6) + kidx) ^ ((col & 7) << 2)) << 2));
                acc[ng] = __builtin_amdgcn_mfma_f32_16x16x32_bf16(a[kc], b, acc[ng], 0, 0, 0);
            }
        }
    }
    __syncthreads();
    unsigned short* sb16 = (unsigned short*)Bt;
    #pragma unroll
    for (int ng = 0; ng < 8; ++ng) {
        int col = ng * 16 + (lane & 15);
        float bv = bias[colBase + col];
        int cp = col >> 1, cb = col & 1;
        #pragma unroll
        for (int r = 0; r < 4; ++r) {
            int row = wid * 16 + (lane >> 4) * 4 + r;
            float val = acc[ng][r] + bv;
            if (ACT == 1) val = 0.5f * val * (1.f + erff(val * 0.70710678118654752f));
            else if (ACT == 2) val = fmaxf(val, 0.f);
            sb16[((row << 6) + (cp ^ ((row & 7) << 2))) * 2 + cb] = f2b(val);
        }
    }
    __syncthreads();
    unsigned* outw = (unsigned*)out;
    const int strideU = Dout >> 1, cbU = colBase >> 1;
    #pragma unroll
    for (int i = 0; i < 4; ++i) {
        int j = i * 1024 + t * 4;
        int row = j >> 6, cp = j & 63;
        uint4 v = *(const uint4*)&Bt[(row << 6) + (cp ^ ((row & 7) << 2))];
        int grow = rowBase + row;
        if (grow < rows) *(uint4*)&outw[(size_t)grow * strideU + cbU + cp] = v;
    }
}

// ---------- ffn2 GEMM + residual + LN: writes x (f32) and xb (bf16) ----------
__global__ __launch_bounds__(256) void mgemm_ln(
        const unsigned short* __restrict__ h1, const float* __restrict__ W,
        const float* __restrict__ bias, const float* __restrict__ g,
        const float* __restrict__ bb, float* __restrict__ x,
        unsigned short* __restrict__ xb, int rows) {
    __shared__ unsigned Bt[8192];
    const int t = threadIdx.x;
    const int rowBase = blockIdx.x << 6;
    const int lane = t & 63, wid = t >> 6;
    f32x4 acc[8];
    #pragma unroll
    for (int i = 0; i < 8; ++i) acc[i] = (f32x4){0.f, 0.f, 0.f, 0.f};
    int arow = rowBase + wid * 16 + (lane & 15);
    if (arow > rows - 1) arow = rows - 1;
    const int kqo = (lane >> 4) * 8;
    for (int k0 = 0; k0 < 256; k0 += 128) {
        if (k0) __syncthreads();
        #pragma unroll 8
        for (int it = 0; it < 32; ++it) {
            int idx = it * 256 + t;
            int n = idx & 127, kp = idx >> 7;
            int krow = k0 + kp * 2;
            float w0 = W[(size_t)krow * DD + n];
            float w1 = W[(size_t)(krow + 1) * DD + n];
            Bt[((n << 6) + kp) ^ ((n & 7) << 2)] = packbf(w0, w1);
        }
        __syncthreads();
        short8 a[4];
        #pragma unroll
        for (int kc = 0; kc < 4; ++kc)
            a[kc] = *(const short8*)(h1 + (size_t)arow * 256 + k0 + kc * 32 + kqo);
        #pragma unroll
        for (int ng = 0; ng < 8; ++ng) {
            int col = ng * 16 + (lane & 15);
            #pragma unroll
            for (int kc = 0; kc < 4; ++kc) {
                int kidx = kc * 16 + (lane >> 4) * 4;
                const short8 b = *(const short8*)((const char*)Bt +
                        ((((col << 6) + kidx) ^ ((col & 7) << 2)) << 2));
                acc[ng] = __builtin_amdgcn_mfma_f32_16x16x32_bf16(a[kc], b, acc[ng], 0, 0, 0);
            }
        }
    }
    float tt[8][4];
    float rs[4] = {0.f, 0.f, 0.f, 0.f}, rs2[4] = {0.f, 0.f, 0.f, 0.f};
    #pragma unroll
    for (int ng = 0; ng < 8; ++ng) {
        int col = ng * 16 + (lane & 15);
        float bv = bias[col];
        #pragma unroll
        for (int r = 0; r < 4; ++r) {
            int grow = rowBase + wid * 16 + (lane >> 4) * 4 + r;
            float xo = (grow < rows) ? x[(size_t)grow * DD + col] : 0.f;
            float v = acc[ng][r] + bv + xo;
            tt[ng][r] = v;
            rs[r] += v;
            rs2[r] += v * v;
        }
    }
    #pragma unroll
    for (int r = 0; r < 4; ++r) {
        #pragma unroll
        for (int m = 1; m < 16; m <<= 1) {
            rs[r] += __shfl_xor(rs[r], m);
            rs2[r] += __shfl_xor(rs2[r], m);
        }
    }
    __syncthreads();
    unsigned short* sb16 = (unsigned short*)Bt;
    #pragma unroll
    for (int ng = 0; ng < 8; ++ng) {
        int col = ng * 16 + (lane & 15);
        float gg = g[col], bbb = bb[col];
        int cp = col >> 1, cb = col & 1;
        #pragma unroll
        for (int r = 0; r < 4; ++r) {
            int grow = rowBase + wid * 16 + (lane >> 4) * 4 + r;
            float mean = rs[r] * (1.f / DD);
            float var = rs2[r] * (1.f / DD) - mean * mean;
            float val = (tt[ng][r] - mean) * rsqrtf(var + 1e-5f) * gg + bbb;
            if (grow < rows) x[(size_t)grow * DD + col] = val;
            int row = wid * 16 + (lane >> 4) * 4 + r;
            sb16[((row << 6) + (cp ^ ((row & 7) << 2))) * 2 + cb] = f2b(val);
        }
    }
    __syncthreads();
    unsigned* outw = (unsigned*)xb;
    #pragma unroll
    for (int i = 0; i < 4; ++i) {
        int j = i * 1024 + t * 4;
        int row = j >> 6, cp = j & 63;
        uint4 v = *(const uint4*)&Bt[(row << 6) + (cp ^ ((row & 7) << 2))];
        int grow = rowBase + row;
        if (grow < rows) *(uint4*)&outw[(size_t)grow * 64 + cp] = v;
    }
}

// ---------- small kernels ----------

__global__ void enc_kernel(const float* __restrict__ xyz, const float* __restrict__ attr,
                           const float* __restrict__ W, const float* __restrict__ b,
                           const float* __restrict__ g, const float* __restrict__ bb,
                           float* __restrict__ x, unsigned short* __restrict__ xb) {
    int i = blockIdx.x, d = threadIdx.x;
    __shared__ float sin4[4];
    if (d < 3) sin4[d] = xyz[i * 3 + d];
    if (d == 3) sin4[3] = attr[i];
    __syncthreads();
    float y = b[d];
    #pragma unroll
    for (int kk = 0; kk < 4; ++kk) y += sin4[kk] * W[kk * DD + d];
    float s = y, s2 = y * y;
    redsum2_128(s, s2);
    float mean = s * (1.0f / DD);
    float var = s2 * (1.0f / DD) - mean * mean;
    float xn = fmaxf((y - mean) * rsqrtf(var + 1e-5f) * g[d] + bb[d], 0.f);
    x[i * DD + d] = xn;
    xb[(size_t)i * DD + d] = f2b(xn);
}

// pw[0:512): gc0,gc1,gc2,gbc (g-scaled centered cols); pw[512:522): quad consts (unscaled)
__global__ void posprep_kernel(const float* __restrict__ W1, const float* __restrict__ b1,
                               const float* __restrict__ g, float* __restrict__ pw) {
    int d = threadIdx.x;
    float w0 = W1[d], w1 = W1[DD + d], w2 = W1[2 * DD + d], b = b1[d];
    float s0 = w0, s1 = w1;
    redsum2_128(s0, s1);
    float s2 = w2, s3 = b;
    redsum2_128(s2, s3);
    float c0 = w0 - s0 * (1.f / DD), c1 = w1 - s1 * (1.f / DD);
    float c2 = w2 - s2 * (1.f / DD), bc = b - s3 * (1.f / DD);
    float gd = g[d];
    pw[d] = c0 * gd; pw[DD + d] = c1 * gd; pw[2 * DD + d] = c2 * gd; pw[3 * DD + d] = bc * gd;
    float p0 = c0 * c0, p1 = c0 * c1; redsum2_128(p0, p1);
    float p2 = c0 * c2, p3 = c1 * c1; redsum2_128(p2, p3);
    float p4 = c1 * c2, p5 = c2 * c2; redsum2_128(p4, p5);
    float p6 = c0 * bc, p7 = c1 * bc; redsum2_128(p6, p7);
    float p8 = c2 * bc, p9 = bc * bc; redsum2_128(p8, p9);
    if (d == 0) {
        pw[512] = p0 * (1.f / DD); pw[513] = p1 * (1.f / DD); pw[514] = p2 * (1.f / DD);
        pw[515] = p3 * (1.f / DD); pw[516] = p4 * (1.f / DD); pw[517] = p5 * (1.f / DD);
        pw[518] = p6 * (1.f / DD); pw[519] = p7 * (1.f / DD); pw[520] = p8 * (1.f / DD);
        pw[521] = p9 * (1.f / DD);
    }
}

// ---------- CSR build ----------

__global__ void hist_kernel(const int* __restrict__ ei, int* __restrict__ deg, int E) {
    int e = blockIdx.x * blockDim.x + threadIdx.x;
    if (e < E) atomicAdd(&deg[ei[E + e]], 1);
}

__global__ void scan_kernel(const int* __restrict__ deg, int* __restrict__ ptr, int n) {
    __shared__ int partial[1024];
    int t = threadIdx.x;
    int CH = (n + 1023) >> 10;
    int beg = t * CH;
    int end = beg + CH; if (end > n) end = n;
    int s = 0;
    for (int i = beg; i < end; ++i) s += deg[i];
    partial[t] = s;
    __syncthreads();
    for (int off = 1; off < 1024; off <<= 1) {
        int add = (t >= off) ? partial[t - off] : 0;
        __syncthreads();
        partial[t] += add;
        __syncthreads();
    }
    int base = (t == 0) ? 0 : partial[t - 1];
    for (int i = beg; i < end; ++i) {
        ptr[i] = base;
        base += deg[i];
    }
    if (end == n && beg < n) ptr[n] = base;
}

// scatter + per-edge rel/LN-inv (rel4 in CSR slot order)
__global__ void scatter_kernel(const int* __restrict__ ei, const float* __restrict__ xyz,
                               const float* __restrict__ pw, const int* __restrict__ ptr,
                               int* __restrict__ cur, int* __restrict__ cs_src,
                               float4* __restrict__ rel4, int E) {
    int e = blockIdx.x * blockDim.x + threadIdx.x;
    if (e >= E) return;
    int srcn = ei[e], dstn = ei[E + e];
    int p = atomicAdd(&cur[dstn], 1);
    int slot = ptr[dstn] + p;
    cs_src[slot] = srcn;
    float r0 = xyz[dstn * 3]     - xyz[srcn * 3];
    float r1 = xyz[dstn * 3 + 1] - xyz[srcn * 3 + 1];
    float r2 = xyz[dstn * 3 + 2] - xyz[srcn * 3 + 2];
    float var = pw[512] * r0 * r0 + pw[515] * r1 * r1 + pw[517] * r2 * r2
              + 2.f * (pw[513] * r0 * r1 + pw[514] * r0 * r2 + pw[516] * r1 * r2)
              + 2.f * (pw[518] * r0 + pw[519] * r1 + pw[520] * r2) + pw[521];
    rel4[slot] = make_float4(r0, r1, r2, rsqrtf(var + 1e-5f));
}

// ---------- fused agg (no-max softmax) + beta gate + residual + LN1 ----------
__global__ __launch_bounds__(256) void aggc_kernel(
        const unsigned* __restrict__ qkv, const unsigned* __restrict__ ee,
        const int* __restrict__ ptr, const int* __restrict__ cs_src,
        const float* __restrict__ r, const float* __restrict__ Wb,
        const float* __restrict__ g1, const float* __restrict__ b1,
        float* __restrict__ x, unsigned* __restrict__ xbw, int N) {
    int node = (blockIdx.x << 2) + (threadIdx.x >> 6);
    if (node >= N) return;
    const int lane = threadIdx.x & 63;
    unsigned qp = qkv[(size_t)node * 192 + lane];
    float q0 = b2f((unsigned short)qp), q1 = b2f((unsigned short)(qp >> 16));
    int beg = ptr[node], end = ptr[node + 1];
    float s = 0.f, a0 = 0.f, a1 = 0.f;
    for (int idx = beg; idx < end; ++idx) {
        int j = cs_src[idx];
        unsigned ep = ee[(size_t)idx * 64 + lane];
        unsigned kp = qkv[(size_t)j * 192 + 64 + lane];
        unsigned vp = qkv[(size_t)j * 192 + 128 + lane];
        float e0 = b2f((unsigned short)ep), e1 = b2f((unsigned short)(ep >> 16));
        float kj0 = b2f((unsigned short)kp) + e0;
        float kj1 = b2f((unsigned short)(kp >> 16)) + e1;
        float p = q0 * kj0 + q1 * kj1;
        p += __shfl_xor(p, 1); p += __shfl_xor(p, 2);
        p += __shfl_xor(p, 4); p += __shfl_xor(p, 8);
        float w = __expf(p * 0.17677669529663687f);  // |alpha| << 1: max-shift not needed
        s += w;
        a0 += (b2f((unsigned short)vp) + e0) * w;
        a1 += (b2f((unsigned short)(vp >> 16)) + e1) * w;
    }
    float inv_s = (s > 0.f) ? 1.f / s : 0.f;
    float od0 = a0 * inv_s, od1 = a1 * inv_s;
    float2 rd = *(const float2*)&r[(size_t)node * DD + lane * 2];
    float2 wb0 = *(const float2*)&Wb[lane * 2];
    float2 wb1 = *(const float2*)&Wb[DD + lane * 2];
    float2 wb2 = *(const float2*)&Wb[2 * DD + lane * 2];
    float part = od0 * wb0.x + rd.x * wb1.x + (od0 - rd.x) * wb2.x
               + od1 * wb0.y + rd.y * wb1.y + (od1 - rd.y) * wb2.y;
    #pragma unroll
    for (int m = 1; m < 64; m <<= 1) part += __shfl_xor(part, m);
    float beta = 1.f / (1.f + __expf(-part));
    float2 xo = *(const float2*)&x[(size_t)node * DD + lane * 2];
    float t0 = beta * rd.x + (1.f - beta) * od0 + xo.x;
    float t1 = beta * rd.y + (1.f - beta) * od1 + xo.y;
    float ss = t0 + t1, ss2 = t0 * t0 + t1 * t1;
    #pragma unroll
    for (int m = 1; m < 64; m <<= 1) { ss += __shfl_xor(ss, m); ss2 += __shfl_xor(ss2, m); }
    float mean = ss * (1.f / DD);
    float var = ss2 * (1.f / DD) - mean * mean;
    float inv = rsqrtf(var + 1e-5f);
    float2 gg = *(const float2*)&g1[lane * 2];
    float2 bbv = *(const float2*)&b1[lane * 2];
    float2 res;
    res.x = (t0 - mean) * inv * gg.x + bbv.x;
    res.y = (t1 - mean) * inv * gg.y + bbv.y;
    *(float2*)&x[(size_t)node * DD + lane * 2] = res;
    xbw[(size_t)node * 64 + lane] = packbf(res.x, res.y);
}

// ---------- heads ----------

__global__ void headprep_kernel(const float* __restrict__ cW1, const float* __restrict__ cb1,
                                const float* __restrict__ bW1, const float* __restrict__ bb1,
                                float* __restrict__ W1cat, float* __restrict__ b1cat) {
    int kk = blockIdx.x, d = threadIdx.x;
    W1cat[kk * DD + d] = (d < 64) ? cW1[kk * 64 + d] : bW1[kk * 64 + (d - 64)];
    if (kk == 0) b1cat[d] = (d < 64) ? cb1[d] : bb1[d - 64];
}

__global__ __launch_bounds__(256) void heads2_kernel(
        const unsigned* __restrict__ hh, const float* __restrict__ cW2,
        const float* __restrict__ cb2, const float* __restrict__ bW2,
        const float* __restrict__ bb2, float* __restrict__ outc,
        float* __restrict__ outb, int N) {
    int node = (blockIdx.x << 2) + (threadIdx.x >> 6);
    if (node >= N) return;
    const int lane = threadIdx.x & 63;
    unsigned hp = hh[(size_t)node * 64 + lane];
    float h0 = b2f((unsigned short)hp), h1 = b2f((unsigned short)(hp >> 16));
    bool isCls = lane < 32;
    int dd = isCls ? 2 * lane : 2 * lane - 128 + 64;
    float c[4], bx[7];
    #pragma unroll
    for (int j = 0; j < 4; ++j)
        c[j] = isCls ? h0 * cW2[dd * 4 + j] + h1 * cW2[(dd + 1) * 4 + j] : 0.f;
    #pragma unroll
    for (int j = 0; j < 7; ++j)
        bx[j] = isCls ? 0.f : h0 * bW2[dd * 7 + j] + h1 * bW2[(dd + 1) * 7 + j];
    #pragma unroll
    for (int m = 1; m < 32; m <<= 1) {
        #pragma unroll
        for (int j = 0; j < 4; ++j) c[j] += __shfl_xor(c[j], m);
        #pragma unroll
        for (int j = 0; j < 7; ++j) bx[j] += __shfl_xor(bx[j], m);
    }
    if (lane == 0) {
        #pragma unroll
        for (int j = 0; j < 4; ++j) outc[(size_t)node * 4 + j] = c[j] + cb2[j];
    } else if (lane == 32) {
        #pragma unroll
        for (int j = 0; j < 7; ++j) outb[(size_t)node * 7 + j] = bx[j] + bb2[j];
    }
}

extern "C" void kernel_launch(void* const* d_in, const int* in_sizes, int n_in,
                              void* d_out, int out_size, void* d_ws, size_t ws_size,
                              hipStream_t stream) {
    const float* xyz   = (const float*)d_in[0];
    const float* attr  = (const float*)d_in[1];
    const int*   ei    = (const int*)d_in[2];
    const float* encW  = (const float*)d_in[3];
    const float* encb  = (const float*)d_in[4];
    const float* encg  = (const float*)d_in[5];
    const float* encbb = (const float*)d_in[6];
    const float* posW1 = (const float*)d_in[7];
    const float* posb1 = (const float*)d_in[8];
    const float* posg  = (const float*)d_in[9];
    const float* posbb = (const float*)d_in[10];
    const float* posW2 = (const float*)d_in[11];
    const float* posb2 = (const float*)d_in[12];
    const float* Wq    = (const float*)d_in[13];
    const float* bq    = (const float*)d_in[14];
    const float* Wk    = (const float*)d_in[15];
    const float* bk    = (const float*)d_in[16];
    const float* Wv    = (const float*)d_in[17];
    const float* bv    = (const float*)d_in[18];
    const float* We    = (const float*)d_in[19];
    const float* Wskip = (const float*)d_in[20];
    const float* bskip = (const float*)d_in[21];
    const float* Wbeta = (const float*)d_in[22];
    const float* ln1g  = (const float*)d_in[23];
    const float* ln1b  = (const float*)d_in[24];
    const float* ln2g  = (const float*)d_in[25];
    const float* ln2b  = (const float*)d_in[26];
    const float* fW1   = (const float*)d_in[27];
    const float* fb1   = (const float*)d_in[28];
    const float* fW2   = (const float*)d_in[29];
    const float* fb2   = (const float*)d_in[30];
    const float* cW1   = (const float*)d_in[31];
    const float* cb1   = (const float*)d_in[32];
    const float* cW2   = (const float*)d_in[33];
    const float* cb2   = (const float*)d_in[34];
    const float* bW1   = (const float*)d_in[35];
    const float* bb1   = (const float*)d_in[36];
    const float* bW2   = (const float*)d_in[37];
    const float* bb2   = (const float*)d_in[38];

    const int N = in_sizes[0] / 3;
    const int E = in_sizes[2] / 2;

    size_t off = 0;
    auto alloc = [&](size_t nelem) {
        char* p = (char*)d_ws + off;
        off += nelem * sizeof(float);
        return (float*)p;
    };
    float* x     = alloc((size_t)N * DD);
    unsigned short* qkv = (unsigned short*)alloc((size_t)N * 192);   // N*384 bf16
    float* r     = alloc((size_t)N * DD);
    unsigned short* h1 = (unsigned short*)alloc((size_t)N * 128);    // N*256 bf16
    unsigned short* xb = (unsigned short*)alloc((size_t)N * 64);     // N*128 bf16
    float4* rel4 = (float4*)alloc((size_t)E * 4);                    // CSR-order rel + inv
    unsigned short* eeb = (unsigned short*)alloc((size_t)E * 64);    // E*128 bf16 (CSR order)
    unsigned* W2Wep = (unsigned*)alloc(3 * 8192);                    // folded packed weights
    float* b2We  = alloc(3 * DD);
    unsigned* Wp12 = (unsigned*)alloc(12 * 8192);                    // q/k/v/skip packed
    float* pw    = alloc(544);
    float* W1cat = alloc(DD * DD);
    float* b1cat = alloc(DD);
    int* deg     = (int*)alloc(N);
    int* ptr     = (int*)alloc(N + 1);
    int* cur     = (int*)alloc(N);
    int* cs_src  = (int*)alloc(E);

    const int rtN = (N + 63) / 64;
    const int rtE = (E + 63) / 64;

    // ---- once: encoder, CSR build (+rel4), packed weights ----
    enc_kernel<<<N, DD, 0, stream>>>(xyz, attr, encW, encb, encg, encbb, x, xb);
    hipMemsetAsync(deg, 0, N * sizeof(int), stream);
    hipMemsetAsync(cur, 0, N * sizeof(int), stream);
    hist_kernel<<<(E + 255) / 256, 256, 0, stream>>>(ei, deg, E);
    scan_kernel<<<1, 1024, 0, stream>>>(deg, ptr, N);
    posprep_kernel<<<1, DD, 0, stream>>>(posW1, posb1, posg, pw);
    scatter_kernel<<<(E + 255) / 256, 256, 0, stream>>>(ei, xyz, pw, ptr, cur, cs_src, rel4, E);
    wcombp_kernel<<<dim3(65, 3), DD, 0, stream>>>(posW2, posb2, We, W2Wep, b2We);
    packw12_kernel<<<dim3(64, 12), DD, 0, stream>>>(Wq, Wk, Wv, Wskip, Wp12);
    headprep_kernel<<<DD, DD, 0, stream>>>(cW1, cb1, bW1, bb1, W1cat, b1cat);

    for (int l = 0; l < 3; ++l) {
        const float* Wb_l = Wbeta + (size_t)l * 3 * DD;
        const float* fW1_l = fW1 + (size_t)l * DD * 256;
        const float* fW2_l = fW2 + (size_t)l * 256 * DD;
        B4 bs;
        bs.b[0] = bq + l * DD; bs.b[1] = bk + l * DD;
        bs.b[2] = bv + l * DD; bs.b[3] = bskip + l * DD;

        // ee = t(rel4) @ (W2@We_l) + b2@We_l  (A generated on the fly)
        eegemm<<<rtE, 256, 0, stream>>>(rel4, pw, posbb, W2Wep + l * 8192,
                                        b2We + l * DD, eeb, E);
        // fused q,k,v,skip GEMM from xb
        qkvr_p4<<<dim3(rtN, 4), 256, 0, stream>>>(xb, Wp12 + (size_t)l * 4 * 8192, bs, qkv, r, N);

        // fused: softmax agg + beta gate + residual + LN1 -> x, xb
        aggc_kernel<<<(N + 3) / 4, 256, 0, stream>>>((const unsigned*)qkv, (const unsigned*)eeb,
                                                     ptr, cs_src, r, Wb_l,
                                                     ln1g + l * DD, ln1b + l * DD,
                                                     x, (unsigned*)xb, N);

        // FFN: h1 = gelu(xb@fW1+fb1) bf16; x,xb = LN(h1@fW2+fb2 + x)
        mgemm<1><<<dim3(rtN, 2), 256, 0, stream>>>(xb, fW1_l, fb1 + l * 256, h1, N, DD, 256);
        mgemm_ln<<<rtN, 256, 0, stream>>>(h1, fW2_l, fb2 + l * DD,
                                          ln2g + l * DD, ln2b + l * DD, x, xb, N);
    }

    // ---- heads ----
    float* outc  = (float*)d_out;
    float* outbx = (float*)d_out + (size_t)N * 4;
    mgemm<2><<<dim3(rtN, 1), 256, 0, stream>>>(xb, W1cat, b1cat, h1, N, DD, DD);
    heads2_kernel<<<(N + 3) / 4, 256, 0, stream>>>((const unsigned*)h1, cW2, cb2, bW2, bb2,
                                                   outc, outbx, N);
}